// Round 13
// baseline (1944.894 us; speedup 1.0000x reference)
//
#include <hip/hip_runtime.h>
#include <hip/hip_bf16.h>
#include <math.h>

#define BB 32
#define LL 2048
#define INP 192
#define OUTC 2
#define HH 512
#define NN2 32
#define NNL 4
#define TABB 32768   // bytes of table per (layer,h)

using short8 = __attribute__((ext_vector_type(8))) short;
using f32x4  = __attribute__((ext_vector_type(4))) float;
using f32x2  = __attribute__((ext_vector_type(2))) float;

struct u2x2 { uint2 a, b; };

__device__ __forceinline__ float sigmoidf_(float x) {
  return 1.0f / (1.0f + expf(-x));
}
__device__ __forceinline__ unsigned short bf16bits(float x) {
  __hip_bfloat16 b = __float2bfloat16(x);
  return __builtin_bit_cast(unsigned short, b);
}
__device__ __forceinline__ float bfval(unsigned short b) {
  unsigned int u = (unsigned int)b << 16;
  return __builtin_bit_cast(float, u);
}
// Abramowitz-Stegun 7.1.26 erf (max err 1.5e-7) based exact-GELU
__device__ __forceinline__ float gelu_fast(float x) {
  float s = x * 0.70710678118654752f;
  float ax = fabsf(s);
  float tt = 1.0f / fmaf(0.3275911f, ax, 1.0f);
  float p = fmaf(1.061405429f, tt, -1.453152027f);
  p = fmaf(p, tt, 1.421413741f);
  p = fmaf(p, tt, -0.284496736f);
  p = fmaf(p, tt, 0.254829592f);
  float e = __expf(-s * s);
  float er = 1.0f - p * tt * e;
  er = copysignf(er, s);
  return 0.5f * x * (1.0f + er);
}
__device__ __forceinline__ void gload16(const void* gsrc, void* ldst) {
  __builtin_amdgcn_global_load_lds(
      (const __attribute__((address_space(1))) void*)gsrc,
      (__attribute__((address_space(3))) void*)ldst, 16, 0, 0);
}

// ---------------------------------------------------------------------------
// P[NL][H][N2][4] = {w_re, w_im, c2_re, c2_im}
// ---------------------------------------------------------------------------
__global__ __launch_bounds__(256) void k_params(const float* __restrict__ log_dt,
                                                const float* __restrict__ Cri,
                                                const float* __restrict__ lAr,
                                                const float* __restrict__ Aim,
                                                float* __restrict__ P) {
  int idx = blockIdx.x * 256 + threadIdx.x;
  if (idx >= NNL * HH * NN2) return;
  float dt  = expf(log_dt[idx / NN2]);
  float Are = -expf(lAr[idx]);
  float Aimv = Aim[idx];
  float dre = Are * dt, dim = Aimv * dt;
  float er = expf(dre);
  float wrv = er * cosf(dim);
  float wiv = er * sinf(dim);
  float Er = wrv - 1.0f, Ei = wiv;
  float den = Are * Are + Aimv * Aimv;
  float Fr = (Er * Are + Ei * Aimv) / den;
  float Fi = (Ei * Are - Er * Aimv) / den;
  float Cre = Cri[idx * 2 + 0], Cim = Cri[idx * 2 + 1];
  P[idx * 4 + 0] = wrv;
  P[idx * 4 + 1] = wiv;
  P[idx * 4 + 2] = 2.0f * (Cre * Fr - Cim * Fi);
  P[idx * 4 + 3] = 2.0f * (Cre * Fi + Cim * Fr);
}

// ---------------------------------------------------------------------------
// Build per-(layer,h) MFMA fragment tables (split bf16 hi/lo) + scan tables.
// ---------------------------------------------------------------------------
__global__ __launch_bounds__(64) void k_tables(const float* __restrict__ P,
                                               char* __restrict__ Tab) {
  __shared__ float kk[32];
  int tid = threadIdx.x;
  int lh = blockIdx.x;
  char* tb = Tab + (size_t)lh * TABB;
  if (tid < 32) {
    int n = tid;
    const float4 pq = reinterpret_cast<const float4*>(P)[(size_t)lh * NN2 + n];
    float wr = pq.x, wi = pq.y, c2r = pq.z, c2i = pq.w;
    int mt = n >> 4;
    float pr = 1.0f, pi = 0.0f;   // w^d
    for (int d = 0; d < 32; ++d) {
      {  // WA at t = 31-d
        int t_ = 31 - d;
        int lane = ((t_ >> 3) << 4) + (n & 15);
        int j = t_ & 7;
        unsigned short hr = bf16bits(pr);
        unsigned short lr = bf16bits(pr - bfval(hr));
        unsigned short hi_ = bf16bits(pi);
        unsigned short li_ = bf16bits(pi - bfval(hi_));
        *(unsigned short*)(tb + (mt * 2 + 0) * 1024 + lane * 16 + j * 2) = hr;
        *(unsigned short*)(tb + (mt * 2 + 1) * 1024 + lane * 16 + j * 2) = hi_;
        *(unsigned short*)(tb + 4096 + (mt * 2 + 0) * 1024 + lane * 16 + j * 2) = lr;
        *(unsigned short*)(tb + 4096 + (mt * 2 + 1) * 1024 + lane * 16 + j * 2) = li_;
      }
      {  // WC at t = d
        int mtT = d >> 4;
        int lane = (((n & 15) >> 2) << 4) + (d & 15);
        int jre = n & 3, jim = (n & 3) + 4;
        unsigned short hr = bf16bits(pr);
        unsigned short lr = bf16bits(pr - bfval(hr));
        float nim = -pi;
        unsigned short hi_ = bf16bits(nim);
        unsigned short li_ = bf16bits(nim - bfval(hi_));
        char* bh = tb + 8192 + (mtT * 2 + mt) * 1024 + lane * 16;
        char* bl = tb + 12288 + (mtT * 2 + mt) * 1024 + lane * 16;
        *(unsigned short*)(bh + jre * 2) = hr;
        *(unsigned short*)(bh + jim * 2) = hi_;
        *(unsigned short*)(bl + jre * 2) = lr;
        *(unsigned short*)(bl + jim * 2) = li_;
      }
      float kp = c2r * pr - c2i * pi;
      #pragma unroll
      for (int k = 1; k < 32; k <<= 1) kp += __shfl_xor(kp, k, 32);
      if (n == 0) kk[d] = kp;
      float nr = pr * wr - pi * wi;
      pi = pr * wi + pi * wr;
      pr = nr;
    }
    float w32r = pr, w32i = pi;
    float c2wr = c2r * wr - c2i * wi;
    float c2wi = c2r * wi + c2i * wr;
    int s = ((n >> 4) << 2) + (n & 3);
    int gg = (n & 15) >> 2;
    float pmr = 1.0f, pmi = 0.0f;   // w32^m
    for (int m = 0; m < 16; ++m) {
      float* q = (float*)(tb + 20480 + (size_t)((s * 64) + (gg * 16 + m)) * 24);
      q[0] = w32r; q[1] = w32i; q[2] = pmr; q[3] = pmi; q[4] = c2wr; q[5] = c2wi;
      float t2 = pmr * w32r - pmi * w32i;
      pmi = pmr * w32i + pmi * w32r;
      pmr = t2;
    }
  }
  __syncthreads();
  for (int idx = tid; idx < 1024; idx += 64) {
    int mt = idx >> 9, rem = idx & 511;
    int lane = rem >> 3, j = rem & 7;
    int tt = (mt << 4) + (lane & 15);
    int jf = ((lane >> 4) << 3) + j;
    float val = (jf <= tt) ? kk[tt - jf] : 0.0f;
    unsigned short hb = bf16bits(val);
    unsigned short lb = bf16bits(val - bfval(hb));
    *(unsigned short*)(tb + 16384 + mt * 1024 + lane * 16 + j * 2) = hb;
    *(unsigned short*)(tb + 18432 + mt * 1024 + lane * 16 + j * 2) = lb;
  }
}

// ---------------------------------------------------------------------------
// fp32 -> bf16 convert (CW weights).
// ---------------------------------------------------------------------------
__global__ __launch_bounds__(256) void k_tobf16(const float* __restrict__ src,
                                                __hip_bfloat16* __restrict__ dst,
                                                int n) {
  int i = (blockIdx.x * 256 + threadIdx.x) * 4;
  if (i >= n) return;
  float4 v = *reinterpret_cast<const float4*>(&src[i]);
  dst[i + 0] = __float2bfloat16(v.x);
  dst[i + 1] = __float2bfloat16(v.y);
  dst[i + 2] = __float2bfloat16(v.z);
  dst[i + 3] = __float2bfloat16(v.w);
}

// ---------------------------------------------------------------------------
// Split X fp32 -> Xhi/Xlo bf16 planes (same [b][l][k] layout).
// ---------------------------------------------------------------------------
__global__ __launch_bounds__(256) void k_splitx(const float* __restrict__ src,
                                                __hip_bfloat16* __restrict__ hi,
                                                __hip_bfloat16* __restrict__ lo,
                                                int n) {
  int i = (blockIdx.x * 256 + threadIdx.x) * 4;
  if (i >= n) return;
  float4 v = *reinterpret_cast<const float4*>(&src[i]);
  float vv[4] = {v.x, v.y, v.z, v.w};
  unsigned short hb[4], lb[4];
  #pragma unroll
  for (int j = 0; j < 4; ++j) {
    hb[j] = bf16bits(vv[j]);
    lb[j] = bf16bits(vv[j] - bfval(hb[j]));
  }
  *reinterpret_cast<uint2*>(hi + i) = make_uint2(
      (unsigned)hb[0] | ((unsigned)hb[1] << 16), (unsigned)hb[2] | ((unsigned)hb[3] << 16));
  *reinterpret_cast<uint2*>(lo + i) = make_uint2(
      (unsigned)lb[0] | ((unsigned)lb[1] << 16), (unsigned)lb[2] | ((unsigned)lb[3] << 16));
}

// ---------------------------------------------------------------------------
// W[k][h] fp32 -> Wt hi/lo bf16 [h][k] (transposed, split). One-time, tiny.
// ---------------------------------------------------------------------------
__global__ __launch_bounds__(256) void k_prepwt(const float* __restrict__ W,
                                                __hip_bfloat16* __restrict__ hi,
                                                __hip_bfloat16* __restrict__ lo) {
  int idx = blockIdx.x * 256 + threadIdx.x;   // h*INP + k
  if (idx >= HH * INP) return;
  int h = idx / INP, k = idx - h * INP;
  float v = W[(size_t)k * HH + h];
  unsigned short hb = bf16bits(v);
  hi[idx] = __builtin_bit_cast(__hip_bfloat16, hb);
  lo[idx] = __float2bfloat16(v - bfval(hb));
}

// ---------------------------------------------------------------------------
// Input GEMM, bf16 MFMA split (unchanged from round 8).
// ---------------------------------------------------------------------------
__global__ __launch_bounds__(256) void k_ingemm(const __hip_bfloat16* __restrict__ Xhi,
                                                const __hip_bfloat16* __restrict__ Xlo,
                                                const __hip_bfloat16* __restrict__ Wthi,
                                                const __hip_bfloat16* __restrict__ Wtlo,
                                                const float* __restrict__ bias,
                                                float* __restrict__ U) {
  int lt = blockIdx.x * 128;
  int ht = blockIdx.y * 128;
  int b  = blockIdx.z;
  int t = threadIdx.x;
  int wid = t >> 6, lane = t & 63;
  int wrow = wid >> 1, wcol = wid & 1;
  int l15 = lane & 15, g = lane >> 4;

  const short* Xh = (const short*)Xhi + (size_t)b * LL * INP;
  const short* Xl = (const short*)Xlo + (size_t)b * LL * INP;
  const short* Bh = (const short*)Wthi;
  const short* Bl = (const short*)Wtlo;

  f32x4 acc[4][4];
  #pragma unroll
  for (int m = 0; m < 4; ++m)
    #pragma unroll
    for (int n = 0; n < 4; ++n) acc[m][n] = f32x4{0.f, 0.f, 0.f, 0.f};

  int lbase = lt + wrow * 64 + l15;
  int hbase = ht + wcol * 64 + l15;

  #pragma unroll
  for (int ks = 0; ks < 6; ++ks) {
    int k0 = ks * 32 + 8 * g;
    short8 ah[4], al[4], bh[4], bl[4];
    #pragma unroll
    for (int m = 0; m < 4; ++m) {
      size_t off = (size_t)(lbase + m * 16) * INP + k0;
      ah[m] = *reinterpret_cast<const short8*>(Xh + off);
      al[m] = *reinterpret_cast<const short8*>(Xl + off);
    }
    #pragma unroll
    for (int n = 0; n < 4; ++n) {
      size_t off = (size_t)(hbase + n * 16) * INP + k0;
      bh[n] = *reinterpret_cast<const short8*>(Bh + off);
      bl[n] = *reinterpret_cast<const short8*>(Bl + off);
    }
    #pragma unroll
    for (int m = 0; m < 4; ++m)
      #pragma unroll
      for (int n = 0; n < 4; ++n) {
        acc[m][n] = __builtin_amdgcn_mfma_f32_16x16x32_bf16(ah[m], bh[n], acc[m][n], 0, 0, 0);
        acc[m][n] = __builtin_amdgcn_mfma_f32_16x16x32_bf16(ah[m], bl[n], acc[m][n], 0, 0, 0);
        acc[m][n] = __builtin_amdgcn_mfma_f32_16x16x32_bf16(al[m], bh[n], acc[m][n], 0, 0, 0);
      }
  }

  #pragma unroll
  for (int n = 0; n < 4; ++n) {
    int h = hbase + n * 16;
    float bv = bias[h];
    #pragma unroll
    for (int m = 0; m < 4; ++m) {
      int l0 = lt + wrow * 64 + m * 16 + g * 4;
      float4 o;
      o.x = acc[m][n][0] + bv;
      o.y = acc[m][n][1] + bv;
      o.z = acc[m][n][2] + bv;
      o.w = acc[m][n][3] + bv;
      *reinterpret_cast<float4*>(&U[((size_t)b * HH + h) * LL + l0]) = o;
    }
  }
}

// ---------------------------------------------------------------------------
// MFMA chunk-parallel S4D scan, round 13: round-12 structure with
// (a) __launch_bounds__(256,5): target <=102 VGPR (5 waves/SIMD; was 108/4),
//     mild 6-reg shave -- NOT round-11's 23-reg spill-inducing demand;
// (b) epilogue LDS swizzle (l>>5)&7 (spreads the 16 m-lanes across banks;
//     (l>>4) left the m dimension unspread -> ~4-way conflicts).
// Math bit-identical.
// ---------------------------------------------------------------------------
__global__ __launch_bounds__(256, 5) void k_scan(const float* __restrict__ U,
                                                 short* __restrict__ Ybt,
                                                 const char* __restrict__ Tab,
                                                 const float* __restrict__ Dp) {
  __shared__ __align__(16) char smem[16384];  // ylds [l][h'4], XOR-swizzled
  int t = threadIdx.x;
  int lane = t & 63;
  int wid = t >> 6;                              // 0..3 = h'
  int row = __builtin_amdgcn_readfirstlane(blockIdx.x * 4 + wid);
  int h = row & (HH - 1);
  const char* tb = Tab + (size_t)h * TABB;
  const float* urow = U + (size_t)row * LL;
  int g = lane >> 4, m = lane & 15;

  short8 uh[4], ul[4];
  #pragma unroll
  for (int c0 = 0; c0 < 4; ++c0) {
    const float* p = urow + 512 * c0 + 32 * m + 8 * g;
    float4 va = *reinterpret_cast<const float4*>(p);
    float4 vb = *reinterpret_cast<const float4*>(p + 4);
    float v[8] = {va.x, va.y, va.z, va.w, vb.x, vb.y, vb.z, vb.w};
    short8 hi, lo;
    #pragma unroll
    for (int j = 0; j < 8; ++j) {
      unsigned short hb = bf16bits(v[j]);
      hi[j] = (short)hb;
      lo[j] = (short)bf16bits(v[j] - bfval(hb));
    }
    uh[c0] = hi;
    ul[c0] = lo;
  }

  f32x4 Z[2][2][4];
  #pragma unroll
  for (int mt = 0; mt < 2; ++mt)
    #pragma unroll
    for (int reim = 0; reim < 2; ++reim) {
      short8 whi = *reinterpret_cast<const short8*>(tb + (mt * 2 + reim) * 1024 + lane * 16);
      short8 wlo = *reinterpret_cast<const short8*>(tb + 4096 + (mt * 2 + reim) * 1024 + lane * 16);
      #pragma unroll
      for (int c0 = 0; c0 < 4; ++c0) {
        f32x4 z = {0.f, 0.f, 0.f, 0.f};
        z = __builtin_amdgcn_mfma_f32_16x16x32_bf16(whi, uh[c0], z, 0, 0, 0);
        z = __builtin_amdgcn_mfma_f32_16x16x32_bf16(whi, ul[c0], z, 0, 0, 0);
        z = __builtin_amdgcn_mfma_f32_16x16x32_bf16(wlo, uh[c0], z, 0, 0, 0);
        Z[mt][reim][c0] = z;
      }
    }

  float aR[8][4], aI[8][4];
  #pragma unroll
  for (int s = 0; s < 8; ++s) {
    int mt = s >> 2, i = s & 3;
    const char* plb = tb + 20480 + (size_t)(s * 64 + lane) * 24;
    f32x2 w32 = *reinterpret_cast<const f32x2*>(plb);
    f32x2 w32m = *reinterpret_cast<const f32x2*>(plb + 8);
    f32x2 c2w = *reinterpret_cast<const f32x2*>(plb + 16);
    float r1r = w32[0], r1i = w32[1];
    float r2r = r1r * r1r - r1i * r1i, r2i = 2.f * r1r * r1i;
    float r4r = r2r * r2r - r2i * r2i, r4i = 2.f * r2r * r2i;
    float r8r = r4r * r4r - r4i * r4i, r8i = 2.f * r4r * r4i;
    float w16r = r8r * r8r - r8i * r8i, w16i = 2.f * r8r * r8i;  // w32^16

    float Er[4], Ei[4], Tr[4], Ti[4];
    #pragma unroll
    for (int c0 = 0; c0 < 4; ++c0) {
      float Pr = Z[mt][0][c0][i], Pi = Z[mt][1][c0][i];
      {
        float qr = __shfl_up(Pr, 1u, 16), qi = __shfl_up(Pi, 1u, 16);
        if (m < 1) { qr = 0.f; qi = 0.f; }
        Pr = fmaf(r1r, qr, fmaf(-r1i, qi, Pr));
        Pi = fmaf(r1r, qi, fmaf(r1i, qr, Pi));
      }
      {
        float qr = __shfl_up(Pr, 2u, 16), qi = __shfl_up(Pi, 2u, 16);
        if (m < 2) { qr = 0.f; qi = 0.f; }
        Pr = fmaf(r2r, qr, fmaf(-r2i, qi, Pr));
        Pi = fmaf(r2r, qi, fmaf(r2i, qr, Pi));
      }
      {
        float qr = __shfl_up(Pr, 4u, 16), qi = __shfl_up(Pi, 4u, 16);
        if (m < 4) { qr = 0.f; qi = 0.f; }
        Pr = fmaf(r4r, qr, fmaf(-r4i, qi, Pr));
        Pi = fmaf(r4r, qi, fmaf(r4i, qr, Pi));
      }
      {
        float qr = __shfl_up(Pr, 8u, 16), qi = __shfl_up(Pi, 8u, 16);
        if (m < 8) { qr = 0.f; qi = 0.f; }
        Pr = fmaf(r8r, qr, fmaf(-r8i, qi, Pr));
        Pi = fmaf(r8r, qi, fmaf(r8i, qr, Pi));
      }
      float eqr = __shfl_up(Pr, 1u, 16), eqi = __shfl_up(Pi, 1u, 16);
      if (m == 0) { eqr = 0.f; eqi = 0.f; }
      Er[c0] = eqr; Ei[c0] = eqi;
      Tr[c0] = __shfl(Pr, 15, 16);
      Ti[c0] = __shfl(Pi, 15, 16);
    }
    float C1r = Tr[0], C1i = Ti[0];
    float C2r = fmaf(w16r, C1r, fmaf(-w16i, C1i, Tr[1]));
    float C2i = fmaf(w16r, C1i, fmaf(w16i, C1r, Ti[1]));
    float C3r = fmaf(w16r, C2r, fmaf(-w16i, C2i, Tr[2]));
    float C3i = fmaf(w16r, C2i, fmaf(w16i, C2r, Ti[2]));
    float Cr[4] = {0.f, C1r, C2r, C3r};
    float Ci[4] = {0.f, C1i, C2i, C3i};
    #pragma unroll
    for (int c0 = 0; c0 < 4; ++c0) {
      float Erc = fmaf(w32m[0], Cr[c0], fmaf(-w32m[1], Ci[c0], Er[c0]));
      float Eic = fmaf(w32m[0], Ci[c0], fmaf(w32m[1], Cr[c0], Ei[c0]));
      aR[s][c0] = c2w[0] * Erc - c2w[1] * Eic;
      aI[s][c0] = c2w[0] * Eic + c2w[1] * Erc;
    }
  }

  short8 afh[2][4], afl[2][4];
  #pragma unroll
  for (int kt = 0; kt < 2; ++kt)
    #pragma unroll
    for (int c0 = 0; c0 < 4; ++c0) {
      float av[8] = {aR[kt * 4 + 0][c0], aR[kt * 4 + 1][c0], aR[kt * 4 + 2][c0], aR[kt * 4 + 3][c0],
                     aI[kt * 4 + 0][c0], aI[kt * 4 + 1][c0], aI[kt * 4 + 2][c0], aI[kt * 4 + 3][c0]};
      short8 hi, lo;
      #pragma unroll
      for (int j = 0; j < 8; ++j) {
        unsigned short hb = bf16bits(av[j]);
        hi[j] = (short)hb;
        lo[j] = (short)bf16bits(av[j] - bfval(hb));
      }
      afh[kt][c0] = hi;
      afl[kt][c0] = lo;
    }

  f32x4 y[2][4];
  #pragma unroll
  for (int mtT = 0; mtT < 2; ++mtT) {
    short8 fh = *reinterpret_cast<const short8*>(tb + 16384 + mtT * 1024 + lane * 16);
    short8 fl = *reinterpret_cast<const short8*>(tb + 18432 + mtT * 1024 + lane * 16);
    short8 wch0 = *reinterpret_cast<const short8*>(tb + 8192 + (mtT * 2 + 0) * 1024 + lane * 16);
    short8 wcl0 = *reinterpret_cast<const short8*>(tb + 12288 + (mtT * 2 + 0) * 1024 + lane * 16);
    short8 wch1 = *reinterpret_cast<const short8*>(tb + 8192 + (mtT * 2 + 1) * 1024 + lane * 16);
    short8 wcl1 = *reinterpret_cast<const short8*>(tb + 12288 + (mtT * 2 + 1) * 1024 + lane * 16);
    #pragma unroll
    for (int c0 = 0; c0 < 4; ++c0) {
      f32x4 acc = {0.f, 0.f, 0.f, 0.f};
      acc = __builtin_amdgcn_mfma_f32_16x16x32_bf16(fh, uh[c0], acc, 0, 0, 0);
      acc = __builtin_amdgcn_mfma_f32_16x16x32_bf16(fh, ul[c0], acc, 0, 0, 0);
      acc = __builtin_amdgcn_mfma_f32_16x16x32_bf16(fl, uh[c0], acc, 0, 0, 0);
      acc = __builtin_amdgcn_mfma_f32_16x16x32_bf16(wch0, afh[0][c0], acc, 0, 0, 0);
      acc = __builtin_amdgcn_mfma_f32_16x16x32_bf16(wch0, afl[0][c0], acc, 0, 0, 0);
      acc = __builtin_amdgcn_mfma_f32_16x16x32_bf16(wcl0, afh[0][c0], acc, 0, 0, 0);
      acc = __builtin_amdgcn_mfma_f32_16x16x32_bf16(wch1, afh[1][c0], acc, 0, 0, 0);
      acc = __builtin_amdgcn_mfma_f32_16x16x32_bf16(wch1, afl[1][c0], acc, 0, 0, 0);
      acc = __builtin_amdgcn_mfma_f32_16x16x32_bf16(wcl1, afh[1][c0], acc, 0, 0, 0);
      y[mtT][c0] = acc;
    }
  }

  // epilogue: + D*u, GELU, write bf16 into ylds [l][h'] (XOR-swizzled, l>>5)
  float Dv = Dp[h];
  #pragma unroll
  for (int mtT = 0; mtT < 2; ++mtT)
    #pragma unroll
    for (int c0 = 0; c0 < 4; ++c0) {
      int eb = 512 * c0 + 32 * m + 16 * mtT + 4 * g;
      float4 uu = *reinterpret_cast<const float4*>(urow + eb);
      f32x4 vv = y[mtT][c0];
      unsigned short bv[4];
      bv[0] = bf16bits(gelu_fast(fmaf(Dv, uu.x, vv[0])));
      bv[1] = bf16bits(gelu_fast(fmaf(Dv, uu.y, vv[1])));
      bv[2] = bf16bits(gelu_fast(fmaf(Dv, uu.z, vv[2])));
      bv[3] = bf16bits(gelu_fast(fmaf(Dv, uu.w, vv[3])));
      #pragma unroll
      for (int k = 0; k < 4; ++k) {
        int l = eb + k;
        *(short*)(smem + ((l * 8 + wid * 2) ^ (((l >> 5) & 7) << 3))) = (short)bv[k];
      }
    }
  __syncthreads();
  // packed 8B stores: Ybt[(blockIdx.x * 2048 + l) * 4 + 0..3]
  #pragma unroll
  for (int i = 0; i < 8; ++i) {
    int l = t + 256 * i;
    uint2 v = *reinterpret_cast<const uint2*>(smem + ((l * 8) ^ (((l >> 5) & 7) << 3)));
    *reinterpret_cast<uint2*>(Ybt + ((size_t)blockIdx.x * 2048 + l) * 4) = v;
  }
}

// ---------------------------------------------------------------------------
// conv1x1 + GLU, bf16 MFMA 16x16x32. B fragments from h-quartet Ybt layout
// (2 x 8B loads per fragment). A (CW) staged in LDS via gload16, XOR swizzle.
// ---------------------------------------------------------------------------
__global__ __launch_bounds__(256) void k_conv(const short* __restrict__ Ybt,
                                              const __hip_bfloat16* __restrict__ CWb,
                                              const float* __restrict__ CB,
                                              float* __restrict__ U) {
  __shared__ short Alds[128 * 64];
  int lt = blockIdx.x * 128;
  int ot = blockIdx.y * 64;
  int b  = blockIdx.z;
  int t = threadIdx.x;
  int wid = t >> 6, lane = t & 63;
  int wr = wid >> 1, wc = wid & 1;
  int l15 = lane & 15, l4 = lane >> 4;
  f32x4 zero = {0.f, 0.f, 0.f, 0.f};
  f32x4 accA[2][4], accG[2][4];
  #pragma unroll
  for (int m = 0; m < 2; ++m)
    #pragma unroll
    for (int n = 0; n < 4; ++n) { accA[m][n] = zero; accG[m][n] = zero; }

  const short* Yb = Ybt + (size_t)b * 128 * 2048 * 4;
  const char* Wb = (const char*)CWb;

  for (int kt = 0; kt < HH; kt += 64) {
    #pragma unroll
    for (int it = 0; it < 4; ++it) {
      int d = 16 * (t + 256 * it);
      int rowl = d >> 7, cb = d & 127;
      int orow = (rowl < 64) ? (ot + rowl) : (448 + ot + rowl);
      gload16(Wb + (size_t)orow * 1024 + kt * 2 + (cb ^ ((rowl & 7) << 4)),
              (char*)Alds + d);
    }
    short8 bfrag[2][4];
    #pragma unroll
    for (int ks = 0; ks < 2; ++ks)
      #pragma unroll
      for (int n = 0; n < 4; ++n) {
        int l = lt + wc * 64 + n * 16 + l15;
        int octg = (kt >> 3) + ks * 4 + l4;
        const short* p0 = Yb + ((size_t)(2 * octg) * 2048 + l) * 4;
        uint2 A = *reinterpret_cast<const uint2*>(p0);
        uint2 B2 = *reinterpret_cast<const uint2*>(p0 + 8192);
        bfrag[ks][n] = __builtin_bit_cast(short8, u2x2{A, B2});
      }
    __syncthreads();
    #pragma unroll
    for (int ks = 0; ks < 2; ++ks) {
      short8 af[4];
      #pragma unroll
      for (int m = 0; m < 4; ++m) {
        int mrow = ((m < 2) ? (wr * 32 + m * 16) : (64 + wr * 32 + (m - 2) * 16)) + l15;
        int colb = (ks * 64 + 16 * l4) ^ ((mrow & 7) << 4);
        af[m] = *reinterpret_cast<const short8*>((const char*)Alds + mrow * 128 + colb);
      }
      #pragma unroll
      for (int m = 0; m < 2; ++m)
        #pragma unroll
        for (int n = 0; n < 4; ++n) {
          accA[m][n] = __builtin_amdgcn_mfma_f32_16x16x32_bf16(af[m], bfrag[ks][n], accA[m][n], 0, 0, 0);
          accG[m][n] = __builtin_amdgcn_mfma_f32_16x16x32_bf16(af[m + 2], bfrag[ks][n], accG[m][n], 0, 0, 0);
        }
    }
    __syncthreads();
  }
  #pragma unroll
  for (int m = 0; m < 2; ++m) {
    #pragma unroll
    for (int r = 0; r < 4; ++r) {
      int rowl = wr * 32 + m * 16 + l4 * 4 + r;
      float ba = CB[ot + rowl];
      float bg = CB[512 + ot + rowl];
      float* urow_ = U + ((size_t)b * HH + ot + rowl) * LL + lt + wc * 64;
      #pragma unroll
      for (int n = 0; n < 4; ++n) {
        float a = accA[m][n][r] + ba;
        float g = accG[m][n][r] + bg;
        urow_[n * 16 + l15] = a * sigmoidf_(g);
      }
    }
  }
}

// ---------------------------------------------------------------------------
// Output projection (fp32 out).
// ---------------------------------------------------------------------------
__global__ __launch_bounds__(256) void k_outgemm(const float* __restrict__ U,
                                                 const float* __restrict__ Wo,
                                                 const float* __restrict__ bo,
                                                 float* __restrict__ out) {
  int bl = blockIdx.x * 256 + threadIdx.x;
  int b = bl >> 11, l = bl & (LL - 1);
  float a0 = 0.0f, a1 = 0.0f;
  const float* up = U + (size_t)b * HH * LL + l;
  #pragma unroll 4
  for (int h = 0; h < HH; ++h) {
    float v = up[(size_t)h * LL];
    a0 = fmaf(v, Wo[h * 2 + 0], a0);
    a1 = fmaf(v, Wo[h * 2 + 1], a1);
  }
  out[(size_t)bl * 2 + 0] = a0 + bo[0];
  out[(size_t)bl * 2 + 1] = a1 + bo[1];
}

extern "C" void kernel_launch(void* const* d_in, const int* in_sizes, int n_in,
                              void* d_out, int out_size, void* d_ws, size_t ws_size,
                              hipStream_t stream) {
  const float* X      = (const float*)d_in[0];
  const float* Win    = (const float*)d_in[1];
  const float* bin    = (const float*)d_in[2];
  const float* log_dt = (const float*)d_in[3];
  const float* Cri    = (const float*)d_in[4];
  const float* lAr    = (const float*)d_in[5];
  const float* Aim    = (const float*)d_in[6];
  const float* Dp     = (const float*)d_in[7];
  const float* CW     = (const float*)d_in[8];
  const float* CB     = (const float*)d_in[9];
  const float* Wo     = (const float*)d_in[10];
  const float* bo     = (const float*)d_in[11];
  float* out = (float*)d_out;

  const size_t Pfloats   = (size_t)NNL * HH * NN2 * 4;        // 262144
  const size_t CWfloats  = (size_t)NNL * 2 * HH * HH / 2;     // 1048576
  const size_t Tabfloats = (size_t)NNL * HH * (TABB / 4);     // 16777216
  const size_t Wtfloats  = (size_t)HH * INP;                  // 98304 (hi+lo bf16)
  const size_t Xnf       = (size_t)BB * LL * INP;             // 12582912 elems
  const size_t HL        = (size_t)HH * LL;                   // 1048576

  float* P = (float*)d_ws;
  __hip_bfloat16* CWb = (__hip_bfloat16*)(P + Pfloats);
  char* Tab = (char*)(P + Pfloats + CWfloats);
  __hip_bfloat16* Wthi = (__hip_bfloat16*)(P + Pfloats + CWfloats + Tabfloats);
  __hip_bfloat16* Wtlo = Wthi + Wtfloats;
  __hip_bfloat16* Xhi  = (__hip_bfloat16*)(P + Pfloats + CWfloats + Tabfloats + Wtfloats);
  __hip_bfloat16* Xlo  = Xhi + Xnf;
  size_t head = Pfloats + CWfloats + Tabfloats + Wtfloats + Xnf;

  size_t ws_floats = ws_size / sizeof(float);
  size_t avail = (ws_floats > head) ? (ws_floats - head) : 0;
  int G = (int)(avail / (HL + HL / 2));   // U fp32 + Ybt bf16
  if (G >= 32) G = 32;
  else if (G >= 16) G = 16;
  else if (G >= 8) G = 8;
  else if (G >= 4) G = 4;
  else if (G >= 2) G = 2;
  else G = 1;

  float* U = P + head;
  short* Ybt = (short*)(U + (size_t)G * HL);

  k_params<<<(NNL * HH * NN2 + 255) / 256, 256, 0, stream>>>(log_dt, Cri, lAr, Aim, P);
  k_tables<<<NNL * HH, 64, 0, stream>>>(P, Tab);
  k_tobf16<<<(NNL * 2 * HH * HH) / 1024, 256, 0, stream>>>(CW, CWb, NNL * 2 * HH * HH);
  k_prepwt<<<(HH * INP + 255) / 256, 256, 0, stream>>>(Win, Wthi, Wtlo);
  k_splitx<<<(int)(Xnf / 1024), 256, 0, stream>>>(X, Xhi, Xlo, (int)Xnf);

  for (int b0 = 0; b0 < BB; b0 += G) {
    int g = (BB - b0 < G) ? (BB - b0) : G;
    k_ingemm<<<dim3(LL / 128, HH / 128, g), 256, 0, stream>>>(
        Xhi + (size_t)b0 * LL * INP, Xlo + (size_t)b0 * LL * INP, Wthi, Wtlo, bin, U);
    for (int layer = 0; layer < NNL; ++layer) {
      k_scan<<<g * (HH / 4), 256, 0, stream>>>(
          U, Ybt,
          Tab + (size_t)layer * HH * TABB,
          Dp + (size_t)layer * HH);
      k_conv<<<dim3(LL / 128, HH / 64, g), 256, 0, stream>>>(
          Ybt, CWb + (size_t)layer * 2 * HH * HH, CB + (size_t)layer * 2 * HH, U);
    }
    k_outgemm<<<g * LL / 256, 256, 0, stream>>>(
        U, Wo, bo, out + (size_t)b0 * LL * OUTC);
  }
}

// Round 14
// 1225.288 us; speedup vs baseline: 1.5873x; 1.5873x over previous
//
#include <hip/hip_runtime.h>
#include <hip/hip_bf16.h>
#include <math.h>

#define BB 32
#define LL 2048
#define INP 192
#define OUTC 2
#define HH 512
#define NN2 32
#define NNL 4
#define TABB 32768   // bytes of table per (layer,h)

using short8 = __attribute__((ext_vector_type(8))) short;
using f32x4  = __attribute__((ext_vector_type(4))) float;
using f32x2  = __attribute__((ext_vector_type(2))) float;

struct u2x2 { uint2 a, b; };

__device__ __forceinline__ float sigmoidf_(float x) {
  return 1.0f / (1.0f + expf(-x));
}
__device__ __forceinline__ unsigned short bf16bits(float x) {
  __hip_bfloat16 b = __float2bfloat16(x);
  return __builtin_bit_cast(unsigned short, b);
}
__device__ __forceinline__ float bfval(unsigned short b) {
  unsigned int u = (unsigned int)b << 16;
  return __builtin_bit_cast(float, u);
}
// Abramowitz-Stegun 7.1.26 erf (max err 1.5e-7) based exact-GELU
__device__ __forceinline__ float gelu_fast(float x) {
  float s = x * 0.70710678118654752f;
  float ax = fabsf(s);
  float tt = 1.0f / fmaf(0.3275911f, ax, 1.0f);
  float p = fmaf(1.061405429f, tt, -1.453152027f);
  p = fmaf(p, tt, 1.421413741f);
  p = fmaf(p, tt, -0.284496736f);
  p = fmaf(p, tt, 0.254829592f);
  float e = __expf(-s * s);
  float er = 1.0f - p * tt * e;
  er = copysignf(er, s);
  return 0.5f * x * (1.0f + er);
}
__device__ __forceinline__ void gload16(const void* gsrc, void* ldst) {
  __builtin_amdgcn_global_load_lds(
      (const __attribute__((address_space(1))) void*)gsrc,
      (__attribute__((address_space(3))) void*)ldst, 16, 0, 0);
}

// ---------------------------------------------------------------------------
// P[NL][H][N2][4] = {w_re, w_im, c2_re, c2_im}
// ---------------------------------------------------------------------------
__global__ __launch_bounds__(256) void k_params(const float* __restrict__ log_dt,
                                                const float* __restrict__ Cri,
                                                const float* __restrict__ lAr,
                                                const float* __restrict__ Aim,
                                                float* __restrict__ P) {
  int idx = blockIdx.x * 256 + threadIdx.x;
  if (idx >= NNL * HH * NN2) return;
  float dt  = expf(log_dt[idx / NN2]);
  float Are = -expf(lAr[idx]);
  float Aimv = Aim[idx];
  float dre = Are * dt, dim = Aimv * dt;
  float er = expf(dre);
  float wrv = er * cosf(dim);
  float wiv = er * sinf(dim);
  float Er = wrv - 1.0f, Ei = wiv;
  float den = Are * Are + Aimv * Aimv;
  float Fr = (Er * Are + Ei * Aimv) / den;
  float Fi = (Ei * Are - Er * Aimv) / den;
  float Cre = Cri[idx * 2 + 0], Cim = Cri[idx * 2 + 1];
  P[idx * 4 + 0] = wrv;
  P[idx * 4 + 1] = wiv;
  P[idx * 4 + 2] = 2.0f * (Cre * Fr - Cim * Fi);
  P[idx * 4 + 3] = 2.0f * (Cre * Fi + Cim * Fr);
}

// ---------------------------------------------------------------------------
// Build per-(layer,h) MFMA fragment tables (split bf16 hi/lo) + scan tables.
// Round-14: FIR tap 0 absorbs D[h] (kk[0] += Dp[lh]) so the scan's FIR MFMA
// computes D*u and the scan epilogue needs no u re-read.
// ---------------------------------------------------------------------------
__global__ __launch_bounds__(64) void k_tables(const float* __restrict__ P,
                                               const float* __restrict__ Dp,
                                               char* __restrict__ Tab) {
  __shared__ float kk[32];
  int tid = threadIdx.x;
  int lh = blockIdx.x;
  char* tb = Tab + (size_t)lh * TABB;
  if (tid < 32) {
    int n = tid;
    const float4 pq = reinterpret_cast<const float4*>(P)[(size_t)lh * NN2 + n];
    float wr = pq.x, wi = pq.y, c2r = pq.z, c2i = pq.w;
    int mt = n >> 4;
    float pr = 1.0f, pi = 0.0f;   // w^d
    for (int d = 0; d < 32; ++d) {
      {  // WA at t = 31-d
        int t_ = 31 - d;
        int lane = ((t_ >> 3) << 4) + (n & 15);
        int j = t_ & 7;
        unsigned short hr = bf16bits(pr);
        unsigned short lr = bf16bits(pr - bfval(hr));
        unsigned short hi_ = bf16bits(pi);
        unsigned short li_ = bf16bits(pi - bfval(hi_));
        *(unsigned short*)(tb + (mt * 2 + 0) * 1024 + lane * 16 + j * 2) = hr;
        *(unsigned short*)(tb + (mt * 2 + 1) * 1024 + lane * 16 + j * 2) = hi_;
        *(unsigned short*)(tb + 4096 + (mt * 2 + 0) * 1024 + lane * 16 + j * 2) = lr;
        *(unsigned short*)(tb + 4096 + (mt * 2 + 1) * 1024 + lane * 16 + j * 2) = li_;
      }
      {  // WC at t = d
        int mtT = d >> 4;
        int lane = (((n & 15) >> 2) << 4) + (d & 15);
        int jre = n & 3, jim = (n & 3) + 4;
        unsigned short hr = bf16bits(pr);
        unsigned short lr = bf16bits(pr - bfval(hr));
        float nim = -pi;
        unsigned short hi_ = bf16bits(nim);
        unsigned short li_ = bf16bits(nim - bfval(hi_));
        char* bh = tb + 8192 + (mtT * 2 + mt) * 1024 + lane * 16;
        char* bl = tb + 12288 + (mtT * 2 + mt) * 1024 + lane * 16;
        *(unsigned short*)(bh + jre * 2) = hr;
        *(unsigned short*)(bh + jim * 2) = hi_;
        *(unsigned short*)(bl + jre * 2) = lr;
        *(unsigned short*)(bl + jim * 2) = li_;
      }
      float kp = c2r * pr - c2i * pi;
      #pragma unroll
      for (int k = 1; k < 32; k <<= 1) kp += __shfl_xor(kp, k, 32);
      if (n == 0) kk[d] = (d == 0) ? (kp + Dp[lh]) : kp;
      float nr = pr * wr - pi * wi;
      pi = pr * wi + pi * wr;
      pr = nr;
    }
    float w32r = pr, w32i = pi;
    float c2wr = c2r * wr - c2i * wi;
    float c2wi = c2r * wi + c2i * wr;
    int s = ((n >> 4) << 2) + (n & 3);
    int gg = (n & 15) >> 2;
    float pmr = 1.0f, pmi = 0.0f;   // w32^m
    for (int m = 0; m < 16; ++m) {
      float* q = (float*)(tb + 20480 + (size_t)((s * 64) + (gg * 16 + m)) * 24);
      q[0] = w32r; q[1] = w32i; q[2] = pmr; q[3] = pmi; q[4] = c2wr; q[5] = c2wi;
      float t2 = pmr * w32r - pmi * w32i;
      pmi = pmr * w32i + pmi * w32r;
      pmr = t2;
    }
  }
  __syncthreads();
  for (int idx = tid; idx < 1024; idx += 64) {
    int mt = idx >> 9, rem = idx & 511;
    int lane = rem >> 3, j = rem & 7;
    int tt = (mt << 4) + (lane & 15);
    int jf = ((lane >> 4) << 3) + j;
    float val = (jf <= tt) ? kk[tt - jf] : 0.0f;
    unsigned short hb = bf16bits(val);
    unsigned short lb = bf16bits(val - bfval(hb));
    *(unsigned short*)(tb + 16384 + mt * 1024 + lane * 16 + j * 2) = hb;
    *(unsigned short*)(tb + 18432 + mt * 1024 + lane * 16 + j * 2) = lb;
  }
}

// ---------------------------------------------------------------------------
// fp32 -> bf16 convert (CW weights).
// ---------------------------------------------------------------------------
__global__ __launch_bounds__(256) void k_tobf16(const float* __restrict__ src,
                                                __hip_bfloat16* __restrict__ dst,
                                                int n) {
  int i = (blockIdx.x * 256 + threadIdx.x) * 4;
  if (i >= n) return;
  float4 v = *reinterpret_cast<const float4*>(&src[i]);
  dst[i + 0] = __float2bfloat16(v.x);
  dst[i + 1] = __float2bfloat16(v.y);
  dst[i + 2] = __float2bfloat16(v.z);
  dst[i + 3] = __float2bfloat16(v.w);
}

// ---------------------------------------------------------------------------
// Split X fp32 -> Xhi/Xlo bf16 planes (same [b][l][k] layout).
// ---------------------------------------------------------------------------
__global__ __launch_bounds__(256) void k_splitx(const float* __restrict__ src,
                                                __hip_bfloat16* __restrict__ hi,
                                                __hip_bfloat16* __restrict__ lo,
                                                int n) {
  int i = (blockIdx.x * 256 + threadIdx.x) * 4;
  if (i >= n) return;
  float4 v = *reinterpret_cast<const float4*>(&src[i]);
  float vv[4] = {v.x, v.y, v.z, v.w};
  unsigned short hb[4], lb[4];
  #pragma unroll
  for (int j = 0; j < 4; ++j) {
    hb[j] = bf16bits(vv[j]);
    lb[j] = bf16bits(vv[j] - bfval(hb[j]));
  }
  *reinterpret_cast<uint2*>(hi + i) = make_uint2(
      (unsigned)hb[0] | ((unsigned)hb[1] << 16), (unsigned)hb[2] | ((unsigned)hb[3] << 16));
  *reinterpret_cast<uint2*>(lo + i) = make_uint2(
      (unsigned)lb[0] | ((unsigned)lb[1] << 16), (unsigned)lb[2] | ((unsigned)lb[3] << 16));
}

// ---------------------------------------------------------------------------
// W[k][h] fp32 -> Wt hi/lo bf16 [h][k] (transposed, split). One-time, tiny.
// ---------------------------------------------------------------------------
__global__ __launch_bounds__(256) void k_prepwt(const float* __restrict__ W,
                                                __hip_bfloat16* __restrict__ hi,
                                                __hip_bfloat16* __restrict__ lo) {
  int idx = blockIdx.x * 256 + threadIdx.x;   // h*INP + k
  if (idx >= HH * INP) return;
  int h = idx / INP, k = idx - h * INP;
  float v = W[(size_t)k * HH + h];
  unsigned short hb = bf16bits(v);
  hi[idx] = __builtin_bit_cast(__hip_bfloat16, hb);
  lo[idx] = __float2bfloat16(v - bfval(hb));
}

// ---------------------------------------------------------------------------
// Input GEMM, bf16 MFMA split. Round-14: writes U as bf16 hi/lo planes
// (Uhi/Ulo, [b][h][l]) so the scan consumes fragments with no conversion.
// ---------------------------------------------------------------------------
__global__ __launch_bounds__(256) void k_ingemm(const __hip_bfloat16* __restrict__ Xhi,
                                                const __hip_bfloat16* __restrict__ Xlo,
                                                const __hip_bfloat16* __restrict__ Wthi,
                                                const __hip_bfloat16* __restrict__ Wtlo,
                                                const float* __restrict__ bias,
                                                short* __restrict__ Uhi,
                                                short* __restrict__ Ulo) {
  int lt = blockIdx.x * 128;
  int ht = blockIdx.y * 128;
  int b  = blockIdx.z;
  int t = threadIdx.x;
  int wid = t >> 6, lane = t & 63;
  int wrow = wid >> 1, wcol = wid & 1;
  int l15 = lane & 15, g = lane >> 4;

  const short* Xh = (const short*)Xhi + (size_t)b * LL * INP;
  const short* Xl = (const short*)Xlo + (size_t)b * LL * INP;
  const short* Bh = (const short*)Wthi;
  const short* Bl = (const short*)Wtlo;

  f32x4 acc[4][4];
  #pragma unroll
  for (int m = 0; m < 4; ++m)
    #pragma unroll
    for (int n = 0; n < 4; ++n) acc[m][n] = f32x4{0.f, 0.f, 0.f, 0.f};

  int lbase = lt + wrow * 64 + l15;
  int hbase = ht + wcol * 64 + l15;

  #pragma unroll
  for (int ks = 0; ks < 6; ++ks) {
    int k0 = ks * 32 + 8 * g;
    short8 ah[4], al[4], bh[4], bl[4];
    #pragma unroll
    for (int m = 0; m < 4; ++m) {
      size_t off = (size_t)(lbase + m * 16) * INP + k0;
      ah[m] = *reinterpret_cast<const short8*>(Xh + off);
      al[m] = *reinterpret_cast<const short8*>(Xl + off);
    }
    #pragma unroll
    for (int n = 0; n < 4; ++n) {
      size_t off = (size_t)(hbase + n * 16) * INP + k0;
      bh[n] = *reinterpret_cast<const short8*>(Bh + off);
      bl[n] = *reinterpret_cast<const short8*>(Bl + off);
    }
    #pragma unroll
    for (int m = 0; m < 4; ++m)
      #pragma unroll
      for (int n = 0; n < 4; ++n) {
        acc[m][n] = __builtin_amdgcn_mfma_f32_16x16x32_bf16(ah[m], bh[n], acc[m][n], 0, 0, 0);
        acc[m][n] = __builtin_amdgcn_mfma_f32_16x16x32_bf16(ah[m], bl[n], acc[m][n], 0, 0, 0);
        acc[m][n] = __builtin_amdgcn_mfma_f32_16x16x32_bf16(al[m], bh[n], acc[m][n], 0, 0, 0);
      }
  }

  #pragma unroll
  for (int n = 0; n < 4; ++n) {
    int h = hbase + n * 16;
    float bv = bias[h];
    size_t rowoff = ((size_t)b * HH + h) * LL;
    #pragma unroll
    for (int m = 0; m < 4; ++m) {
      int l0 = lt + wrow * 64 + m * 16 + g * 4;
      unsigned short hb[4], lb[4];
      #pragma unroll
      for (int k = 0; k < 4; ++k) {
        float v = acc[m][n][k] + bv;
        hb[k] = bf16bits(v);
        lb[k] = bf16bits(v - bfval(hb[k]));
      }
      *reinterpret_cast<uint2*>(Uhi + rowoff + l0) = make_uint2(
          (unsigned)hb[0] | ((unsigned)hb[1] << 16), (unsigned)hb[2] | ((unsigned)hb[3] << 16));
      *reinterpret_cast<uint2*>(Ulo + rowoff + l0) = make_uint2(
          (unsigned)lb[0] | ((unsigned)lb[1] << 16), (unsigned)lb[2] | ((unsigned)lb[3] << 16));
    }
  }
}

// ---------------------------------------------------------------------------
// MFMA chunk-parallel S4D scan, round 14: free register allocation (no
// forced bound -- rounds 11/13 proved any min-waves hint spills). Inputs are
// pre-split bf16 planes (no in-kernel split); D*u folded into FIR tap 0
// (no u re-read; epilogue is gelu+pack only). Epilogue swizzle (l>>5)&7.
// Output: Ybt[b][h>>2][l][h&3] bf16 via 16 KB LDS transpose.
// ---------------------------------------------------------------------------
__global__ __launch_bounds__(256) void k_scan(const short* __restrict__ Uhi,
                                              const short* __restrict__ Ulo,
                                              short* __restrict__ Ybt,
                                              const char* __restrict__ Tab) {
  __shared__ __align__(16) char smem[16384];  // ylds [l][h'4], XOR-swizzled
  int t = threadIdx.x;
  int lane = t & 63;
  int wid = t >> 6;                              // 0..3 = h'
  int row = __builtin_amdgcn_readfirstlane(blockIdx.x * 4 + wid);
  int h = row & (HH - 1);
  const char* tb = Tab + (size_t)h * TABB;
  const short* uhrow = Uhi + (size_t)row * LL;
  const short* ulrow = Ulo + (size_t)row * LL;
  int g = lane >> 4, m = lane & 15;

  short8 uh[4], ul[4];
  #pragma unroll
  for (int c0 = 0; c0 < 4; ++c0) {
    int off = 512 * c0 + 32 * m + 8 * g;
    uh[c0] = *reinterpret_cast<const short8*>(uhrow + off);
    ul[c0] = *reinterpret_cast<const short8*>(ulrow + off);
  }

  f32x4 Z[2][2][4];
  #pragma unroll
  for (int mt = 0; mt < 2; ++mt)
    #pragma unroll
    for (int reim = 0; reim < 2; ++reim) {
      short8 whi = *reinterpret_cast<const short8*>(tb + (mt * 2 + reim) * 1024 + lane * 16);
      short8 wlo = *reinterpret_cast<const short8*>(tb + 4096 + (mt * 2 + reim) * 1024 + lane * 16);
      #pragma unroll
      for (int c0 = 0; c0 < 4; ++c0) {
        f32x4 z = {0.f, 0.f, 0.f, 0.f};
        z = __builtin_amdgcn_mfma_f32_16x16x32_bf16(whi, uh[c0], z, 0, 0, 0);
        z = __builtin_amdgcn_mfma_f32_16x16x32_bf16(whi, ul[c0], z, 0, 0, 0);
        z = __builtin_amdgcn_mfma_f32_16x16x32_bf16(wlo, uh[c0], z, 0, 0, 0);
        Z[mt][reim][c0] = z;
      }
    }

  float aR[8][4], aI[8][4];
  #pragma unroll
  for (int s = 0; s < 8; ++s) {
    int mt = s >> 2, i = s & 3;
    const char* plb = tb + 20480 + (size_t)(s * 64 + lane) * 24;
    f32x2 w32 = *reinterpret_cast<const f32x2*>(plb);
    f32x2 w32m = *reinterpret_cast<const f32x2*>(plb + 8);
    f32x2 c2w = *reinterpret_cast<const f32x2*>(plb + 16);
    float r1r = w32[0], r1i = w32[1];
    float r2r = r1r * r1r - r1i * r1i, r2i = 2.f * r1r * r1i;
    float r4r = r2r * r2r - r2i * r2i, r4i = 2.f * r2r * r2i;
    float r8r = r4r * r4r - r4i * r4i, r8i = 2.f * r4r * r4i;
    float w16r = r8r * r8r - r8i * r8i, w16i = 2.f * r8r * r8i;  // w32^16

    float Er[4], Ei[4], Tr[4], Ti[4];
    #pragma unroll
    for (int c0 = 0; c0 < 4; ++c0) {
      float Pr = Z[mt][0][c0][i], Pi = Z[mt][1][c0][i];
      {
        float qr = __shfl_up(Pr, 1u, 16), qi = __shfl_up(Pi, 1u, 16);
        if (m < 1) { qr = 0.f; qi = 0.f; }
        Pr = fmaf(r1r, qr, fmaf(-r1i, qi, Pr));
        Pi = fmaf(r1r, qi, fmaf(r1i, qr, Pi));
      }
      {
        float qr = __shfl_up(Pr, 2u, 16), qi = __shfl_up(Pi, 2u, 16);
        if (m < 2) { qr = 0.f; qi = 0.f; }
        Pr = fmaf(r2r, qr, fmaf(-r2i, qi, Pr));
        Pi = fmaf(r2r, qi, fmaf(r2i, qr, Pi));
      }
      {
        float qr = __shfl_up(Pr, 4u, 16), qi = __shfl_up(Pi, 4u, 16);
        if (m < 4) { qr = 0.f; qi = 0.f; }
        Pr = fmaf(r4r, qr, fmaf(-r4i, qi, Pr));
        Pi = fmaf(r4r, qi, fmaf(r4i, qr, Pi));
      }
      {
        float qr = __shfl_up(Pr, 8u, 16), qi = __shfl_up(Pi, 8u, 16);
        if (m < 8) { qr = 0.f; qi = 0.f; }
        Pr = fmaf(r8r, qr, fmaf(-r8i, qi, Pr));
        Pi = fmaf(r8r, qi, fmaf(r8i, qr, Pi));
      }
      float eqr = __shfl_up(Pr, 1u, 16), eqi = __shfl_up(Pi, 1u, 16);
      if (m == 0) { eqr = 0.f; eqi = 0.f; }
      Er[c0] = eqr; Ei[c0] = eqi;
      Tr[c0] = __shfl(Pr, 15, 16);
      Ti[c0] = __shfl(Pi, 15, 16);
    }
    float C1r = Tr[0], C1i = Ti[0];
    float C2r = fmaf(w16r, C1r, fmaf(-w16i, C1i, Tr[1]));
    float C2i = fmaf(w16r, C1i, fmaf(w16i, C1r, Ti[1]));
    float C3r = fmaf(w16r, C2r, fmaf(-w16i, C2i, Tr[2]));
    float C3i = fmaf(w16r, C2i, fmaf(w16i, C2r, Ti[2]));
    float Cr[4] = {0.f, C1r, C2r, C3r};
    float Ci[4] = {0.f, C1i, C2i, C3i};
    #pragma unroll
    for (int c0 = 0; c0 < 4; ++c0) {
      float Erc = fmaf(w32m[0], Cr[c0], fmaf(-w32m[1], Ci[c0], Er[c0]));
      float Eic = fmaf(w32m[0], Ci[c0], fmaf(w32m[1], Cr[c0], Ei[c0]));
      aR[s][c0] = c2w[0] * Erc - c2w[1] * Eic;
      aI[s][c0] = c2w[0] * Eic + c2w[1] * Erc;
    }
  }

  short8 afh[2][4], afl[2][4];
  #pragma unroll
  for (int kt = 0; kt < 2; ++kt)
    #pragma unroll
    for (int c0 = 0; c0 < 4; ++c0) {
      float av[8] = {aR[kt * 4 + 0][c0], aR[kt * 4 + 1][c0], aR[kt * 4 + 2][c0], aR[kt * 4 + 3][c0],
                     aI[kt * 4 + 0][c0], aI[kt * 4 + 1][c0], aI[kt * 4 + 2][c0], aI[kt * 4 + 3][c0]};
      short8 hi, lo;
      #pragma unroll
      for (int j = 0; j < 8; ++j) {
        unsigned short hb = bf16bits(av[j]);
        hi[j] = (short)hb;
        lo[j] = (short)bf16bits(av[j] - bfval(hb));
      }
      afh[kt][c0] = hi;
      afl[kt][c0] = lo;
    }

  f32x4 y[2][4];
  #pragma unroll
  for (int mtT = 0; mtT < 2; ++mtT) {
    short8 fh = *reinterpret_cast<const short8*>(tb + 16384 + mtT * 1024 + lane * 16);
    short8 fl = *reinterpret_cast<const short8*>(tb + 18432 + mtT * 1024 + lane * 16);
    short8 wch0 = *reinterpret_cast<const short8*>(tb + 8192 + (mtT * 2 + 0) * 1024 + lane * 16);
    short8 wcl0 = *reinterpret_cast<const short8*>(tb + 12288 + (mtT * 2 + 0) * 1024 + lane * 16);
    short8 wch1 = *reinterpret_cast<const short8*>(tb + 8192 + (mtT * 2 + 1) * 1024 + lane * 16);
    short8 wcl1 = *reinterpret_cast<const short8*>(tb + 12288 + (mtT * 2 + 1) * 1024 + lane * 16);
    #pragma unroll
    for (int c0 = 0; c0 < 4; ++c0) {
      f32x4 acc = {0.f, 0.f, 0.f, 0.f};
      acc = __builtin_amdgcn_mfma_f32_16x16x32_bf16(fh, uh[c0], acc, 0, 0, 0);
      acc = __builtin_amdgcn_mfma_f32_16x16x32_bf16(fh, ul[c0], acc, 0, 0, 0);
      acc = __builtin_amdgcn_mfma_f32_16x16x32_bf16(fl, uh[c0], acc, 0, 0, 0);
      acc = __builtin_amdgcn_mfma_f32_16x16x32_bf16(wch0, afh[0][c0], acc, 0, 0, 0);
      acc = __builtin_amdgcn_mfma_f32_16x16x32_bf16(wch0, afl[0][c0], acc, 0, 0, 0);
      acc = __builtin_amdgcn_mfma_f32_16x16x32_bf16(wcl0, afh[0][c0], acc, 0, 0, 0);
      acc = __builtin_amdgcn_mfma_f32_16x16x32_bf16(wch1, afh[1][c0], acc, 0, 0, 0);
      acc = __builtin_amdgcn_mfma_f32_16x16x32_bf16(wch1, afl[1][c0], acc, 0, 0, 0);
      acc = __builtin_amdgcn_mfma_f32_16x16x32_bf16(wcl1, afh[1][c0], acc, 0, 0, 0);
      y[mtT][c0] = acc;
    }
  }

  // epilogue: GELU (D*u already in y via FIR tap 0), pack, LDS transpose
  #pragma unroll
  for (int mtT = 0; mtT < 2; ++mtT)
    #pragma unroll
    for (int c0 = 0; c0 < 4; ++c0) {
      int eb = 512 * c0 + 32 * m + 16 * mtT + 4 * g;
      f32x4 vv = y[mtT][c0];
      unsigned short bv[4];
      bv[0] = bf16bits(gelu_fast(vv[0]));
      bv[1] = bf16bits(gelu_fast(vv[1]));
      bv[2] = bf16bits(gelu_fast(vv[2]));
      bv[3] = bf16bits(gelu_fast(vv[3]));
      #pragma unroll
      for (int k = 0; k < 4; ++k) {
        int l = eb + k;
        *(short*)(smem + ((l * 8 + wid * 2) ^ (((l >> 5) & 7) << 3))) = (short)bv[k];
      }
    }
  __syncthreads();
  // packed 8B stores: Ybt[(blockIdx.x * 2048 + l) * 4 + 0..3]
  #pragma unroll
  for (int i = 0; i < 8; ++i) {
    int l = t + 256 * i;
    uint2 v = *reinterpret_cast<const uint2*>(smem + ((l * 8) ^ (((l >> 5) & 7) << 3)));
    *reinterpret_cast<uint2*>(Ybt + ((size_t)blockIdx.x * 2048 + l) * 4) = v;
  }
}

// ---------------------------------------------------------------------------
// conv1x1 + GLU, bf16 MFMA 16x16x32. B fragments from h-quartet Ybt layout;
// A (CW) staged in LDS via gload16, XOR swizzle. Round-14: writes Uhi/Ulo
// bf16 planes.
// ---------------------------------------------------------------------------
__global__ __launch_bounds__(256) void k_conv(const short* __restrict__ Ybt,
                                              const __hip_bfloat16* __restrict__ CWb,
                                              const float* __restrict__ CB,
                                              short* __restrict__ Uhi,
                                              short* __restrict__ Ulo) {
  __shared__ short Alds[128 * 64];
  int lt = blockIdx.x * 128;
  int ot = blockIdx.y * 64;
  int b  = blockIdx.z;
  int t = threadIdx.x;
  int wid = t >> 6, lane = t & 63;
  int wr = wid >> 1, wc = wid & 1;
  int l15 = lane & 15, l4 = lane >> 4;
  f32x4 zero = {0.f, 0.f, 0.f, 0.f};
  f32x4 accA[2][4], accG[2][4];
  #pragma unroll
  for (int m = 0; m < 2; ++m)
    #pragma unroll
    for (int n = 0; n < 4; ++n) { accA[m][n] = zero; accG[m][n] = zero; }

  const short* Yb = Ybt + (size_t)b * 128 * 2048 * 4;
  const char* Wb = (const char*)CWb;

  for (int kt = 0; kt < HH; kt += 64) {
    #pragma unroll
    for (int it = 0; it < 4; ++it) {
      int d = 16 * (t + 256 * it);
      int rowl = d >> 7, cb = d & 127;
      int orow = (rowl < 64) ? (ot + rowl) : (448 + ot + rowl);
      gload16(Wb + (size_t)orow * 1024 + kt * 2 + (cb ^ ((rowl & 7) << 4)),
              (char*)Alds + d);
    }
    short8 bfrag[2][4];
    #pragma unroll
    for (int ks = 0; ks < 2; ++ks)
      #pragma unroll
      for (int n = 0; n < 4; ++n) {
        int l = lt + wc * 64 + n * 16 + l15;
        int octg = (kt >> 3) + ks * 4 + l4;
        const short* p0 = Yb + ((size_t)(2 * octg) * 2048 + l) * 4;
        uint2 A = *reinterpret_cast<const uint2*>(p0);
        uint2 B2 = *reinterpret_cast<const uint2*>(p0 + 8192);
        bfrag[ks][n] = __builtin_bit_cast(short8, u2x2{A, B2});
      }
    __syncthreads();
    #pragma unroll
    for (int ks = 0; ks < 2; ++ks) {
      short8 af[4];
      #pragma unroll
      for (int m = 0; m < 4; ++m) {
        int mrow = ((m < 2) ? (wr * 32 + m * 16) : (64 + wr * 32 + (m - 2) * 16)) + l15;
        int colb = (ks * 64 + 16 * l4) ^ ((mrow & 7) << 4);
        af[m] = *reinterpret_cast<const short8*>((const char*)Alds + mrow * 128 + colb);
      }
      #pragma unroll
      for (int m = 0; m < 2; ++m)
        #pragma unroll
        for (int n = 0; n < 4; ++n) {
          accA[m][n] = __builtin_amdgcn_mfma_f32_16x16x32_bf16(af[m], bfrag[ks][n], accA[m][n], 0, 0, 0);
          accG[m][n] = __builtin_amdgcn_mfma_f32_16x16x32_bf16(af[m + 2], bfrag[ks][n], accG[m][n], 0, 0, 0);
        }
    }
    __syncthreads();
  }
  #pragma unroll
  for (int m = 0; m < 2; ++m) {
    #pragma unroll
    for (int r = 0; r < 4; ++r) {
      int rowl = wr * 32 + m * 16 + l4 * 4 + r;
      float ba = CB[ot + rowl];
      float bg = CB[512 + ot + rowl];
      size_t rowoff = ((size_t)b * HH + ot + rowl) * LL + lt + wc * 64;
      #pragma unroll
      for (int n = 0; n < 4; ++n) {
        float a = accA[m][n][r] + ba;
        float gg = accG[m][n][r] + bg;
        float v = a * sigmoidf_(gg);
        unsigned short hb = bf16bits(v);
        Uhi[rowoff + n * 16 + l15] = (short)hb;
        Ulo[rowoff + n * 16 + l15] = (short)bf16bits(v - bfval(hb));
      }
    }
  }
}

// ---------------------------------------------------------------------------
// Output projection (fp32 out); reads hi/lo planes, u = hi + lo.
// ---------------------------------------------------------------------------
__global__ __launch_bounds__(256) void k_outgemm(const short* __restrict__ Uhi,
                                                 const short* __restrict__ Ulo,
                                                 const float* __restrict__ Wo,
                                                 const float* __restrict__ bo,
                                                 float* __restrict__ out) {
  int bl = blockIdx.x * 256 + threadIdx.x;
  int b = bl >> 11, l = bl & (LL - 1);
  float a0 = 0.0f, a1 = 0.0f;
  const short* hp = Uhi + (size_t)b * HH * LL + l;
  const short* lp = Ulo + (size_t)b * HH * LL + l;
  #pragma unroll 4
  for (int h = 0; h < HH; ++h) {
    float v = bfval((unsigned short)hp[(size_t)h * LL]) +
              bfval((unsigned short)lp[(size_t)h * LL]);
    a0 = fmaf(v, Wo[h * 2 + 0], a0);
    a1 = fmaf(v, Wo[h * 2 + 1], a1);
  }
  out[(size_t)bl * 2 + 0] = a0 + bo[0];
  out[(size_t)bl * 2 + 1] = a1 + bo[1];
}

extern "C" void kernel_launch(void* const* d_in, const int* in_sizes, int n_in,
                              void* d_out, int out_size, void* d_ws, size_t ws_size,
                              hipStream_t stream) {
  const float* X      = (const float*)d_in[0];
  const float* Win    = (const float*)d_in[1];
  const float* bin    = (const float*)d_in[2];
  const float* log_dt = (const float*)d_in[3];
  const float* Cri    = (const float*)d_in[4];
  const float* lAr    = (const float*)d_in[5];
  const float* Aim    = (const float*)d_in[6];
  const float* Dp     = (const float*)d_in[7];
  const float* CW     = (const float*)d_in[8];
  const float* CB     = (const float*)d_in[9];
  const float* Wo     = (const float*)d_in[10];
  const float* bo     = (const float*)d_in[11];
  float* out = (float*)d_out;

  const size_t Pfloats   = (size_t)NNL * HH * NN2 * 4;        // 262144
  const size_t CWfloats  = (size_t)NNL * 2 * HH * HH / 2;     // 1048576
  const size_t Tabfloats = (size_t)NNL * HH * (TABB / 4);     // 16777216
  const size_t Wtfloats  = (size_t)HH * INP;                  // 98304 (hi+lo bf16)
  const size_t Xnf       = (size_t)BB * LL * INP;             // 12582912 elems
  const size_t HL        = (size_t)HH * LL;                   // 1048576

  float* P = (float*)d_ws;
  __hip_bfloat16* CWb = (__hip_bfloat16*)(P + Pfloats);
  char* Tab = (char*)(P + Pfloats + CWfloats);
  __hip_bfloat16* Wthi = (__hip_bfloat16*)(P + Pfloats + CWfloats + Tabfloats);
  __hip_bfloat16* Wtlo = Wthi + Wtfloats;
  __hip_bfloat16* Xhi  = (__hip_bfloat16*)(P + Pfloats + CWfloats + Tabfloats + Wtfloats);
  __hip_bfloat16* Xlo  = Xhi + Xnf;
  size_t head = Pfloats + CWfloats + Tabfloats + Wtfloats + Xnf;

  size_t ws_floats = ws_size / sizeof(float);
  size_t avail = (ws_floats > head) ? (ws_floats - head) : 0;
  // per-batch: Uhi+Ulo = HL shorts each (HL floats total) + Ybt HL shorts (HL/2 floats)
  int G = (int)(avail / (HL + HL / 2));
  if (G >= 32) G = 32;
  else if (G >= 16) G = 16;
  else if (G >= 8) G = 8;
  else if (G >= 4) G = 4;
  else if (G >= 2) G = 2;
  else G = 1;

  short* Uhi = (short*)(P + head);
  short* Ulo = Uhi + (size_t)G * HL;
  short* Ybt = Ulo + (size_t)G * HL;

  k_params<<<(NNL * HH * NN2 + 255) / 256, 256, 0, stream>>>(log_dt, Cri, lAr, Aim, P);
  k_tables<<<NNL * HH, 64, 0, stream>>>(P, Dp, Tab);
  k_tobf16<<<(NNL * 2 * HH * HH) / 1024, 256, 0, stream>>>(CW, CWb, NNL * 2 * HH * HH);
  k_prepwt<<<(HH * INP + 255) / 256, 256, 0, stream>>>(Win, Wthi, Wtlo);
  k_splitx<<<(int)(Xnf / 1024), 256, 0, stream>>>(X, Xhi, Xlo, (int)Xnf);

  for (int b0 = 0; b0 < BB; b0 += G) {
    int g = (BB - b0 < G) ? (BB - b0) : G;
    k_ingemm<<<dim3(LL / 128, HH / 128, g), 256, 0, stream>>>(
        Xhi + (size_t)b0 * LL * INP, Xlo + (size_t)b0 * LL * INP, Wthi, Wtlo, bin,
        Uhi, Ulo);
    for (int layer = 0; layer < NNL; ++layer) {
      k_scan<<<g * (HH / 4), 256, 0, stream>>>(
          Uhi, Ulo, Ybt, Tab + (size_t)layer * HH * TABB);
      k_conv<<<dim3(LL / 128, HH / 64, g), 256, 0, stream>>>(
          Ybt, CWb + (size_t)layer * 2 * HH * HH, CB + (size_t)layer * 2 * HH,
          Uhi, Ulo);
    }
    k_outgemm<<<g * LL / 256, 256, 0, stream>>>(
        Uhi, Ulo, Wo, bo, out + (size_t)b0 * LL * OUTC);
  }
}

// Round 15
// 1218.773 us; speedup vs baseline: 1.5958x; 1.0053x over previous
//
#include <hip/hip_runtime.h>
#include <hip/hip_bf16.h>
#include <math.h>

#define BB 32
#define LL 2048
#define INP 192
#define OUTC 2
#define HH 512
#define NN2 32
#define NNL 4
#define TABB 32768   // bytes of table per (layer,h)

using short8 = __attribute__((ext_vector_type(8))) short;
using f32x4  = __attribute__((ext_vector_type(4))) float;
using f32x2  = __attribute__((ext_vector_type(2))) float;

struct u2x2 { uint2 a, b; };

__device__ __forceinline__ float sigmoidf_(float x) {
  return 1.0f / (1.0f + expf(-x));
}
__device__ __forceinline__ unsigned short bf16bits(float x) {
  __hip_bfloat16 b = __float2bfloat16(x);
  return __builtin_bit_cast(unsigned short, b);
}
__device__ __forceinline__ float bfval(unsigned short b) {
  unsigned int u = (unsigned int)b << 16;
  return __builtin_bit_cast(float, u);
}
// pack split-bf16 (hi<<16)|lo from fp32
__device__ __forceinline__ unsigned packsplit(float v) {
  unsigned short hb = bf16bits(v);
  unsigned short lb = bf16bits(v - bfval(hb));
  return ((unsigned)hb << 16) | (unsigned)lb;
}
// Abramowitz-Stegun 7.1.26 erf (max err 1.5e-7) based exact-GELU
__device__ __forceinline__ float gelu_fast(float x) {
  float s = x * 0.70710678118654752f;
  float ax = fabsf(s);
  float tt = 1.0f / fmaf(0.3275911f, ax, 1.0f);
  float p = fmaf(1.061405429f, tt, -1.453152027f);
  p = fmaf(p, tt, 1.421413741f);
  p = fmaf(p, tt, -0.284496736f);
  p = fmaf(p, tt, 0.254829592f);
  float e = __expf(-s * s);
  float er = 1.0f - p * tt * e;
  er = copysignf(er, s);
  return 0.5f * x * (1.0f + er);
}
__device__ __forceinline__ void gload16(const void* gsrc, void* ldst) {
  __builtin_amdgcn_global_load_lds(
      (const __attribute__((address_space(1))) void*)gsrc,
      (__attribute__((address_space(3))) void*)ldst, 16, 0, 0);
}

// ---------------------------------------------------------------------------
// P[NL][H][N2][4] = {w_re, w_im, c2_re, c2_im}
// ---------------------------------------------------------------------------
__global__ __launch_bounds__(256) void k_params(const float* __restrict__ log_dt,
                                                const float* __restrict__ Cri,
                                                const float* __restrict__ lAr,
                                                const float* __restrict__ Aim,
                                                float* __restrict__ P) {
  int idx = blockIdx.x * 256 + threadIdx.x;
  if (idx >= NNL * HH * NN2) return;
  float dt  = expf(log_dt[idx / NN2]);
  float Are = -expf(lAr[idx]);
  float Aimv = Aim[idx];
  float dre = Are * dt, dim = Aimv * dt;
  float er = expf(dre);
  float wrv = er * cosf(dim);
  float wiv = er * sinf(dim);
  float Er = wrv - 1.0f, Ei = wiv;
  float den = Are * Are + Aimv * Aimv;
  float Fr = (Er * Are + Ei * Aimv) / den;
  float Fi = (Ei * Are - Er * Aimv) / den;
  float Cre = Cri[idx * 2 + 0], Cim = Cri[idx * 2 + 1];
  P[idx * 4 + 0] = wrv;
  P[idx * 4 + 1] = wiv;
  P[idx * 4 + 2] = 2.0f * (Cre * Fr - Cim * Fi);
  P[idx * 4 + 3] = 2.0f * (Cre * Fi + Cim * Fr);
}

// ---------------------------------------------------------------------------
// Build per-(layer,h) MFMA fragment tables (split bf16 hi/lo) + scan tables.
// FIR tap 0 absorbs D[h].
// ---------------------------------------------------------------------------
__global__ __launch_bounds__(64) void k_tables(const float* __restrict__ P,
                                               const float* __restrict__ Dp,
                                               char* __restrict__ Tab) {
  __shared__ float kk[32];
  int tid = threadIdx.x;
  int lh = blockIdx.x;
  char* tb = Tab + (size_t)lh * TABB;
  if (tid < 32) {
    int n = tid;
    const float4 pq = reinterpret_cast<const float4*>(P)[(size_t)lh * NN2 + n];
    float wr = pq.x, wi = pq.y, c2r = pq.z, c2i = pq.w;
    int mt = n >> 4;
    float pr = 1.0f, pi = 0.0f;   // w^d
    for (int d = 0; d < 32; ++d) {
      {  // WA at t = 31-d
        int t_ = 31 - d;
        int lane = ((t_ >> 3) << 4) + (n & 15);
        int j = t_ & 7;
        unsigned short hr = bf16bits(pr);
        unsigned short lr = bf16bits(pr - bfval(hr));
        unsigned short hi_ = bf16bits(pi);
        unsigned short li_ = bf16bits(pi - bfval(hi_));
        *(unsigned short*)(tb + (mt * 2 + 0) * 1024 + lane * 16 + j * 2) = hr;
        *(unsigned short*)(tb + (mt * 2 + 1) * 1024 + lane * 16 + j * 2) = hi_;
        *(unsigned short*)(tb + 4096 + (mt * 2 + 0) * 1024 + lane * 16 + j * 2) = lr;
        *(unsigned short*)(tb + 4096 + (mt * 2 + 1) * 1024 + lane * 16 + j * 2) = li_;
      }
      {  // WC at t = d
        int mtT = d >> 4;
        int lane = (((n & 15) >> 2) << 4) + (d & 15);
        int jre = n & 3, jim = (n & 3) + 4;
        unsigned short hr = bf16bits(pr);
        unsigned short lr = bf16bits(pr - bfval(hr));
        float nim = -pi;
        unsigned short hi_ = bf16bits(nim);
        unsigned short li_ = bf16bits(nim - bfval(hi_));
        char* bh = tb + 8192 + (mtT * 2 + mt) * 1024 + lane * 16;
        char* bl = tb + 12288 + (mtT * 2 + mt) * 1024 + lane * 16;
        *(unsigned short*)(bh + jre * 2) = hr;
        *(unsigned short*)(bh + jim * 2) = hi_;
        *(unsigned short*)(bl + jre * 2) = lr;
        *(unsigned short*)(bl + jim * 2) = li_;
      }
      float kp = c2r * pr - c2i * pi;
      #pragma unroll
      for (int k = 1; k < 32; k <<= 1) kp += __shfl_xor(kp, k, 32);
      if (n == 0) kk[d] = (d == 0) ? (kp + Dp[lh]) : kp;
      float nr = pr * wr - pi * wi;
      pi = pr * wi + pi * wr;
      pr = nr;
    }
    float w32r = pr, w32i = pi;
    float c2wr = c2r * wr - c2i * wi;
    float c2wi = c2r * wi + c2i * wr;
    int s = ((n >> 4) << 2) + (n & 3);
    int gg = (n & 15) >> 2;
    float pmr = 1.0f, pmi = 0.0f;   // w32^m
    for (int m = 0; m < 16; ++m) {
      float* q = (float*)(tb + 20480 + (size_t)((s * 64) + (gg * 16 + m)) * 24);
      q[0] = w32r; q[1] = w32i; q[2] = pmr; q[3] = pmi; q[4] = c2wr; q[5] = c2wi;
      float t2 = pmr * w32r - pmi * w32i;
      pmi = pmr * w32i + pmi * w32r;
      pmr = t2;
    }
  }
  __syncthreads();
  for (int idx = tid; idx < 1024; idx += 64) {
    int mt = idx >> 9, rem = idx & 511;
    int lane = rem >> 3, j = rem & 7;
    int tt = (mt << 4) + (lane & 15);
    int jf = ((lane >> 4) << 3) + j;
    float val = (jf <= tt) ? kk[tt - jf] : 0.0f;
    unsigned short hb = bf16bits(val);
    unsigned short lb = bf16bits(val - bfval(hb));
    *(unsigned short*)(tb + 16384 + mt * 1024 + lane * 16 + j * 2) = hb;
    *(unsigned short*)(tb + 18432 + mt * 1024 + lane * 16 + j * 2) = lb;
  }
}

// ---------------------------------------------------------------------------
// fp32 -> bf16 convert (CW weights).
// ---------------------------------------------------------------------------
__global__ __launch_bounds__(256) void k_tobf16(const float* __restrict__ src,
                                                __hip_bfloat16* __restrict__ dst,
                                                int n) {
  int i = (blockIdx.x * 256 + threadIdx.x) * 4;
  if (i >= n) return;
  float4 v = *reinterpret_cast<const float4*>(&src[i]);
  dst[i + 0] = __float2bfloat16(v.x);
  dst[i + 1] = __float2bfloat16(v.y);
  dst[i + 2] = __float2bfloat16(v.z);
  dst[i + 3] = __float2bfloat16(v.w);
}

// ---------------------------------------------------------------------------
// Split X fp32 -> Xhi/Xlo bf16 planes (same [b][l][k] layout).
// ---------------------------------------------------------------------------
__global__ __launch_bounds__(256) void k_splitx(const float* __restrict__ src,
                                                __hip_bfloat16* __restrict__ hi,
                                                __hip_bfloat16* __restrict__ lo,
                                                int n) {
  int i = (blockIdx.x * 256 + threadIdx.x) * 4;
  if (i >= n) return;
  float4 v = *reinterpret_cast<const float4*>(&src[i]);
  float vv[4] = {v.x, v.y, v.z, v.w};
  unsigned short hb[4], lb[4];
  #pragma unroll
  for (int j = 0; j < 4; ++j) {
    hb[j] = bf16bits(vv[j]);
    lb[j] = bf16bits(vv[j] - bfval(hb[j]));
  }
  *reinterpret_cast<uint2*>(hi + i) = make_uint2(
      (unsigned)hb[0] | ((unsigned)hb[1] << 16), (unsigned)hb[2] | ((unsigned)hb[3] << 16));
  *reinterpret_cast<uint2*>(lo + i) = make_uint2(
      (unsigned)lb[0] | ((unsigned)lb[1] << 16), (unsigned)lb[2] | ((unsigned)lb[3] << 16));
}

// ---------------------------------------------------------------------------
// W[k][h] fp32 -> Wt hi/lo bf16 [h][k] (transposed, split). One-time, tiny.
// ---------------------------------------------------------------------------
__global__ __launch_bounds__(256) void k_prepwt(const float* __restrict__ W,
                                                __hip_bfloat16* __restrict__ hi,
                                                __hip_bfloat16* __restrict__ lo) {
  int idx = blockIdx.x * 256 + threadIdx.x;   // h*INP + k
  if (idx >= HH * INP) return;
  int h = idx / INP, k = idx - h * INP;
  float v = W[(size_t)k * HH + h];
  unsigned short hb = bf16bits(v);
  hi[idx] = __builtin_bit_cast(__hip_bfloat16, hb);
  lo[idx] = __float2bfloat16(v - bfval(hb));
}

// ---------------------------------------------------------------------------
// Input GEMM, bf16 MFMA split. Round-15: writes packed-u32 plane
// Upk[b][h][l] = (hi_bf16<<16)|lo_bf16; one uint4 store per (m,n).
// ---------------------------------------------------------------------------
__global__ __launch_bounds__(256) void k_ingemm(const __hip_bfloat16* __restrict__ Xhi,
                                                const __hip_bfloat16* __restrict__ Xlo,
                                                const __hip_bfloat16* __restrict__ Wthi,
                                                const __hip_bfloat16* __restrict__ Wtlo,
                                                const float* __restrict__ bias,
                                                unsigned* __restrict__ Upk) {
  int lt = blockIdx.x * 128;
  int ht = blockIdx.y * 128;
  int b  = blockIdx.z;
  int t = threadIdx.x;
  int wid = t >> 6, lane = t & 63;
  int wrow = wid >> 1, wcol = wid & 1;
  int l15 = lane & 15, g = lane >> 4;

  const short* Xh = (const short*)Xhi + (size_t)b * LL * INP;
  const short* Xl = (const short*)Xlo + (size_t)b * LL * INP;
  const short* Bh = (const short*)Wthi;
  const short* Bl = (const short*)Wtlo;

  f32x4 acc[4][4];
  #pragma unroll
  for (int m = 0; m < 4; ++m)
    #pragma unroll
    for (int n = 0; n < 4; ++n) acc[m][n] = f32x4{0.f, 0.f, 0.f, 0.f};

  int lbase = lt + wrow * 64 + l15;
  int hbase = ht + wcol * 64 + l15;

  #pragma unroll
  for (int ks = 0; ks < 6; ++ks) {
    int k0 = ks * 32 + 8 * g;
    short8 ah[4], al[4], bh[4], bl[4];
    #pragma unroll
    for (int m = 0; m < 4; ++m) {
      size_t off = (size_t)(lbase + m * 16) * INP + k0;
      ah[m] = *reinterpret_cast<const short8*>(Xh + off);
      al[m] = *reinterpret_cast<const short8*>(Xl + off);
    }
    #pragma unroll
    for (int n = 0; n < 4; ++n) {
      size_t off = (size_t)(hbase + n * 16) * INP + k0;
      bh[n] = *reinterpret_cast<const short8*>(Bh + off);
      bl[n] = *reinterpret_cast<const short8*>(Bl + off);
    }
    #pragma unroll
    for (int m = 0; m < 4; ++m)
      #pragma unroll
      for (int n = 0; n < 4; ++n) {
        acc[m][n] = __builtin_amdgcn_mfma_f32_16x16x32_bf16(ah[m], bh[n], acc[m][n], 0, 0, 0);
        acc[m][n] = __builtin_amdgcn_mfma_f32_16x16x32_bf16(ah[m], bl[n], acc[m][n], 0, 0, 0);
        acc[m][n] = __builtin_amdgcn_mfma_f32_16x16x32_bf16(al[m], bh[n], acc[m][n], 0, 0, 0);
      }
  }

  #pragma unroll
  for (int n = 0; n < 4; ++n) {
    int h = hbase + n * 16;
    float bv = bias[h];
    size_t rowoff = ((size_t)b * HH + h) * LL;
    #pragma unroll
    for (int m = 0; m < 4; ++m) {
      int l0 = lt + wrow * 64 + m * 16 + g * 4;
      uint4 o;
      o.x = packsplit(acc[m][n][0] + bv);
      o.y = packsplit(acc[m][n][1] + bv);
      o.z = packsplit(acc[m][n][2] + bv);
      o.w = packsplit(acc[m][n][3] + bv);
      *reinterpret_cast<uint4*>(Upk + rowoff + l0) = o;
    }
  }
}

// ---------------------------------------------------------------------------
// MFMA chunk-parallel S4D scan, round 15: input is packed-u32 plane;
// unpack to hi/lo fragments with 2 bit-ops per word (v_perm-selectable).
// Free register allocation; D in FIR tap 0; (l>>5) epilogue swizzle.
// Output: Ybt[b][h>>2][l][h&3] bf16 via 16 KB LDS transpose.
// ---------------------------------------------------------------------------
__global__ __launch_bounds__(256) void k_scan(const unsigned* __restrict__ Upk,
                                              short* __restrict__ Ybt,
                                              const char* __restrict__ Tab) {
  __shared__ __align__(16) char smem[16384];  // ylds [l][h'4], XOR-swizzled
  int t = threadIdx.x;
  int lane = t & 63;
  int wid = t >> 6;                              // 0..3 = h'
  int row = __builtin_amdgcn_readfirstlane(blockIdx.x * 4 + wid);
  int h = row & (HH - 1);
  const char* tb = Tab + (size_t)h * TABB;
  const unsigned* urow = Upk + (size_t)row * LL;
  int g = lane >> 4, m = lane & 15;

  short8 uh[4], ul[4];
  #pragma unroll
  for (int c0 = 0; c0 < 4; ++c0) {
    int off = 512 * c0 + 32 * m + 8 * g;
    uint4 pa = *reinterpret_cast<const uint4*>(urow + off);
    uint4 pb = *reinterpret_cast<const uint4*>(urow + off + 4);
    unsigned p[8] = {pa.x, pa.y, pa.z, pa.w, pb.x, pb.y, pb.z, pb.w};
    unsigned hw[4], lw[4];
    #pragma unroll
    for (int w = 0; w < 4; ++w) {
      unsigned p0 = p[2 * w], p1 = p[2 * w + 1];
      hw[w] = (p1 & 0xFFFF0000u) | (p0 >> 16);
      lw[w] = (p1 << 16) | (p0 & 0x0000FFFFu);
    }
    uh[c0] = __builtin_bit_cast(short8, make_uint4(hw[0], hw[1], hw[2], hw[3]));
    ul[c0] = __builtin_bit_cast(short8, make_uint4(lw[0], lw[1], lw[2], lw[3]));
  }

  f32x4 Z[2][2][4];
  #pragma unroll
  for (int mt = 0; mt < 2; ++mt)
    #pragma unroll
    for (int reim = 0; reim < 2; ++reim) {
      short8 whi = *reinterpret_cast<const short8*>(tb + (mt * 2 + reim) * 1024 + lane * 16);
      short8 wlo = *reinterpret_cast<const short8*>(tb + 4096 + (mt * 2 + reim) * 1024 + lane * 16);
      #pragma unroll
      for (int c0 = 0; c0 < 4; ++c0) {
        f32x4 z = {0.f, 0.f, 0.f, 0.f};
        z = __builtin_amdgcn_mfma_f32_16x16x32_bf16(whi, uh[c0], z, 0, 0, 0);
        z = __builtin_amdgcn_mfma_f32_16x16x32_bf16(whi, ul[c0], z, 0, 0, 0);
        z = __builtin_amdgcn_mfma_f32_16x16x32_bf16(wlo, uh[c0], z, 0, 0, 0);
        Z[mt][reim][c0] = z;
      }
    }

  float aR[8][4], aI[8][4];
  #pragma unroll
  for (int s = 0; s < 8; ++s) {
    int mt = s >> 2, i = s & 3;
    const char* plb = tb + 20480 + (size_t)(s * 64 + lane) * 24;
    f32x2 w32 = *reinterpret_cast<const f32x2*>(plb);
    f32x2 w32m = *reinterpret_cast<const f32x2*>(plb + 8);
    f32x2 c2w = *reinterpret_cast<const f32x2*>(plb + 16);
    float r1r = w32[0], r1i = w32[1];
    float r2r = r1r * r1r - r1i * r1i, r2i = 2.f * r1r * r1i;
    float r4r = r2r * r2r - r2i * r2i, r4i = 2.f * r2r * r2i;
    float r8r = r4r * r4r - r4i * r4i, r8i = 2.f * r4r * r4i;
    float w16r = r8r * r8r - r8i * r8i, w16i = 2.f * r8r * r8i;  // w32^16

    float Er[4], Ei[4], Tr[4], Ti[4];
    #pragma unroll
    for (int c0 = 0; c0 < 4; ++c0) {
      float Pr = Z[mt][0][c0][i], Pi = Z[mt][1][c0][i];
      {
        float qr = __shfl_up(Pr, 1u, 16), qi = __shfl_up(Pi, 1u, 16);
        if (m < 1) { qr = 0.f; qi = 0.f; }
        Pr = fmaf(r1r, qr, fmaf(-r1i, qi, Pr));
        Pi = fmaf(r1r, qi, fmaf(r1i, qr, Pi));
      }
      {
        float qr = __shfl_up(Pr, 2u, 16), qi = __shfl_up(Pi, 2u, 16);
        if (m < 2) { qr = 0.f; qi = 0.f; }
        Pr = fmaf(r2r, qr, fmaf(-r2i, qi, Pr));
        Pi = fmaf(r2r, qi, fmaf(r2i, qr, Pi));
      }
      {
        float qr = __shfl_up(Pr, 4u, 16), qi = __shfl_up(Pi, 4u, 16);
        if (m < 4) { qr = 0.f; qi = 0.f; }
        Pr = fmaf(r4r, qr, fmaf(-r4i, qi, Pr));
        Pi = fmaf(r4r, qi, fmaf(r4i, qr, Pi));
      }
      {
        float qr = __shfl_up(Pr, 8u, 16), qi = __shfl_up(Pi, 8u, 16);
        if (m < 8) { qr = 0.f; qi = 0.f; }
        Pr = fmaf(r8r, qr, fmaf(-r8i, qi, Pr));
        Pi = fmaf(r8r, qi, fmaf(r8i, qr, Pi));
      }
      float eqr = __shfl_up(Pr, 1u, 16), eqi = __shfl_up(Pi, 1u, 16);
      if (m == 0) { eqr = 0.f; eqi = 0.f; }
      Er[c0] = eqr; Ei[c0] = eqi;
      Tr[c0] = __shfl(Pr, 15, 16);
      Ti[c0] = __shfl(Pi, 15, 16);
    }
    float C1r = Tr[0], C1i = Ti[0];
    float C2r = fmaf(w16r, C1r, fmaf(-w16i, C1i, Tr[1]));
    float C2i = fmaf(w16r, C1i, fmaf(w16i, C1r, Ti[1]));
    float C3r = fmaf(w16r, C2r, fmaf(-w16i, C2i, Tr[2]));
    float C3i = fmaf(w16r, C2i, fmaf(w16i, C2r, Ti[2]));
    float Cr[4] = {0.f, C1r, C2r, C3r};
    float Ci[4] = {0.f, C1i, C2i, C3i};
    #pragma unroll
    for (int c0 = 0; c0 < 4; ++c0) {
      float Erc = fmaf(w32m[0], Cr[c0], fmaf(-w32m[1], Ci[c0], Er[c0]));
      float Eic = fmaf(w32m[0], Ci[c0], fmaf(w32m[1], Cr[c0], Ei[c0]));
      aR[s][c0] = c2w[0] * Erc - c2w[1] * Eic;
      aI[s][c0] = c2w[0] * Eic + c2w[1] * Erc;
    }
  }

  short8 afh[2][4], afl[2][4];
  #pragma unroll
  for (int kt = 0; kt < 2; ++kt)
    #pragma unroll
    for (int c0 = 0; c0 < 4; ++c0) {
      float av[8] = {aR[kt * 4 + 0][c0], aR[kt * 4 + 1][c0], aR[kt * 4 + 2][c0], aR[kt * 4 + 3][c0],
                     aI[kt * 4 + 0][c0], aI[kt * 4 + 1][c0], aI[kt * 4 + 2][c0], aI[kt * 4 + 3][c0]};
      short8 hi, lo;
      #pragma unroll
      for (int j = 0; j < 8; ++j) {
        unsigned short hb = bf16bits(av[j]);
        hi[j] = (short)hb;
        lo[j] = (short)bf16bits(av[j] - bfval(hb));
      }
      afh[kt][c0] = hi;
      afl[kt][c0] = lo;
    }

  f32x4 y[2][4];
  #pragma unroll
  for (int mtT = 0; mtT < 2; ++mtT) {
    short8 fh = *reinterpret_cast<const short8*>(tb + 16384 + mtT * 1024 + lane * 16);
    short8 fl = *reinterpret_cast<const short8*>(tb + 18432 + mtT * 1024 + lane * 16);
    short8 wch0 = *reinterpret_cast<const short8*>(tb + 8192 + (mtT * 2 + 0) * 1024 + lane * 16);
    short8 wcl0 = *reinterpret_cast<const short8*>(tb + 12288 + (mtT * 2 + 0) * 1024 + lane * 16);
    short8 wch1 = *reinterpret_cast<const short8*>(tb + 8192 + (mtT * 2 + 1) * 1024 + lane * 16);
    short8 wcl1 = *reinterpret_cast<const short8*>(tb + 12288 + (mtT * 2 + 1) * 1024 + lane * 16);
    #pragma unroll
    for (int c0 = 0; c0 < 4; ++c0) {
      f32x4 acc = {0.f, 0.f, 0.f, 0.f};
      acc = __builtin_amdgcn_mfma_f32_16x16x32_bf16(fh, uh[c0], acc, 0, 0, 0);
      acc = __builtin_amdgcn_mfma_f32_16x16x32_bf16(fh, ul[c0], acc, 0, 0, 0);
      acc = __builtin_amdgcn_mfma_f32_16x16x32_bf16(fl, uh[c0], acc, 0, 0, 0);
      acc = __builtin_amdgcn_mfma_f32_16x16x32_bf16(wch0, afh[0][c0], acc, 0, 0, 0);
      acc = __builtin_amdgcn_mfma_f32_16x16x32_bf16(wch0, afl[0][c0], acc, 0, 0, 0);
      acc = __builtin_amdgcn_mfma_f32_16x16x32_bf16(wcl0, afh[0][c0], acc, 0, 0, 0);
      acc = __builtin_amdgcn_mfma_f32_16x16x32_bf16(wch1, afh[1][c0], acc, 0, 0, 0);
      acc = __builtin_amdgcn_mfma_f32_16x16x32_bf16(wch1, afl[1][c0], acc, 0, 0, 0);
      acc = __builtin_amdgcn_mfma_f32_16x16x32_bf16(wcl1, afh[1][c0], acc, 0, 0, 0);
      y[mtT][c0] = acc;
    }
  }

  // epilogue: GELU (D*u already in y via FIR tap 0), pack, LDS transpose
  #pragma unroll
  for (int mtT = 0; mtT < 2; ++mtT)
    #pragma unroll
    for (int c0 = 0; c0 < 4; ++c0) {
      int eb = 512 * c0 + 32 * m + 16 * mtT + 4 * g;
      f32x4 vv = y[mtT][c0];
      unsigned short bv[4];
      bv[0] = bf16bits(gelu_fast(vv[0]));
      bv[1] = bf16bits(gelu_fast(vv[1]));
      bv[2] = bf16bits(gelu_fast(vv[2]));
      bv[3] = bf16bits(gelu_fast(vv[3]));
      #pragma unroll
      for (int k = 0; k < 4; ++k) {
        int l = eb + k;
        *(short*)(smem + ((l * 8 + wid * 2) ^ (((l >> 5) & 7) << 3))) = (short)bv[k];
      }
    }
  __syncthreads();
  // packed 8B stores: Ybt[(blockIdx.x * 2048 + l) * 4 + 0..3]
  #pragma unroll
  for (int i = 0; i < 8; ++i) {
    int l = t + 256 * i;
    uint2 v = *reinterpret_cast<const uint2*>(smem + ((l * 8) ^ (((l >> 5) & 7) << 3)));
    *reinterpret_cast<uint2*>(Ybt + ((size_t)blockIdx.x * 2048 + l) * 4) = v;
  }
}

// ---------------------------------------------------------------------------
// conv1x1 + GLU, bf16 MFMA 16x16x32. B fragments from h-quartet Ybt layout;
// A (CW) staged in LDS via gload16, XOR swizzle. Round-15: single packed-u32
// store per output element (coalesced 4B stores).
// ---------------------------------------------------------------------------
__global__ __launch_bounds__(256) void k_conv(const short* __restrict__ Ybt,
                                              const __hip_bfloat16* __restrict__ CWb,
                                              const float* __restrict__ CB,
                                              unsigned* __restrict__ Upk) {
  __shared__ short Alds[128 * 64];
  int lt = blockIdx.x * 128;
  int ot = blockIdx.y * 64;
  int b  = blockIdx.z;
  int t = threadIdx.x;
  int wid = t >> 6, lane = t & 63;
  int wr = wid >> 1, wc = wid & 1;
  int l15 = lane & 15, l4 = lane >> 4;
  f32x4 zero = {0.f, 0.f, 0.f, 0.f};
  f32x4 accA[2][4], accG[2][4];
  #pragma unroll
  for (int m = 0; m < 2; ++m)
    #pragma unroll
    for (int n = 0; n < 4; ++n) { accA[m][n] = zero; accG[m][n] = zero; }

  const short* Yb = Ybt + (size_t)b * 128 * 2048 * 4;
  const char* Wb = (const char*)CWb;

  for (int kt = 0; kt < HH; kt += 64) {
    #pragma unroll
    for (int it = 0; it < 4; ++it) {
      int d = 16 * (t + 256 * it);
      int rowl = d >> 7, cb = d & 127;
      int orow = (rowl < 64) ? (ot + rowl) : (448 + ot + rowl);
      gload16(Wb + (size_t)orow * 1024 + kt * 2 + (cb ^ ((rowl & 7) << 4)),
              (char*)Alds + d);
    }
    short8 bfrag[2][4];
    #pragma unroll
    for (int ks = 0; ks < 2; ++ks)
      #pragma unroll
      for (int n = 0; n < 4; ++n) {
        int l = lt + wc * 64 + n * 16 + l15;
        int octg = (kt >> 3) + ks * 4 + l4;
        const short* p0 = Yb + ((size_t)(2 * octg) * 2048 + l) * 4;
        uint2 A = *reinterpret_cast<const uint2*>(p0);
        uint2 B2 = *reinterpret_cast<const uint2*>(p0 + 8192);
        bfrag[ks][n] = __builtin_bit_cast(short8, u2x2{A, B2});
      }
    __syncthreads();
    #pragma unroll
    for (int ks = 0; ks < 2; ++ks) {
      short8 af[4];
      #pragma unroll
      for (int m = 0; m < 4; ++m) {
        int mrow = ((m < 2) ? (wr * 32 + m * 16) : (64 + wr * 32 + (m - 2) * 16)) + l15;
        int colb = (ks * 64 + 16 * l4) ^ ((mrow & 7) << 4);
        af[m] = *reinterpret_cast<const short8*>((const char*)Alds + mrow * 128 + colb);
      }
      #pragma unroll
      for (int m = 0; m < 2; ++m)
        #pragma unroll
        for (int n = 0; n < 4; ++n) {
          accA[m][n] = __builtin_amdgcn_mfma_f32_16x16x32_bf16(af[m], bfrag[ks][n], accA[m][n], 0, 0, 0);
          accG[m][n] = __builtin_amdgcn_mfma_f32_16x16x32_bf16(af[m + 2], bfrag[ks][n], accG[m][n], 0, 0, 0);
        }
    }
    __syncthreads();
  }
  #pragma unroll
  for (int m = 0; m < 2; ++m) {
    #pragma unroll
    for (int r = 0; r < 4; ++r) {
      int rowl = wr * 32 + m * 16 + l4 * 4 + r;
      float ba = CB[ot + rowl];
      float bg = CB[512 + ot + rowl];
      size_t rowoff = ((size_t)b * HH + ot + rowl) * LL + lt + wc * 64;
      #pragma unroll
      for (int n = 0; n < 4; ++n) {
        float a = accA[m][n][r] + ba;
        float gg = accG[m][n][r] + bg;
        Upk[rowoff + n * 16 + l15] = packsplit(a * sigmoidf_(gg));
      }
    }
  }
}

// ---------------------------------------------------------------------------
// Output projection (fp32 out); reads packed plane, u = hi + lo.
// ---------------------------------------------------------------------------
__global__ __launch_bounds__(256) void k_outgemm(const unsigned* __restrict__ Upk,
                                                 const float* __restrict__ Wo,
                                                 const float* __restrict__ bo,
                                                 float* __restrict__ out) {
  int bl = blockIdx.x * 256 + threadIdx.x;
  int b = bl >> 11, l = bl & (LL - 1);
  float a0 = 0.0f, a1 = 0.0f;
  const unsigned* up = Upk + (size_t)b * HH * LL + l;
  #pragma unroll 4
  for (int h = 0; h < HH; ++h) {
    unsigned u = up[(size_t)h * LL];
    float v = bfval((unsigned short)(u >> 16)) + bfval((unsigned short)(u & 0xFFFFu));
    a0 = fmaf(v, Wo[h * 2 + 0], a0);
    a1 = fmaf(v, Wo[h * 2 + 1], a1);
  }
  out[(size_t)bl * 2 + 0] = a0 + bo[0];
  out[(size_t)bl * 2 + 1] = a1 + bo[1];
}

extern "C" void kernel_launch(void* const* d_in, const int* in_sizes, int n_in,
                              void* d_out, int out_size, void* d_ws, size_t ws_size,
                              hipStream_t stream) {
  const float* X      = (const float*)d_in[0];
  const float* Win    = (const float*)d_in[1];
  const float* bin    = (const float*)d_in[2];
  const float* log_dt = (const float*)d_in[3];
  const float* Cri    = (const float*)d_in[4];
  const float* lAr    = (const float*)d_in[5];
  const float* Aim    = (const float*)d_in[6];
  const float* Dp     = (const float*)d_in[7];
  const float* CW     = (const float*)d_in[8];
  const float* CB     = (const float*)d_in[9];
  const float* Wo     = (const float*)d_in[10];
  const float* bo     = (const float*)d_in[11];
  float* out = (float*)d_out;

  const size_t Pfloats   = (size_t)NNL * HH * NN2 * 4;        // 262144
  const size_t CWfloats  = (size_t)NNL * 2 * HH * HH / 2;     // 1048576
  const size_t Tabfloats = (size_t)NNL * HH * (TABB / 4);     // 16777216
  const size_t Wtfloats  = (size_t)HH * INP;                  // 98304 (hi+lo bf16)
  const size_t Xnf       = (size_t)BB * LL * INP;             // 12582912 elems
  const size_t HL        = (size_t)HH * LL;                   // 1048576

  float* P = (float*)d_ws;
  __hip_bfloat16* CWb = (__hip_bfloat16*)(P + Pfloats);
  char* Tab = (char*)(P + Pfloats + CWfloats);
  __hip_bfloat16* Wthi = (__hip_bfloat16*)(P + Pfloats + CWfloats + Tabfloats);
  __hip_bfloat16* Wtlo = Wthi + Wtfloats;
  __hip_bfloat16* Xhi  = (__hip_bfloat16*)(P + Pfloats + CWfloats + Tabfloats + Wtfloats);
  __hip_bfloat16* Xlo  = Xhi + Xnf;
  size_t head = Pfloats + CWfloats + Tabfloats + Wtfloats + Xnf;

  size_t ws_floats = ws_size / sizeof(float);
  size_t avail = (ws_floats > head) ? (ws_floats - head) : 0;
  // per-batch: Upk = HL u32 (HL floats) + Ybt HL shorts (HL/2 floats)
  int G = (int)(avail / (HL + HL / 2));
  if (G >= 32) G = 32;
  else if (G >= 16) G = 16;
  else if (G >= 8) G = 8;
  else if (G >= 4) G = 4;
  else if (G >= 2) G = 2;
  else G = 1;

  unsigned* Upk = (unsigned*)(P + head);
  short* Ybt = (short*)(Upk + (size_t)G * HL);

  k_params<<<(NNL * HH * NN2 + 255) / 256, 256, 0, stream>>>(log_dt, Cri, lAr, Aim, P);
  k_tables<<<NNL * HH, 64, 0, stream>>>(P, Dp, Tab);
  k_tobf16<<<(NNL * 2 * HH * HH) / 1024, 256, 0, stream>>>(CW, CWb, NNL * 2 * HH * HH);
  k_prepwt<<<(HH * INP + 255) / 256, 256, 0, stream>>>(Win, Wthi, Wtlo);
  k_splitx<<<(int)(Xnf / 1024), 256, 0, stream>>>(X, Xhi, Xlo, (int)Xnf);

  for (int b0 = 0; b0 < BB; b0 += G) {
    int g = (BB - b0 < G) ? (BB - b0) : G;
    k_ingemm<<<dim3(LL / 128, HH / 128, g), 256, 0, stream>>>(
        Xhi + (size_t)b0 * LL * INP, Xlo + (size_t)b0 * LL * INP, Wthi, Wtlo, bin, Upk);
    for (int layer = 0; layer < NNL; ++layer) {
      k_scan<<<g * (HH / 4), 256, 0, stream>>>(
          Upk, Ybt, Tab + (size_t)layer * HH * TABB);
      k_conv<<<dim3(LL / 128, HH / 64, g), 256, 0, stream>>>(
          Ybt, CWb + (size_t)layer * 2 * HH * HH, CB + (size_t)layer * 2 * HH, Upk);
    }
    k_outgemm<<<g * LL / 256, 256, 0, stream>>>(
        Upk, Wo, bo, out + (size_t)b0 * LL * OUTC);
  }
}

// Round 16
// 1211.669 us; speedup vs baseline: 1.6051x; 1.0059x over previous
//
#include <hip/hip_runtime.h>
#include <hip/hip_bf16.h>
#include <math.h>

#define BB 32
#define LL 2048
#define INP 192
#define OUTC 2
#define HH 512
#define NN2 32
#define NNL 4
#define TABB 32768   // bytes of table per (layer,h)

using short8 = __attribute__((ext_vector_type(8))) short;
using f32x4  = __attribute__((ext_vector_type(4))) float;
using f32x2  = __attribute__((ext_vector_type(2))) float;

struct u2x2 { uint2 a, b; };

__device__ __forceinline__ float sigmoidf_(float x) {
  return 1.0f / (1.0f + expf(-x));
}
__device__ __forceinline__ unsigned short bf16bits(float x) {
  __hip_bfloat16 b = __float2bfloat16(x);
  return __builtin_bit_cast(unsigned short, b);
}
__device__ __forceinline__ float bfval(unsigned short b) {
  unsigned int u = (unsigned int)b << 16;
  return __builtin_bit_cast(float, u);
}
// pack split-bf16 (hi<<16)|lo from fp32
__device__ __forceinline__ unsigned packsplit(float v) {
  unsigned short hb = bf16bits(v);
  unsigned short lb = bf16bits(v - bfval(hb));
  return ((unsigned)hb << 16) | (unsigned)lb;
}
// Abramowitz-Stegun 7.1.26 erf (max err 1.5e-7) based exact-GELU
__device__ __forceinline__ float gelu_fast(float x) {
  float s = x * 0.70710678118654752f;
  float ax = fabsf(s);
  float tt = 1.0f / fmaf(0.3275911f, ax, 1.0f);
  float p = fmaf(1.061405429f, tt, -1.453152027f);
  p = fmaf(p, tt, 1.421413741f);
  p = fmaf(p, tt, -0.284496736f);
  p = fmaf(p, tt, 0.254829592f);
  float e = __expf(-s * s);
  float er = 1.0f - p * tt * e;
  er = copysignf(er, s);
  return 0.5f * x * (1.0f + er);
}
__device__ __forceinline__ void gload16(const void* gsrc, void* ldst) {
  __builtin_amdgcn_global_load_lds(
      (const __attribute__((address_space(1))) void*)gsrc,
      (__attribute__((address_space(3))) void*)ldst, 16, 0, 0);
}

// ---------------------------------------------------------------------------
// P[NL][H][N2][4] = {w_re, w_im, c2_re, c2_im}
// ---------------------------------------------------------------------------
__global__ __launch_bounds__(256) void k_params(const float* __restrict__ log_dt,
                                                const float* __restrict__ Cri,
                                                const float* __restrict__ lAr,
                                                const float* __restrict__ Aim,
                                                float* __restrict__ P) {
  int idx = blockIdx.x * 256 + threadIdx.x;
  if (idx >= NNL * HH * NN2) return;
  float dt  = expf(log_dt[idx / NN2]);
  float Are = -expf(lAr[idx]);
  float Aimv = Aim[idx];
  float dre = Are * dt, dim = Aimv * dt;
  float er = expf(dre);
  float wrv = er * cosf(dim);
  float wiv = er * sinf(dim);
  float Er = wrv - 1.0f, Ei = wiv;
  float den = Are * Are + Aimv * Aimv;
  float Fr = (Er * Are + Ei * Aimv) / den;
  float Fi = (Ei * Are - Er * Aimv) / den;
  float Cre = Cri[idx * 2 + 0], Cim = Cri[idx * 2 + 1];
  P[idx * 4 + 0] = wrv;
  P[idx * 4 + 1] = wiv;
  P[idx * 4 + 2] = 2.0f * (Cre * Fr - Cim * Fi);
  P[idx * 4 + 3] = 2.0f * (Cre * Fi + Cim * Fr);
}

// ---------------------------------------------------------------------------
// Build per-(layer,h) MFMA fragment tables (split bf16 hi/lo) + scan tables.
// FIR tap 0 absorbs D[h].
// ---------------------------------------------------------------------------
__global__ __launch_bounds__(64) void k_tables(const float* __restrict__ P,
                                               const float* __restrict__ Dp,
                                               char* __restrict__ Tab) {
  __shared__ float kk[32];
  int tid = threadIdx.x;
  int lh = blockIdx.x;
  char* tb = Tab + (size_t)lh * TABB;
  if (tid < 32) {
    int n = tid;
    const float4 pq = reinterpret_cast<const float4*>(P)[(size_t)lh * NN2 + n];
    float wr = pq.x, wi = pq.y, c2r = pq.z, c2i = pq.w;
    int mt = n >> 4;
    float pr = 1.0f, pi = 0.0f;   // w^d
    for (int d = 0; d < 32; ++d) {
      {  // WA at t = 31-d
        int t_ = 31 - d;
        int lane = ((t_ >> 3) << 4) + (n & 15);
        int j = t_ & 7;
        unsigned short hr = bf16bits(pr);
        unsigned short lr = bf16bits(pr - bfval(hr));
        unsigned short hi_ = bf16bits(pi);
        unsigned short li_ = bf16bits(pi - bfval(hi_));
        *(unsigned short*)(tb + (mt * 2 + 0) * 1024 + lane * 16 + j * 2) = hr;
        *(unsigned short*)(tb + (mt * 2 + 1) * 1024 + lane * 16 + j * 2) = hi_;
        *(unsigned short*)(tb + 4096 + (mt * 2 + 0) * 1024 + lane * 16 + j * 2) = lr;
        *(unsigned short*)(tb + 4096 + (mt * 2 + 1) * 1024 + lane * 16 + j * 2) = li_;
      }
      {  // WC at t = d
        int mtT = d >> 4;
        int lane = (((n & 15) >> 2) << 4) + (d & 15);
        int jre = n & 3, jim = (n & 3) + 4;
        unsigned short hr = bf16bits(pr);
        unsigned short lr = bf16bits(pr - bfval(hr));
        float nim = -pi;
        unsigned short hi_ = bf16bits(nim);
        unsigned short li_ = bf16bits(nim - bfval(hi_));
        char* bh = tb + 8192 + (mtT * 2 + mt) * 1024 + lane * 16;
        char* bl = tb + 12288 + (mtT * 2 + mt) * 1024 + lane * 16;
        *(unsigned short*)(bh + jre * 2) = hr;
        *(unsigned short*)(bh + jim * 2) = hi_;
        *(unsigned short*)(bl + jre * 2) = lr;
        *(unsigned short*)(bl + jim * 2) = li_;
      }
      float kp = c2r * pr - c2i * pi;
      #pragma unroll
      for (int k = 1; k < 32; k <<= 1) kp += __shfl_xor(kp, k, 32);
      if (n == 0) kk[d] = (d == 0) ? (kp + Dp[lh]) : kp;
      float nr = pr * wr - pi * wi;
      pi = pr * wi + pi * wr;
      pr = nr;
    }
    float w32r = pr, w32i = pi;
    float c2wr = c2r * wr - c2i * wi;
    float c2wi = c2r * wi + c2i * wr;
    int s = ((n >> 4) << 2) + (n & 3);
    int gg = (n & 15) >> 2;
    float pmr = 1.0f, pmi = 0.0f;   // w32^m
    for (int m = 0; m < 16; ++m) {
      float* q = (float*)(tb + 20480 + (size_t)((s * 64) + (gg * 16 + m)) * 24);
      q[0] = w32r; q[1] = w32i; q[2] = pmr; q[3] = pmi; q[4] = c2wr; q[5] = c2wi;
      float t2 = pmr * w32r - pmi * w32i;
      pmi = pmr * w32i + pmi * w32r;
      pmr = t2;
    }
  }
  __syncthreads();
  for (int idx = tid; idx < 1024; idx += 64) {
    int mt = idx >> 9, rem = idx & 511;
    int lane = rem >> 3, j = rem & 7;
    int tt = (mt << 4) + (lane & 15);
    int jf = ((lane >> 4) << 3) + j;
    float val = (jf <= tt) ? kk[tt - jf] : 0.0f;
    unsigned short hb = bf16bits(val);
    unsigned short lb = bf16bits(val - bfval(hb));
    *(unsigned short*)(tb + 16384 + mt * 1024 + lane * 16 + j * 2) = hb;
    *(unsigned short*)(tb + 18432 + mt * 1024 + lane * 16 + j * 2) = lb;
  }
}

// ---------------------------------------------------------------------------
// fp32 -> bf16 convert (CW weights).
// ---------------------------------------------------------------------------
__global__ __launch_bounds__(256) void k_tobf16(const float* __restrict__ src,
                                                __hip_bfloat16* __restrict__ dst,
                                                int n) {
  int i = (blockIdx.x * 256 + threadIdx.x) * 4;
  if (i >= n) return;
  float4 v = *reinterpret_cast<const float4*>(&src[i]);
  dst[i + 0] = __float2bfloat16(v.x);
  dst[i + 1] = __float2bfloat16(v.y);
  dst[i + 2] = __float2bfloat16(v.z);
  dst[i + 3] = __float2bfloat16(v.w);
}

// ---------------------------------------------------------------------------
// Split X fp32 -> Xhi/Xlo bf16 planes (same [b][l][k] layout).
// ---------------------------------------------------------------------------
__global__ __launch_bounds__(256) void k_splitx(const float* __restrict__ src,
                                                __hip_bfloat16* __restrict__ hi,
                                                __hip_bfloat16* __restrict__ lo,
                                                int n) {
  int i = (blockIdx.x * 256 + threadIdx.x) * 4;
  if (i >= n) return;
  float4 v = *reinterpret_cast<const float4*>(&src[i]);
  float vv[4] = {v.x, v.y, v.z, v.w};
  unsigned short hb[4], lb[4];
  #pragma unroll
  for (int j = 0; j < 4; ++j) {
    hb[j] = bf16bits(vv[j]);
    lb[j] = bf16bits(vv[j] - bfval(hb[j]));
  }
  *reinterpret_cast<uint2*>(hi + i) = make_uint2(
      (unsigned)hb[0] | ((unsigned)hb[1] << 16), (unsigned)hb[2] | ((unsigned)hb[3] << 16));
  *reinterpret_cast<uint2*>(lo + i) = make_uint2(
      (unsigned)lb[0] | ((unsigned)lb[1] << 16), (unsigned)lb[2] | ((unsigned)lb[3] << 16));
}

// ---------------------------------------------------------------------------
// W[k][h] fp32 -> Wt hi/lo bf16 [h][k] (transposed, split). One-time, tiny.
// ---------------------------------------------------------------------------
__global__ __launch_bounds__(256) void k_prepwt(const float* __restrict__ W,
                                                __hip_bfloat16* __restrict__ hi,
                                                __hip_bfloat16* __restrict__ lo) {
  int idx = blockIdx.x * 256 + threadIdx.x;   // h*INP + k
  if (idx >= HH * INP) return;
  int h = idx / INP, k = idx - h * INP;
  float v = W[(size_t)k * HH + h];
  unsigned short hb = bf16bits(v);
  hi[idx] = __builtin_bit_cast(__hip_bfloat16, hb);
  lo[idx] = __float2bfloat16(v - bfval(hb));
}

// ---------------------------------------------------------------------------
// Input GEMM, bf16 MFMA split; writes packed-u32 plane Upk.
// ---------------------------------------------------------------------------
__global__ __launch_bounds__(256) void k_ingemm(const __hip_bfloat16* __restrict__ Xhi,
                                                const __hip_bfloat16* __restrict__ Xlo,
                                                const __hip_bfloat16* __restrict__ Wthi,
                                                const __hip_bfloat16* __restrict__ Wtlo,
                                                const float* __restrict__ bias,
                                                unsigned* __restrict__ Upk) {
  int lt = blockIdx.x * 128;
  int ht = blockIdx.y * 128;
  int b  = blockIdx.z;
  int t = threadIdx.x;
  int wid = t >> 6, lane = t & 63;
  int wrow = wid >> 1, wcol = wid & 1;
  int l15 = lane & 15, g = lane >> 4;

  const short* Xh = (const short*)Xhi + (size_t)b * LL * INP;
  const short* Xl = (const short*)Xlo + (size_t)b * LL * INP;
  const short* Bh = (const short*)Wthi;
  const short* Bl = (const short*)Wtlo;

  f32x4 acc[4][4];
  #pragma unroll
  for (int m = 0; m < 4; ++m)
    #pragma unroll
    for (int n = 0; n < 4; ++n) acc[m][n] = f32x4{0.f, 0.f, 0.f, 0.f};

  int lbase = lt + wrow * 64 + l15;
  int hbase = ht + wcol * 64 + l15;

  #pragma unroll
  for (int ks = 0; ks < 6; ++ks) {
    int k0 = ks * 32 + 8 * g;
    short8 ah[4], al[4], bh[4], bl[4];
    #pragma unroll
    for (int m = 0; m < 4; ++m) {
      size_t off = (size_t)(lbase + m * 16) * INP + k0;
      ah[m] = *reinterpret_cast<const short8*>(Xh + off);
      al[m] = *reinterpret_cast<const short8*>(Xl + off);
    }
    #pragma unroll
    for (int n = 0; n < 4; ++n) {
      size_t off = (size_t)(hbase + n * 16) * INP + k0;
      bh[n] = *reinterpret_cast<const short8*>(Bh + off);
      bl[n] = *reinterpret_cast<const short8*>(Bl + off);
    }
    #pragma unroll
    for (int m = 0; m < 4; ++m)
      #pragma unroll
      for (int n = 0; n < 4; ++n) {
        acc[m][n] = __builtin_amdgcn_mfma_f32_16x16x32_bf16(ah[m], bh[n], acc[m][n], 0, 0, 0);
        acc[m][n] = __builtin_amdgcn_mfma_f32_16x16x32_bf16(ah[m], bl[n], acc[m][n], 0, 0, 0);
        acc[m][n] = __builtin_amdgcn_mfma_f32_16x16x32_bf16(al[m], bh[n], acc[m][n], 0, 0, 0);
      }
  }

  #pragma unroll
  for (int n = 0; n < 4; ++n) {
    int h = hbase + n * 16;
    float bv = bias[h];
    size_t rowoff = ((size_t)b * HH + h) * LL;
    #pragma unroll
    for (int m = 0; m < 4; ++m) {
      int l0 = lt + wrow * 64 + m * 16 + g * 4;
      uint4 o;
      o.x = packsplit(acc[m][n][0] + bv);
      o.y = packsplit(acc[m][n][1] + bv);
      o.z = packsplit(acc[m][n][2] + bv);
      o.w = packsplit(acc[m][n][3] + bv);
      *reinterpret_cast<uint4*>(Upk + rowoff + l0) = o;
    }
  }
}

// ---------------------------------------------------------------------------
// MFMA chunk-parallel S4D scan, round 16: VGPR-dieted via (a) half-split
// phase A (Z live range halved: compute Z for one mt, consume via its 4
// slots, then the other mt) and (b) incremental a-pack (aR/aI fp32 arrays
// deleted; each slot packs its a directly into afh/afl at static element
// index). Same ops, same values -- only live-range reordering. FREE register
// allocation (no launch-bound hint: rounds 11/13 proved hints spill).
// ---------------------------------------------------------------------------
__global__ __launch_bounds__(256) void k_scan(const unsigned* __restrict__ Upk,
                                              short* __restrict__ Ybt,
                                              const char* __restrict__ Tab) {
  __shared__ __align__(16) char smem[16384];  // ylds [l][h'4], XOR-swizzled
  int t = threadIdx.x;
  int lane = t & 63;
  int wid = t >> 6;                              // 0..3 = h'
  int row = __builtin_amdgcn_readfirstlane(blockIdx.x * 4 + wid);
  int h = row & (HH - 1);
  const char* tb = Tab + (size_t)h * TABB;
  const unsigned* urow = Upk + (size_t)row * LL;
  int g = lane >> 4, m = lane & 15;

  short8 uh[4], ul[4];
  #pragma unroll
  for (int c0 = 0; c0 < 4; ++c0) {
    int off = 512 * c0 + 32 * m + 8 * g;
    uint4 pa = *reinterpret_cast<const uint4*>(urow + off);
    uint4 pb = *reinterpret_cast<const uint4*>(urow + off + 4);
    unsigned p[8] = {pa.x, pa.y, pa.z, pa.w, pb.x, pb.y, pb.z, pb.w};
    unsigned hw[4], lw[4];
    #pragma unroll
    for (int w = 0; w < 4; ++w) {
      unsigned p0 = p[2 * w], p1 = p[2 * w + 1];
      hw[w] = (p1 & 0xFFFF0000u) | (p0 >> 16);
      lw[w] = (p1 << 16) | (p0 & 0x0000FFFFu);
    }
    uh[c0] = __builtin_bit_cast(short8, make_uint4(hw[0], hw[1], hw[2], hw[3]));
    ul[c0] = __builtin_bit_cast(short8, make_uint4(lw[0], lw[1], lw[2], lw[3]));
  }

  short8 afh[2][4], afl[2][4];
  #pragma unroll
  for (int mt = 0; mt < 2; ++mt) {
    // phase A for this half only (Z live range = this iteration)
    f32x4 Z[2][4];
    #pragma unroll
    for (int reim = 0; reim < 2; ++reim) {
      short8 whi = *reinterpret_cast<const short8*>(tb + (mt * 2 + reim) * 1024 + lane * 16);
      short8 wlo = *reinterpret_cast<const short8*>(tb + 4096 + (mt * 2 + reim) * 1024 + lane * 16);
      #pragma unroll
      for (int c0 = 0; c0 < 4; ++c0) {
        f32x4 z = {0.f, 0.f, 0.f, 0.f};
        z = __builtin_amdgcn_mfma_f32_16x16x32_bf16(whi, uh[c0], z, 0, 0, 0);
        z = __builtin_amdgcn_mfma_f32_16x16x32_bf16(whi, ul[c0], z, 0, 0, 0);
        z = __builtin_amdgcn_mfma_f32_16x16x32_bf16(wlo, uh[c0], z, 0, 0, 0);
        Z[reim][c0] = z;
      }
    }
    // 4 slots of this half; pack a into fragments immediately (static idx)
    #pragma unroll
    for (int i = 0; i < 4; ++i) {
      int s = mt * 4 + i;
      const char* plb = tb + 20480 + (size_t)(s * 64 + lane) * 24;
      f32x2 w32 = *reinterpret_cast<const f32x2*>(plb);
      f32x2 w32m = *reinterpret_cast<const f32x2*>(plb + 8);
      f32x2 c2w = *reinterpret_cast<const f32x2*>(plb + 16);
      float r1r = w32[0], r1i = w32[1];
      float r2r = r1r * r1r - r1i * r1i, r2i = 2.f * r1r * r1i;
      float r4r = r2r * r2r - r2i * r2i, r4i = 2.f * r2r * r2i;
      float r8r = r4r * r4r - r4i * r4i, r8i = 2.f * r4r * r4i;
      float w16r = r8r * r8r - r8i * r8i, w16i = 2.f * r8r * r8i;  // w32^16

      float Er[4], Ei[4], Tr[4], Ti[4];
      #pragma unroll
      for (int c0 = 0; c0 < 4; ++c0) {
        float Pr = Z[0][c0][i], Pi = Z[1][c0][i];
        {
          float qr = __shfl_up(Pr, 1u, 16), qi = __shfl_up(Pi, 1u, 16);
          if (m < 1) { qr = 0.f; qi = 0.f; }
          Pr = fmaf(r1r, qr, fmaf(-r1i, qi, Pr));
          Pi = fmaf(r1r, qi, fmaf(r1i, qr, Pi));
        }
        {
          float qr = __shfl_up(Pr, 2u, 16), qi = __shfl_up(Pi, 2u, 16);
          if (m < 2) { qr = 0.f; qi = 0.f; }
          Pr = fmaf(r2r, qr, fmaf(-r2i, qi, Pr));
          Pi = fmaf(r2r, qi, fmaf(r2i, qr, Pi));
        }
        {
          float qr = __shfl_up(Pr, 4u, 16), qi = __shfl_up(Pi, 4u, 16);
          if (m < 4) { qr = 0.f; qi = 0.f; }
          Pr = fmaf(r4r, qr, fmaf(-r4i, qi, Pr));
          Pi = fmaf(r4r, qi, fmaf(r4i, qr, Pi));
        }
        {
          float qr = __shfl_up(Pr, 8u, 16), qi = __shfl_up(Pi, 8u, 16);
          if (m < 8) { qr = 0.f; qi = 0.f; }
          Pr = fmaf(r8r, qr, fmaf(-r8i, qi, Pr));
          Pi = fmaf(r8r, qi, fmaf(r8i, qr, Pi));
        }
        float eqr = __shfl_up(Pr, 1u, 16), eqi = __shfl_up(Pi, 1u, 16);
        if (m == 0) { eqr = 0.f; eqi = 0.f; }
        Er[c0] = eqr; Ei[c0] = eqi;
        Tr[c0] = __shfl(Pr, 15, 16);
        Ti[c0] = __shfl(Pi, 15, 16);
      }
      float C1r = Tr[0], C1i = Ti[0];
      float C2r = fmaf(w16r, C1r, fmaf(-w16i, C1i, Tr[1]));
      float C2i = fmaf(w16r, C1i, fmaf(w16i, C1r, Ti[1]));
      float C3r = fmaf(w16r, C2r, fmaf(-w16i, C2i, Tr[2]));
      float C3i = fmaf(w16r, C2i, fmaf(w16i, C2r, Ti[2]));
      float Cr[4] = {0.f, C1r, C2r, C3r};
      float Ci[4] = {0.f, C1i, C2i, C3i};
      #pragma unroll
      for (int c0 = 0; c0 < 4; ++c0) {
        float Erc = fmaf(w32m[0], Cr[c0], fmaf(-w32m[1], Ci[c0], Er[c0]));
        float Eic = fmaf(w32m[0], Ci[c0], fmaf(w32m[1], Cr[c0], Ei[c0]));
        float ar = c2w[0] * Erc - c2w[1] * Eic;
        float ai = c2w[0] * Eic + c2w[1] * Erc;
        unsigned short hr = bf16bits(ar);
        afh[mt][c0][i] = (short)hr;
        afl[mt][c0][i] = (short)bf16bits(ar - bfval(hr));
        unsigned short hi2 = bf16bits(ai);
        afh[mt][c0][4 + i] = (short)hi2;
        afl[mt][c0][4 + i] = (short)bf16bits(ai - bfval(hi2));
      }
    }
  }

  f32x4 y[2][4];
  #pragma unroll
  for (int mtT = 0; mtT < 2; ++mtT) {
    short8 fh = *reinterpret_cast<const short8*>(tb + 16384 + mtT * 1024 + lane * 16);
    short8 fl = *reinterpret_cast<const short8*>(tb + 18432 + mtT * 1024 + lane * 16);
    short8 wch0 = *reinterpret_cast<const short8*>(tb + 8192 + (mtT * 2 + 0) * 1024 + lane * 16);
    short8 wcl0 = *reinterpret_cast<const short8*>(tb + 12288 + (mtT * 2 + 0) * 1024 + lane * 16);
    short8 wch1 = *reinterpret_cast<const short8*>(tb + 8192 + (mtT * 2 + 1) * 1024 + lane * 16);
    short8 wcl1 = *reinterpret_cast<const short8*>(tb + 12288 + (mtT * 2 + 1) * 1024 + lane * 16);
    #pragma unroll
    for (int c0 = 0; c0 < 4; ++c0) {
      f32x4 acc = {0.f, 0.f, 0.f, 0.f};
      acc = __builtin_amdgcn_mfma_f32_16x16x32_bf16(fh, uh[c0], acc, 0, 0, 0);
      acc = __builtin_amdgcn_mfma_f32_16x16x32_bf16(fh, ul[c0], acc, 0, 0, 0);
      acc = __builtin_amdgcn_mfma_f32_16x16x32_bf16(fl, uh[c0], acc, 0, 0, 0);
      acc = __builtin_amdgcn_mfma_f32_16x16x32_bf16(wch0, afh[0][c0], acc, 0, 0, 0);
      acc = __builtin_amdgcn_mfma_f32_16x16x32_bf16(wch0, afl[0][c0], acc, 0, 0, 0);
      acc = __builtin_amdgcn_mfma_f32_16x16x32_bf16(wcl0, afh[0][c0], acc, 0, 0, 0);
      acc = __builtin_amdgcn_mfma_f32_16x16x32_bf16(wch1, afh[1][c0], acc, 0, 0, 0);
      acc = __builtin_amdgcn_mfma_f32_16x16x32_bf16(wch1, afl[1][c0], acc, 0, 0, 0);
      acc = __builtin_amdgcn_mfma_f32_16x16x32_bf16(wcl1, afh[1][c0], acc, 0, 0, 0);
      y[mtT][c0] = acc;
    }
  }

  // epilogue: GELU (D*u already in y via FIR tap 0), pack, LDS transpose
  #pragma unroll
  for (int mtT = 0; mtT < 2; ++mtT)
    #pragma unroll
    for (int c0 = 0; c0 < 4; ++c0) {
      int eb = 512 * c0 + 32 * m + 16 * mtT + 4 * g;
      f32x4 vv = y[mtT][c0];
      unsigned short bv[4];
      bv[0] = bf16bits(gelu_fast(vv[0]));
      bv[1] = bf16bits(gelu_fast(vv[1]));
      bv[2] = bf16bits(gelu_fast(vv[2]));
      bv[3] = bf16bits(gelu_fast(vv[3]));
      #pragma unroll
      for (int k = 0; k < 4; ++k) {
        int l = eb + k;
        *(short*)(smem + ((l * 8 + wid * 2) ^ (((l >> 5) & 7) << 3))) = (short)bv[k];
      }
    }
  __syncthreads();
  // packed 8B stores: Ybt[(blockIdx.x * 2048 + l) * 4 + 0..3]
  #pragma unroll
  for (int i = 0; i < 8; ++i) {
    int l = t + 256 * i;
    uint2 v = *reinterpret_cast<const uint2*>(smem + ((l * 8) ^ (((l >> 5) & 7) << 3)));
    *reinterpret_cast<uint2*>(Ybt + ((size_t)blockIdx.x * 2048 + l) * 4) = v;
  }
}

// ---------------------------------------------------------------------------
// conv1x1 + GLU, bf16 MFMA 16x16x32. B fragments from h-quartet Ybt layout;
// A (CW) staged in LDS via gload16, XOR swizzle. Packed-u32 output stores.
// ---------------------------------------------------------------------------
__global__ __launch_bounds__(256) void k_conv(const short* __restrict__ Ybt,
                                              const __hip_bfloat16* __restrict__ CWb,
                                              const float* __restrict__ CB,
                                              unsigned* __restrict__ Upk) {
  __shared__ short Alds[128 * 64];
  int lt = blockIdx.x * 128;
  int ot = blockIdx.y * 64;
  int b  = blockIdx.z;
  int t = threadIdx.x;
  int wid = t >> 6, lane = t & 63;
  int wr = wid >> 1, wc = wid & 1;
  int l15 = lane & 15, l4 = lane >> 4;
  f32x4 zero = {0.f, 0.f, 0.f, 0.f};
  f32x4 accA[2][4], accG[2][4];
  #pragma unroll
  for (int m = 0; m < 2; ++m)
    #pragma unroll
    for (int n = 0; n < 4; ++n) { accA[m][n] = zero; accG[m][n] = zero; }

  const short* Yb = Ybt + (size_t)b * 128 * 2048 * 4;
  const char* Wb = (const char*)CWb;

  for (int kt = 0; kt < HH; kt += 64) {
    #pragma unroll
    for (int it = 0; it < 4; ++it) {
      int d = 16 * (t + 256 * it);
      int rowl = d >> 7, cb = d & 127;
      int orow = (rowl < 64) ? (ot + rowl) : (448 + ot + rowl);
      gload16(Wb + (size_t)orow * 1024 + kt * 2 + (cb ^ ((rowl & 7) << 4)),
              (char*)Alds + d);
    }
    short8 bfrag[2][4];
    #pragma unroll
    for (int ks = 0; ks < 2; ++ks)
      #pragma unroll
      for (int n = 0; n < 4; ++n) {
        int l = lt + wc * 64 + n * 16 + l15;
        int octg = (kt >> 3) + ks * 4 + l4;
        const short* p0 = Yb + ((size_t)(2 * octg) * 2048 + l) * 4;
        uint2 A = *reinterpret_cast<const uint2*>(p0);
        uint2 B2 = *reinterpret_cast<const uint2*>(p0 + 8192);
        bfrag[ks][n] = __builtin_bit_cast(short8, u2x2{A, B2});
      }
    __syncthreads();
    #pragma unroll
    for (int ks = 0; ks < 2; ++ks) {
      short8 af[4];
      #pragma unroll
      for (int m = 0; m < 4; ++m) {
        int mrow = ((m < 2) ? (wr * 32 + m * 16) : (64 + wr * 32 + (m - 2) * 16)) + l15;
        int colb = (ks * 64 + 16 * l4) ^ ((mrow & 7) << 4);
        af[m] = *reinterpret_cast<const short8*>((const char*)Alds + mrow * 128 + colb);
      }
      #pragma unroll
      for (int m = 0; m < 2; ++m)
        #pragma unroll
        for (int n = 0; n < 4; ++n) {
          accA[m][n] = __builtin_amdgcn_mfma_f32_16x16x32_bf16(af[m], bfrag[ks][n], accA[m][n], 0, 0, 0);
          accG[m][n] = __builtin_amdgcn_mfma_f32_16x16x32_bf16(af[m + 2], bfrag[ks][n], accG[m][n], 0, 0, 0);
        }
    }
    __syncthreads();
  }
  #pragma unroll
  for (int m = 0; m < 2; ++m) {
    #pragma unroll
    for (int r = 0; r < 4; ++r) {
      int rowl = wr * 32 + m * 16 + l4 * 4 + r;
      float ba = CB[ot + rowl];
      float bg = CB[512 + ot + rowl];
      size_t rowoff = ((size_t)b * HH + ot + rowl) * LL + lt + wc * 64;
      #pragma unroll
      for (int n = 0; n < 4; ++n) {
        float a = accA[m][n][r] + ba;
        float gg = accG[m][n][r] + bg;
        Upk[rowoff + n * 16 + l15] = packsplit(a * sigmoidf_(gg));
      }
    }
  }
}

// ---------------------------------------------------------------------------
// Output projection (fp32 out); reads packed plane, u = hi + lo.
// ---------------------------------------------------------------------------
__global__ __launch_bounds__(256) void k_outgemm(const unsigned* __restrict__ Upk,
                                                 const float* __restrict__ Wo,
                                                 const float* __restrict__ bo,
                                                 float* __restrict__ out) {
  int bl = blockIdx.x * 256 + threadIdx.x;
  int b = bl >> 11, l = bl & (LL - 1);
  float a0 = 0.0f, a1 = 0.0f;
  const unsigned* up = Upk + (size_t)b * HH * LL + l;
  #pragma unroll 4
  for (int h = 0; h < HH; ++h) {
    unsigned u = up[(size_t)h * LL];
    float v = bfval((unsigned short)(u >> 16)) + bfval((unsigned short)(u & 0xFFFFu));
    a0 = fmaf(v, Wo[h * 2 + 0], a0);
    a1 = fmaf(v, Wo[h * 2 + 1], a1);
  }
  out[(size_t)bl * 2 + 0] = a0 + bo[0];
  out[(size_t)bl * 2 + 1] = a1 + bo[1];
}

extern "C" void kernel_launch(void* const* d_in, const int* in_sizes, int n_in,
                              void* d_out, int out_size, void* d_ws, size_t ws_size,
                              hipStream_t stream) {
  const float* X      = (const float*)d_in[0];
  const float* Win    = (const float*)d_in[1];
  const float* bin    = (const float*)d_in[2];
  const float* log_dt = (const float*)d_in[3];
  const float* Cri    = (const float*)d_in[4];
  const float* lAr    = (const float*)d_in[5];
  const float* Aim    = (const float*)d_in[6];
  const float* Dp     = (const float*)d_in[7];
  const float* CW     = (const float*)d_in[8];
  const float* CB     = (const float*)d_in[9];
  const float* Wo     = (const float*)d_in[10];
  const float* bo     = (const float*)d_in[11];
  float* out = (float*)d_out;

  const size_t Pfloats   = (size_t)NNL * HH * NN2 * 4;        // 262144
  const size_t CWfloats  = (size_t)NNL * 2 * HH * HH / 2;     // 1048576
  const size_t Tabfloats = (size_t)NNL * HH * (TABB / 4);     // 16777216
  const size_t Wtfloats  = (size_t)HH * INP;                  // 98304 (hi+lo bf16)
  const size_t Xnf       = (size_t)BB * LL * INP;             // 12582912 elems
  const size_t HL        = (size_t)HH * LL;                   // 1048576

  float* P = (float*)d_ws;
  __hip_bfloat16* CWb = (__hip_bfloat16*)(P + Pfloats);
  char* Tab = (char*)(P + Pfloats + CWfloats);
  __hip_bfloat16* Wthi = (__hip_bfloat16*)(P + Pfloats + CWfloats + Tabfloats);
  __hip_bfloat16* Wtlo = Wthi + Wtfloats;
  __hip_bfloat16* Xhi  = (__hip_bfloat16*)(P + Pfloats + CWfloats + Tabfloats + Wtfloats);
  __hip_bfloat16* Xlo  = Xhi + Xnf;
  size_t head = Pfloats + CWfloats + Tabfloats + Wtfloats + Xnf;

  size_t ws_floats = ws_size / sizeof(float);
  size_t avail = (ws_floats > head) ? (ws_floats - head) : 0;
  // per-batch: Upk = HL u32 (HL floats) + Ybt HL shorts (HL/2 floats)
  int G = (int)(avail / (HL + HL / 2));
  if (G >= 32) G = 32;
  else if (G >= 16) G = 16;
  else if (G >= 8) G = 8;
  else if (G >= 4) G = 4;
  else if (G >= 2) G = 2;
  else G = 1;

  unsigned* Upk = (unsigned*)(P + head);
  short* Ybt = (short*)(Upk + (size_t)G * HL);

  k_params<<<(NNL * HH * NN2 + 255) / 256, 256, 0, stream>>>(log_dt, Cri, lAr, Aim, P);
  k_tables<<<NNL * HH, 64, 0, stream>>>(P, Dp, Tab);
  k_tobf16<<<(NNL * 2 * HH * HH) / 1024, 256, 0, stream>>>(CW, CWb, NNL * 2 * HH * HH);
  k_prepwt<<<(HH * INP + 255) / 256, 256, 0, stream>>>(Win, Wthi, Wtlo);
  k_splitx<<<(int)(Xnf / 1024), 256, 0, stream>>>(X, Xhi, Xlo, (int)Xnf);

  for (int b0 = 0; b0 < BB; b0 += G) {
    int g = (BB - b0 < G) ? (BB - b0) : G;
    k_ingemm<<<dim3(LL / 128, HH / 128, g), 256, 0, stream>>>(
        Xhi + (size_t)b0 * LL * INP, Xlo + (size_t)b0 * LL * INP, Wthi, Wtlo, bin, Upk);
    for (int layer = 0; layer < NNL; ++layer) {
      k_scan<<<g * (HH / 4), 256, 0, stream>>>(
          Upk, Ybt, Tab + (size_t)layer * HH * TABB);
      k_conv<<<dim3(LL / 128, HH / 64, g), 256, 0, stream>>>(
          Ybt, CWb + (size_t)layer * 2 * HH * HH, CB + (size_t)layer * 2 * HH, Upk);
    }
    k_outgemm<<<g * LL / 256, 256, 0, stream>>>(
        Upk, Wo, bo, out + (size_t)b0 * LL * OUTC);
  }
}

// Round 17
// 1090.090 us; speedup vs baseline: 1.7842x; 1.1115x over previous
//
#include <hip/hip_runtime.h>
#include <hip/hip_bf16.h>
#include <math.h>

#define BB 32
#define LL 2048
#define INP 192
#define OUTC 2
#define HH 512
#define NN2 32
#define NNL 4
#define TABB 25088   // bytes of table per (layer,h): 20480 frag + 4096 PL1 + 512 PL2

using short8 = __attribute__((ext_vector_type(8))) short;
using f32x4  = __attribute__((ext_vector_type(4))) float;
using f32x2  = __attribute__((ext_vector_type(2))) float;

struct u2x2 { uint2 a, b; };

__device__ __forceinline__ float sigmoidf_(float x) {
  return 1.0f / (1.0f + expf(-x));
}
__device__ __forceinline__ unsigned short bf16bits(float x) {
  __hip_bfloat16 b = __float2bfloat16(x);
  return __builtin_bit_cast(unsigned short, b);
}
__device__ __forceinline__ float bfval(unsigned short b) {
  unsigned int u = (unsigned int)b << 16;
  return __builtin_bit_cast(float, u);
}
__device__ __forceinline__ unsigned packsplit(float v) {
  unsigned short hb = bf16bits(v);
  unsigned short lb = bf16bits(v - bfval(hb));
  return ((unsigned)hb << 16) | (unsigned)lb;
}
// Abramowitz-Stegun 7.1.26 erf (max err 1.5e-7) based exact-GELU
__device__ __forceinline__ float gelu_fast(float x) {
  float s = x * 0.70710678118654752f;
  float ax = fabsf(s);
  float tt = 1.0f / fmaf(0.3275911f, ax, 1.0f);
  float p = fmaf(1.061405429f, tt, -1.453152027f);
  p = fmaf(p, tt, 1.421413741f);
  p = fmaf(p, tt, -0.284496736f);
  p = fmaf(p, tt, 0.254829592f);
  float e = __expf(-s * s);
  float er = 1.0f - p * tt * e;
  er = copysignf(er, s);
  return 0.5f * x * (1.0f + er);
}
__device__ __forceinline__ void gload16(const void* gsrc, void* ldst) {
  __builtin_amdgcn_global_load_lds(
      (const __attribute__((address_space(1))) void*)gsrc,
      (__attribute__((address_space(3))) void*)ldst, 16, 0, 0);
}

// ---------------------------------------------------------------------------
// P[NL][H][N2][4] = {w_re, w_im, c2_re, c2_im}
// ---------------------------------------------------------------------------
__global__ __launch_bounds__(256) void k_params(const float* __restrict__ log_dt,
                                                const float* __restrict__ Cri,
                                                const float* __restrict__ lAr,
                                                const float* __restrict__ Aim,
                                                float* __restrict__ P) {
  int idx = blockIdx.x * 256 + threadIdx.x;
  if (idx >= NNL * HH * NN2) return;
  float dt  = expf(log_dt[idx / NN2]);
  float Are = -expf(lAr[idx]);
  float Aimv = Aim[idx];
  float dre = Are * dt, dim = Aimv * dt;
  float er = expf(dre);
  float wrv = er * cosf(dim);
  float wiv = er * sinf(dim);
  float Er = wrv - 1.0f, Ei = wiv;
  float den = Are * Are + Aimv * Aimv;
  float Fr = (Er * Are + Ei * Aimv) / den;
  float Fi = (Ei * Are - Er * Aimv) / den;
  float Cre = Cri[idx * 2 + 0], Cim = Cri[idx * 2 + 1];
  P[idx * 4 + 0] = wrv;
  P[idx * 4 + 1] = wiv;
  P[idx * 4 + 2] = 2.0f * (Cre * Fr - Cim * Fi);
  P[idx * 4 + 3] = 2.0f * (Cre * Fi + Cim * Fr);
}

// ---------------------------------------------------------------------------
// Build per-(layer,h) MFMA fragment tables (split bf16 hi/lo) + scan tables.
// FIR tap 0 absorbs D[h]. Round-17 PL layout:
//   20480: PL1 [s][lane] f32x2 w32^m            (4096 B)
//   24576: PL2 [s][g] {w32r, w32i, c2wr, c2wi}  (512 B)
// ---------------------------------------------------------------------------
__global__ __launch_bounds__(64) void k_tables(const float* __restrict__ P,
                                               const float* __restrict__ Dp,
                                               char* __restrict__ Tab) {
  __shared__ float kk[32];
  int tid = threadIdx.x;
  int lh = blockIdx.x;
  char* tb = Tab + (size_t)lh * TABB;
  if (tid < 32) {
    int n = tid;
    const float4 pq = reinterpret_cast<const float4*>(P)[(size_t)lh * NN2 + n];
    float wr = pq.x, wi = pq.y, c2r = pq.z, c2i = pq.w;
    int mt = n >> 4;
    float pr = 1.0f, pi = 0.0f;   // w^d
    for (int d = 0; d < 32; ++d) {
      {  // WA at t = 31-d
        int t_ = 31 - d;
        int lane = ((t_ >> 3) << 4) + (n & 15);
        int j = t_ & 7;
        unsigned short hr = bf16bits(pr);
        unsigned short lr = bf16bits(pr - bfval(hr));
        unsigned short hi_ = bf16bits(pi);
        unsigned short li_ = bf16bits(pi - bfval(hi_));
        *(unsigned short*)(tb + (mt * 2 + 0) * 1024 + lane * 16 + j * 2) = hr;
        *(unsigned short*)(tb + (mt * 2 + 1) * 1024 + lane * 16 + j * 2) = hi_;
        *(unsigned short*)(tb + 4096 + (mt * 2 + 0) * 1024 + lane * 16 + j * 2) = lr;
        *(unsigned short*)(tb + 4096 + (mt * 2 + 1) * 1024 + lane * 16 + j * 2) = li_;
      }
      {  // WC at t = d
        int mtT = d >> 4;
        int lane = (((n & 15) >> 2) << 4) + (d & 15);
        int jre = n & 3, jim = (n & 3) + 4;
        unsigned short hr = bf16bits(pr);
        unsigned short lr = bf16bits(pr - bfval(hr));
        float nim = -pi;
        unsigned short hi_ = bf16bits(nim);
        unsigned short li_ = bf16bits(nim - bfval(hi_));
        char* bh = tb + 8192 + (mtT * 2 + mt) * 1024 + lane * 16;
        char* bl = tb + 12288 + (mtT * 2 + mt) * 1024 + lane * 16;
        *(unsigned short*)(bh + jre * 2) = hr;
        *(unsigned short*)(bh + jim * 2) = hi_;
        *(unsigned short*)(bl + jre * 2) = lr;
        *(unsigned short*)(bl + jim * 2) = li_;
      }
      float kp = c2r * pr - c2i * pi;
      #pragma unroll
      for (int k = 1; k < 32; k <<= 1) kp += __shfl_xor(kp, k, 32);
      if (n == 0) kk[d] = (d == 0) ? (kp + Dp[lh]) : kp;
      float nr = pr * wr - pi * wi;
      pi = pr * wi + pi * wr;
      pr = nr;
    }
    float w32r = pr, w32i = pi;
    float c2wr = c2r * wr - c2i * wi;
    float c2wi = c2r * wi + c2i * wr;
    int s = ((n >> 4) << 2) + (n & 3);
    int gg = (n & 15) >> 2;
    // PL2: per-(s,g) constants (unique writer: n <-> (s,gg) bijection)
    float* q2 = (float*)(tb + 24576 + (size_t)(s * 4 + gg) * 16);
    q2[0] = w32r; q2[1] = w32i; q2[2] = c2wr; q2[3] = c2wi;
    // PL1: per-lane w32^m
    float pmr = 1.0f, pmi = 0.0f;
    for (int m = 0; m < 16; ++m) {
      float* q = (float*)(tb + 20480 + (size_t)((s * 64) + (gg * 16 + m)) * 8);
      q[0] = pmr; q[1] = pmi;
      float t2 = pmr * w32r - pmi * w32i;
      pmi = pmr * w32i + pmi * w32r;
      pmr = t2;
    }
  }
  __syncthreads();
  for (int idx = tid; idx < 1024; idx += 64) {
    int mt = idx >> 9, rem = idx & 511;
    int lane = rem >> 3, j = rem & 7;
    int tt = (mt << 4) + (lane & 15);
    int jf = ((lane >> 4) << 3) + j;
    float val = (jf <= tt) ? kk[tt - jf] : 0.0f;
    unsigned short hb = bf16bits(val);
    unsigned short lb = bf16bits(val - bfval(hb));
    *(unsigned short*)(tb + 16384 + mt * 1024 + lane * 16 + j * 2) = hb;
    *(unsigned short*)(tb + 18432 + mt * 1024 + lane * 16 + j * 2) = lb;
  }
}

// ---------------------------------------------------------------------------
// fp32 -> bf16 convert (CW weights).
// ---------------------------------------------------------------------------
__global__ __launch_bounds__(256) void k_tobf16(const float* __restrict__ src,
                                                __hip_bfloat16* __restrict__ dst,
                                                int n) {
  int i = (blockIdx.x * 256 + threadIdx.x) * 4;
  if (i >= n) return;
  float4 v = *reinterpret_cast<const float4*>(&src[i]);
  dst[i + 0] = __float2bfloat16(v.x);
  dst[i + 1] = __float2bfloat16(v.y);
  dst[i + 2] = __float2bfloat16(v.z);
  dst[i + 3] = __float2bfloat16(v.w);
}

// ---------------------------------------------------------------------------
// Split X fp32 -> Xhi/Xlo bf16 planes (same [b][l][k] layout).
// ---------------------------------------------------------------------------
__global__ __launch_bounds__(256) void k_splitx(const float* __restrict__ src,
                                                __hip_bfloat16* __restrict__ hi,
                                                __hip_bfloat16* __restrict__ lo,
                                                int n) {
  int i = (blockIdx.x * 256 + threadIdx.x) * 4;
  if (i >= n) return;
  float4 v = *reinterpret_cast<const float4*>(&src[i]);
  float vv[4] = {v.x, v.y, v.z, v.w};
  unsigned short hb[4], lb[4];
  #pragma unroll
  for (int j = 0; j < 4; ++j) {
    hb[j] = bf16bits(vv[j]);
    lb[j] = bf16bits(vv[j] - bfval(hb[j]));
  }
  *reinterpret_cast<uint2*>(hi + i) = make_uint2(
      (unsigned)hb[0] | ((unsigned)hb[1] << 16), (unsigned)hb[2] | ((unsigned)hb[3] << 16));
  *reinterpret_cast<uint2*>(lo + i) = make_uint2(
      (unsigned)lb[0] | ((unsigned)lb[1] << 16), (unsigned)lb[2] | ((unsigned)lb[3] << 16));
}

// ---------------------------------------------------------------------------
// W[k][h] fp32 -> Wt hi/lo bf16 [h][k] (transposed, split). One-time, tiny.
// ---------------------------------------------------------------------------
__global__ __launch_bounds__(256) void k_prepwt(const float* __restrict__ W,
                                                __hip_bfloat16* __restrict__ hi,
                                                __hip_bfloat16* __restrict__ lo) {
  int idx = blockIdx.x * 256 + threadIdx.x;   // h*INP + k
  if (idx >= HH * INP) return;
  int h = idx / INP, k = idx - h * INP;
  float v = W[(size_t)k * HH + h];
  unsigned short hb = bf16bits(v);
  hi[idx] = __builtin_bit_cast(__hip_bfloat16, hb);
  lo[idx] = __float2bfloat16(v - bfval(hb));
}

// ---------------------------------------------------------------------------
// Input GEMM, bf16 MFMA split; writes packed-u32 plane Upk.
// ---------------------------------------------------------------------------
__global__ __launch_bounds__(256) void k_ingemm(const __hip_bfloat16* __restrict__ Xhi,
                                                const __hip_bfloat16* __restrict__ Xlo,
                                                const __hip_bfloat16* __restrict__ Wthi,
                                                const __hip_bfloat16* __restrict__ Wtlo,
                                                const float* __restrict__ bias,
                                                unsigned* __restrict__ Upk) {
  int lt = blockIdx.x * 128;
  int ht = blockIdx.y * 128;
  int b  = blockIdx.z;
  int t = threadIdx.x;
  int wid = t >> 6, lane = t & 63;
  int wrow = wid >> 1, wcol = wid & 1;
  int l15 = lane & 15, g = lane >> 4;

  const short* Xh = (const short*)Xhi + (size_t)b * LL * INP;
  const short* Xl = (const short*)Xlo + (size_t)b * LL * INP;
  const short* Bh = (const short*)Wthi;
  const short* Bl = (const short*)Wtlo;

  f32x4 acc[4][4];
  #pragma unroll
  for (int m = 0; m < 4; ++m)
    #pragma unroll
    for (int n = 0; n < 4; ++n) acc[m][n] = f32x4{0.f, 0.f, 0.f, 0.f};

  int lbase = lt + wrow * 64 + l15;
  int hbase = ht + wcol * 64 + l15;

  #pragma unroll
  for (int ks = 0; ks < 6; ++ks) {
    int k0 = ks * 32 + 8 * g;
    short8 ah[4], al[4], bh[4], bl[4];
    #pragma unroll
    for (int m = 0; m < 4; ++m) {
      size_t off = (size_t)(lbase + m * 16) * INP + k0;
      ah[m] = *reinterpret_cast<const short8*>(Xh + off);
      al[m] = *reinterpret_cast<const short8*>(Xl + off);
    }
    #pragma unroll
    for (int n = 0; n < 4; ++n) {
      size_t off = (size_t)(hbase + n * 16) * INP + k0;
      bh[n] = *reinterpret_cast<const short8*>(Bh + off);
      bl[n] = *reinterpret_cast<const short8*>(Bl + off);
    }
    #pragma unroll
    for (int m = 0; m < 4; ++m)
      #pragma unroll
      for (int n = 0; n < 4; ++n) {
        acc[m][n] = __builtin_amdgcn_mfma_f32_16x16x32_bf16(ah[m], bh[n], acc[m][n], 0, 0, 0);
        acc[m][n] = __builtin_amdgcn_mfma_f32_16x16x32_bf16(ah[m], bl[n], acc[m][n], 0, 0, 0);
        acc[m][n] = __builtin_amdgcn_mfma_f32_16x16x32_bf16(al[m], bh[n], acc[m][n], 0, 0, 0);
      }
  }

  #pragma unroll
  for (int n = 0; n < 4; ++n) {
    int h = hbase + n * 16;
    float bv = bias[h];
    size_t rowoff = ((size_t)b * HH + h) * LL;
    #pragma unroll
    for (int m = 0; m < 4; ++m) {
      int l0 = lt + wrow * 64 + m * 16 + g * 4;
      uint4 o;
      o.x = packsplit(acc[m][n][0] + bv);
      o.y = packsplit(acc[m][n][1] + bv);
      o.z = packsplit(acc[m][n][2] + bv);
      o.w = packsplit(acc[m][n][3] + bv);
      *reinterpret_cast<uint4*>(Upk + rowoff + l0) = o;
    }
  }
}

// ---------------------------------------------------------------------------
// MFMA chunk-parallel S4D scan (round-16 structure; round-17 PL layout).
// ---------------------------------------------------------------------------
__global__ __launch_bounds__(256) void k_scan(const unsigned* __restrict__ Upk,
                                              short* __restrict__ Ybt,
                                              const char* __restrict__ Tab) {
  __shared__ __align__(16) char smem[16384];  // ylds [l][h'4], XOR-swizzled
  int t = threadIdx.x;
  int lane = t & 63;
  int wid = t >> 6;                              // 0..3 = h'
  int row = __builtin_amdgcn_readfirstlane(blockIdx.x * 4 + wid);
  int h = row & (HH - 1);
  const char* tb = Tab + (size_t)h * TABB;
  const unsigned* urow = Upk + (size_t)row * LL;
  int g = lane >> 4, m = lane & 15;

  short8 uh[4], ul[4];
  #pragma unroll
  for (int c0 = 0; c0 < 4; ++c0) {
    int off = 512 * c0 + 32 * m + 8 * g;
    uint4 pa = *reinterpret_cast<const uint4*>(urow + off);
    uint4 pb = *reinterpret_cast<const uint4*>(urow + off + 4);
    unsigned p[8] = {pa.x, pa.y, pa.z, pa.w, pb.x, pb.y, pb.z, pb.w};
    unsigned hw[4], lw[4];
    #pragma unroll
    for (int w = 0; w < 4; ++w) {
      unsigned p0 = p[2 * w], p1 = p[2 * w + 1];
      hw[w] = (p1 & 0xFFFF0000u) | (p0 >> 16);
      lw[w] = (p1 << 16) | (p0 & 0x0000FFFFu);
    }
    uh[c0] = __builtin_bit_cast(short8, make_uint4(hw[0], hw[1], hw[2], hw[3]));
    ul[c0] = __builtin_bit_cast(short8, make_uint4(lw[0], lw[1], lw[2], lw[3]));
  }

  short8 afh[2][4], afl[2][4];
  #pragma unroll
  for (int mt = 0; mt < 2; ++mt) {
    f32x4 Z[2][4];
    #pragma unroll
    for (int reim = 0; reim < 2; ++reim) {
      short8 whi = *reinterpret_cast<const short8*>(tb + (mt * 2 + reim) * 1024 + lane * 16);
      short8 wlo = *reinterpret_cast<const short8*>(tb + 4096 + (mt * 2 + reim) * 1024 + lane * 16);
      #pragma unroll
      for (int c0 = 0; c0 < 4; ++c0) {
        f32x4 z = {0.f, 0.f, 0.f, 0.f};
        z = __builtin_amdgcn_mfma_f32_16x16x32_bf16(whi, uh[c0], z, 0, 0, 0);
        z = __builtin_amdgcn_mfma_f32_16x16x32_bf16(whi, ul[c0], z, 0, 0, 0);
        z = __builtin_amdgcn_mfma_f32_16x16x32_bf16(wlo, uh[c0], z, 0, 0, 0);
        Z[reim][c0] = z;
      }
    }
    #pragma unroll
    for (int i = 0; i < 4; ++i) {
      int s = mt * 4 + i;
      f32x2 w32m = *reinterpret_cast<const f32x2*>(tb + 20480 + (size_t)(s * 64 + lane) * 8);
      float4 cc = *reinterpret_cast<const float4*>(tb + 24576 + (size_t)(s * 4 + g) * 16);
      float r1r = cc.x, r1i = cc.y;
      f32x2 c2w = {cc.z, cc.w};
      float r2r = r1r * r1r - r1i * r1i, r2i = 2.f * r1r * r1i;
      float r4r = r2r * r2r - r2i * r2i, r4i = 2.f * r2r * r2i;
      float r8r = r4r * r4r - r4i * r4i, r8i = 2.f * r4r * r4i;
      float w16r = r8r * r8r - r8i * r8i, w16i = 2.f * r8r * r8i;  // w32^16

      float Er[4], Ei[4], Tr[4], Ti[4];
      #pragma unroll
      for (int c0 = 0; c0 < 4; ++c0) {
        float Pr = Z[0][c0][i], Pi = Z[1][c0][i];
        {
          float qr = __shfl_up(Pr, 1u, 16), qi = __shfl_up(Pi, 1u, 16);
          if (m < 1) { qr = 0.f; qi = 0.f; }
          Pr = fmaf(r1r, qr, fmaf(-r1i, qi, Pr));
          Pi = fmaf(r1r, qi, fmaf(r1i, qr, Pi));
        }
        {
          float qr = __shfl_up(Pr, 2u, 16), qi = __shfl_up(Pi, 2u, 16);
          if (m < 2) { qr = 0.f; qi = 0.f; }
          Pr = fmaf(r2r, qr, fmaf(-r2i, qi, Pr));
          Pi = fmaf(r2r, qi, fmaf(r2i, qr, Pi));
        }
        {
          float qr = __shfl_up(Pr, 4u, 16), qi = __shfl_up(Pi, 4u, 16);
          if (m < 4) { qr = 0.f; qi = 0.f; }
          Pr = fmaf(r4r, qr, fmaf(-r4i, qi, Pr));
          Pi = fmaf(r4r, qi, fmaf(r4i, qr, Pi));
        }
        {
          float qr = __shfl_up(Pr, 8u, 16), qi = __shfl_up(Pi, 8u, 16);
          if (m < 8) { qr = 0.f; qi = 0.f; }
          Pr = fmaf(r8r, qr, fmaf(-r8i, qi, Pr));
          Pi = fmaf(r8r, qi, fmaf(r8i, qr, Pi));
        }
        float eqr = __shfl_up(Pr, 1u, 16), eqi = __shfl_up(Pi, 1u, 16);
        if (m == 0) { eqr = 0.f; eqi = 0.f; }
        Er[c0] = eqr; Ei[c0] = eqi;
        Tr[c0] = __shfl(Pr, 15, 16);
        Ti[c0] = __shfl(Pi, 15, 16);
      }
      float C1r = Tr[0], C1i = Ti[0];
      float C2r = fmaf(w16r, C1r, fmaf(-w16i, C1i, Tr[1]));
      float C2i = fmaf(w16r, C1i, fmaf(w16i, C1r, Ti[1]));
      float C3r = fmaf(w16r, C2r, fmaf(-w16i, C2i, Tr[2]));
      float C3i = fmaf(w16r, C2i, fmaf(w16i, C2r, Ti[2]));
      float Cr[4] = {0.f, C1r, C2r, C3r};
      float Ci[4] = {0.f, C1i, C2i, C3i};
      #pragma unroll
      for (int c0 = 0; c0 < 4; ++c0) {
        float Erc = fmaf(w32m[0], Cr[c0], fmaf(-w32m[1], Ci[c0], Er[c0]));
        float Eic = fmaf(w32m[0], Ci[c0], fmaf(w32m[1], Cr[c0], Ei[c0]));
        float ar = c2w[0] * Erc - c2w[1] * Eic;
        float ai = c2w[0] * Eic + c2w[1] * Erc;
        unsigned short hr = bf16bits(ar);
        afh[mt][c0][i] = (short)hr;
        afl[mt][c0][i] = (short)bf16bits(ar - bfval(hr));
        unsigned short hi2 = bf16bits(ai);
        afh[mt][c0][4 + i] = (short)hi2;
        afl[mt][c0][4 + i] = (short)bf16bits(ai - bfval(hi2));
      }
    }
  }

  f32x4 y[2][4];
  #pragma unroll
  for (int mtT = 0; mtT < 2; ++mtT) {
    short8 fh = *reinterpret_cast<const short8*>(tb + 16384 + mtT * 1024 + lane * 16);
    short8 fl = *reinterpret_cast<const short8*>(tb + 18432 + mtT * 1024 + lane * 16);
    short8 wch0 = *reinterpret_cast<const short8*>(tb + 8192 + (mtT * 2 + 0) * 1024 + lane * 16);
    short8 wcl0 = *reinterpret_cast<const short8*>(tb + 12288 + (mtT * 2 + 0) * 1024 + lane * 16);
    short8 wch1 = *reinterpret_cast<const short8*>(tb + 8192 + (mtT * 2 + 1) * 1024 + lane * 16);
    short8 wcl1 = *reinterpret_cast<const short8*>(tb + 12288 + (mtT * 2 + 1) * 1024 + lane * 16);
    #pragma unroll
    for (int c0 = 0; c0 < 4; ++c0) {
      f32x4 acc = {0.f, 0.f, 0.f, 0.f};
      acc = __builtin_amdgcn_mfma_f32_16x16x32_bf16(fh, uh[c0], acc, 0, 0, 0);
      acc = __builtin_amdgcn_mfma_f32_16x16x32_bf16(fh, ul[c0], acc, 0, 0, 0);
      acc = __builtin_amdgcn_mfma_f32_16x16x32_bf16(fl, uh[c0], acc, 0, 0, 0);
      acc = __builtin_amdgcn_mfma_f32_16x16x32_bf16(wch0, afh[0][c0], acc, 0, 0, 0);
      acc = __builtin_amdgcn_mfma_f32_16x16x32_bf16(wch0, afl[0][c0], acc, 0, 0, 0);
      acc = __builtin_amdgcn_mfma_f32_16x16x32_bf16(wcl0, afh[0][c0], acc, 0, 0, 0);
      acc = __builtin_amdgcn_mfma_f32_16x16x32_bf16(wch1, afh[1][c0], acc, 0, 0, 0);
      acc = __builtin_amdgcn_mfma_f32_16x16x32_bf16(wch1, afl[1][c0], acc, 0, 0, 0);
      acc = __builtin_amdgcn_mfma_f32_16x16x32_bf16(wcl1, afh[1][c0], acc, 0, 0, 0);
      y[mtT][c0] = acc;
    }
  }

  // epilogue: GELU (D*u already in y via FIR tap 0), pack, LDS transpose
  #pragma unroll
  for (int mtT = 0; mtT < 2; ++mtT)
    #pragma unroll
    for (int c0 = 0; c0 < 4; ++c0) {
      int eb = 512 * c0 + 32 * m + 16 * mtT + 4 * g;
      f32x4 vv = y[mtT][c0];
      unsigned short bv[4];
      bv[0] = bf16bits(gelu_fast(vv[0]));
      bv[1] = bf16bits(gelu_fast(vv[1]));
      bv[2] = bf16bits(gelu_fast(vv[2]));
      bv[3] = bf16bits(gelu_fast(vv[3]));
      #pragma unroll
      for (int k = 0; k < 4; ++k) {
        int l = eb + k;
        *(short*)(smem + ((l * 8 + wid * 2) ^ (((l >> 5) & 7) << 3))) = (short)bv[k];
      }
    }
  __syncthreads();
  #pragma unroll
  for (int i = 0; i < 8; ++i) {
    int l = t + 256 * i;
    uint2 v = *reinterpret_cast<const uint2*>(smem + ((l * 8) ^ (((l >> 5) & 7) << 3)));
    *reinterpret_cast<uint2*>(Ybt + ((size_t)blockIdx.x * 2048 + l) * 4) = v;
  }
}

// ---------------------------------------------------------------------------
// conv1x1 + GLU, bf16 MFMA 16x16x32 (unchanged from round 16).
// ---------------------------------------------------------------------------
__global__ __launch_bounds__(256) void k_conv(const short* __restrict__ Ybt,
                                              const __hip_bfloat16* __restrict__ CWb,
                                              const float* __restrict__ CB,
                                              unsigned* __restrict__ Upk) {
  __shared__ short Alds[128 * 64];
  int lt = blockIdx.x * 128;
  int ot = blockIdx.y * 64;
  int b  = blockIdx.z;
  int t = threadIdx.x;
  int wid = t >> 6, lane = t & 63;
  int wr = wid >> 1, wc = wid & 1;
  int l15 = lane & 15, l4 = lane >> 4;
  f32x4 zero = {0.f, 0.f, 0.f, 0.f};
  f32x4 accA[2][4], accG[2][4];
  #pragma unroll
  for (int m = 0; m < 2; ++m)
    #pragma unroll
    for (int n = 0; n < 4; ++n) { accA[m][n] = zero; accG[m][n] = zero; }

  const short* Yb = Ybt + (size_t)b * 128 * 2048 * 4;
  const char* Wb = (const char*)CWb;

  for (int kt = 0; kt < HH; kt += 64) {
    #pragma unroll
    for (int it = 0; it < 4; ++it) {
      int d = 16 * (t + 256 * it);
      int rowl = d >> 7, cb = d & 127;
      int orow = (rowl < 64) ? (ot + rowl) : (448 + ot + rowl);
      gload16(Wb + (size_t)orow * 1024 + kt * 2 + (cb ^ ((rowl & 7) << 4)),
              (char*)Alds + d);
    }
    short8 bfrag[2][4];
    #pragma unroll
    for (int ks = 0; ks < 2; ++ks)
      #pragma unroll
      for (int n = 0; n < 4; ++n) {
        int l = lt + wc * 64 + n * 16 + l15;
        int octg = (kt >> 3) + ks * 4 + l4;
        const short* p0 = Yb + ((size_t)(2 * octg) * 2048 + l) * 4;
        uint2 A = *reinterpret_cast<const uint2*>(p0);
        uint2 B2 = *reinterpret_cast<const uint2*>(p0 + 8192);
        bfrag[ks][n] = __builtin_bit_cast(short8, u2x2{A, B2});
      }
    __syncthreads();
    #pragma unroll
    for (int ks = 0; ks < 2; ++ks) {
      short8 af[4];
      #pragma unroll
      for (int m = 0; m < 4; ++m) {
        int mrow = ((m < 2) ? (wr * 32 + m * 16) : (64 + wr * 32 + (m - 2) * 16)) + l15;
        int colb = (ks * 64 + 16 * l4) ^ ((mrow & 7) << 4);
        af[m] = *reinterpret_cast<const short8*>((const char*)Alds + mrow * 128 + colb);
      }
      #pragma unroll
      for (int m = 0; m < 2; ++m)
        #pragma unroll
        for (int n = 0; n < 4; ++n) {
          accA[m][n] = __builtin_amdgcn_mfma_f32_16x16x32_bf16(af[m], bfrag[ks][n], accA[m][n], 0, 0, 0);
          accG[m][n] = __builtin_amdgcn_mfma_f32_16x16x32_bf16(af[m + 2], bfrag[ks][n], accG[m][n], 0, 0, 0);
        }
    }
    __syncthreads();
  }
  #pragma unroll
  for (int m = 0; m < 2; ++m) {
    #pragma unroll
    for (int r = 0; r < 4; ++r) {
      int rowl = wr * 32 + m * 16 + l4 * 4 + r;
      float ba = CB[ot + rowl];
      float bg = CB[512 + ot + rowl];
      size_t rowoff = ((size_t)b * HH + ot + rowl) * LL + lt + wc * 64;
      #pragma unroll
      for (int n = 0; n < 4; ++n) {
        float a = accA[m][n][r] + ba;
        float gg = accG[m][n][r] + bg;
        Upk[rowoff + n * 16 + l15] = packsplit(a * sigmoidf_(gg));
      }
    }
  }
}

// ---------------------------------------------------------------------------
// Output projection (fp32 out); reads packed plane, u = hi + lo.
// ---------------------------------------------------------------------------
__global__ __launch_bounds__(256) void k_outgemm(const unsigned* __restrict__ Upk,
                                                 const float* __restrict__ Wo,
                                                 const float* __restrict__ bo,
                                                 float* __restrict__ out) {
  int bl = blockIdx.x * 256 + threadIdx.x;
  int b = bl >> 11, l = bl & (LL - 1);
  float a0 = 0.0f, a1 = 0.0f;
  const unsigned* up = Upk + (size_t)b * HH * LL + l;
  #pragma unroll 4
  for (int h = 0; h < HH; ++h) {
    unsigned u = up[(size_t)h * LL];
    float v = bfval((unsigned short)(u >> 16)) + bfval((unsigned short)(u & 0xFFFFu));
    a0 = fmaf(v, Wo[h * 2 + 0], a0);
    a1 = fmaf(v, Wo[h * 2 + 1], a1);
  }
  out[(size_t)bl * 2 + 0] = a0 + bo[0];
  out[(size_t)bl * 2 + 1] = a1 + bo[1];
}

extern "C" void kernel_launch(void* const* d_in, const int* in_sizes, int n_in,
                              void* d_out, int out_size, void* d_ws, size_t ws_size,
                              hipStream_t stream) {
  const float* X      = (const float*)d_in[0];
  const float* Win    = (const float*)d_in[1];
  const float* bin    = (const float*)d_in[2];
  const float* log_dt = (const float*)d_in[3];
  const float* Cri    = (const float*)d_in[4];
  const float* lAr    = (const float*)d_in[5];
  const float* Aim    = (const float*)d_in[6];
  const float* Dp     = (const float*)d_in[7];
  const float* CW     = (const float*)d_in[8];
  const float* CB     = (const float*)d_in[9];
  const float* Wo     = (const float*)d_in[10];
  const float* bo     = (const float*)d_in[11];
  float* out = (float*)d_out;

  const size_t Pfloats   = (size_t)NNL * HH * NN2 * 4;        // 262144
  const size_t CWfloats  = (size_t)NNL * 2 * HH * HH / 2;     // 1048576
  const size_t Tabfloats = (size_t)NNL * HH * (TABB / 4);     // 12845056
  const size_t Wtfloats  = (size_t)HH * INP;                  // 98304 (hi+lo bf16)
  const size_t Xnf       = (size_t)BB * LL * INP;             // 12582912 elems (both planes = Xnf floats)
  const size_t HL        = (size_t)HH * LL;                   // 1048576

  float* P = (float*)d_ws;
  __hip_bfloat16* CWb = (__hip_bfloat16*)(P + Pfloats);
  char* Tab = (char*)(P + Pfloats + CWfloats);
  __hip_bfloat16* Wthi = (__hip_bfloat16*)(P + Pfloats + CWfloats + Tabfloats);
  __hip_bfloat16* Wtlo = Wthi + Wtfloats;
  size_t base = Pfloats + CWfloats + Tabfloats + Wtfloats;

  size_t ws_floats = ws_size / sizeof(float);

  // G=32 single-group layout: [base][Upk 32*HL][region = max(X planes, Ybt)]
  // X planes (consumed only by the single ingemm) overlay Ybt (first written
  // by the first k_scan, after ingemm completes on the same stream).
  size_t upk32 = (size_t)32 * HL;
  size_t ybt32 = (size_t)32 * HL / 2;
  size_t region32 = (Xnf > ybt32) ? Xnf : ybt32;

  int G;
  unsigned* Upk;
  short* Ybt;
  __hip_bfloat16 *Xhi, *Xlo;

  if (ws_floats >= base + upk32 + region32) {
    G = 32;
    Upk = (unsigned*)(P + base);
    float* region = P + base + upk32;
    Xhi = (__hip_bfloat16*)region;
    Xlo = Xhi + Xnf;
    Ybt = (short*)region;          // overlays X; X dead after k_ingemm
  } else {
    // fallback: round-16 layout (X planes resident, groups of <=16)
    Xhi = (__hip_bfloat16*)(P + base);
    Xlo = Xhi + Xnf;
    size_t head = base + Xnf;
    size_t avail = (ws_floats > head) ? (ws_floats - head) : 0;
    G = (int)(avail / (HL + HL / 2));
    if (G >= 16) G = 16;
    else if (G >= 8) G = 8;
    else if (G >= 4) G = 4;
    else if (G >= 2) G = 2;
    else G = 1;
    Upk = (unsigned*)(P + head);
    Ybt = (short*)(Upk + (size_t)G * HL);
  }

  k_params<<<(NNL * HH * NN2 + 255) / 256, 256, 0, stream>>>(log_dt, Cri, lAr, Aim, P);
  k_tables<<<NNL * HH, 64, 0, stream>>>(P, Dp, Tab);
  k_tobf16<<<(NNL * 2 * HH * HH) / 1024, 256, 0, stream>>>(CW, CWb, NNL * 2 * HH * HH);
  k_prepwt<<<(HH * INP + 255) / 256, 256, 0, stream>>>(Win, Wthi, Wtlo);

  for (int b0 = 0; b0 < BB; b0 += G) {
    int g = (BB - b0 < G) ? (BB - b0) : G;
    // split X for this group (in overlay mode this is the whole batch once)
    k_splitx<<<(int)((size_t)g * LL * INP / 1024), 256, 0, stream>>>(
        X + (size_t)b0 * LL * INP, Xhi, Xlo, (int)((size_t)g * LL * INP));
    k_ingemm<<<dim3(LL / 128, HH / 128, g), 256, 0, stream>>>(
        Xhi, Xlo, Wthi, Wtlo, bin, Upk);
    for (int layer = 0; layer < NNL; ++layer) {
      k_scan<<<g * (HH / 4), 256, 0, stream>>>(
          Upk, Ybt, Tab + (size_t)layer * HH * TABB);
      k_conv<<<dim3(LL / 128, HH / 64, g), 256, 0, stream>>>(
          Ybt, CWb + (size_t)layer * 2 * HH * HH, CB + (size_t)layer * 2 * HH, Upk);
    }
    k_outgemm<<<g * LL / 256, 256, 0, stream>>>(
        Upk, Wo, bo, out + (size_t)b0 * LL * OUTC);
  }
}

// Round 18
// 1070.722 us; speedup vs baseline: 1.8164x; 1.0181x over previous
//
#include <hip/hip_runtime.h>
#include <hip/hip_bf16.h>
#include <math.h>

#define BB 32
#define LL 2048
#define INP 192
#define OUTC 2
#define HH 512
#define NN2 32
#define NNL 4
#define TABB 26112   // 20480 frag + 4096 PL1 + 1536 PL2

using short8 = __attribute__((ext_vector_type(8))) short;
using f32x4  = __attribute__((ext_vector_type(4))) float;
using f32x2  = __attribute__((ext_vector_type(2))) float;

struct u2x2 { uint2 a, b; };

__device__ __forceinline__ float sigmoidf_(float x) {
  return 1.0f / (1.0f + expf(-x));
}
__device__ __forceinline__ unsigned short bf16bits(float x) {
  __hip_bfloat16 b = __float2bfloat16(x);
  return __builtin_bit_cast(unsigned short, b);
}
__device__ __forceinline__ float bfval(unsigned short b) {
  unsigned int u = (unsigned int)b << 16;
  return __builtin_bit_cast(float, u);
}
__device__ __forceinline__ unsigned packsplit(float v) {
  unsigned short hb = bf16bits(v);
  unsigned short lb = bf16bits(v - bfval(hb));
  return ((unsigned)hb << 16) | (unsigned)lb;
}
// Abramowitz-Stegun 7.1.26 erf (max err 1.5e-7) based exact-GELU
__device__ __forceinline__ float gelu_fast(float x) {
  float s = x * 0.70710678118654752f;
  float ax = fabsf(s);
  float tt = 1.0f / fmaf(0.3275911f, ax, 1.0f);
  float p = fmaf(1.061405429f, tt, -1.453152027f);
  p = fmaf(p, tt, 1.421413741f);
  p = fmaf(p, tt, -0.284496736f);
  p = fmaf(p, tt, 0.254829592f);
  float e = __expf(-s * s);
  float er = 1.0f - p * tt * e;
  er = copysignf(er, s);
  return 0.5f * x * (1.0f + er);
}
__device__ __forceinline__ void gload16(const void* gsrc, void* ldst) {
  __builtin_amdgcn_global_load_lds(
      (const __attribute__((address_space(1))) void*)gsrc,
      (__attribute__((address_space(3))) void*)ldst, 16, 0, 0);
}

// ---------------------------------------------------------------------------
// P[NL][H][N2][4] = {w_re, w_im, c2_re, c2_im}
// ---------------------------------------------------------------------------
__global__ __launch_bounds__(256) void k_params(const float* __restrict__ log_dt,
                                                const float* __restrict__ Cri,
                                                const float* __restrict__ lAr,
                                                const float* __restrict__ Aim,
                                                float* __restrict__ P) {
  int idx = blockIdx.x * 256 + threadIdx.x;
  if (idx >= NNL * HH * NN2) return;
  float dt  = expf(log_dt[idx / NN2]);
  float Are = -expf(lAr[idx]);
  float Aimv = Aim[idx];
  float dre = Are * dt, dim = Aimv * dt;
  float er = expf(dre);
  float wrv = er * cosf(dim);
  float wiv = er * sinf(dim);
  float Er = wrv - 1.0f, Ei = wiv;
  float den = Are * Are + Aimv * Aimv;
  float Fr = (Er * Are + Ei * Aimv) / den;
  float Fi = (Ei * Are - Er * Aimv) / den;
  float Cre = Cri[idx * 2 + 0], Cim = Cri[idx * 2 + 1];
  P[idx * 4 + 0] = wrv;
  P[idx * 4 + 1] = wiv;
  P[idx * 4 + 2] = 2.0f * (Cre * Fr - Cim * Fi);
  P[idx * 4 + 3] = 2.0f * (Cre * Fi + Cim * Fr);
}

// ---------------------------------------------------------------------------
// Build per-(layer,h) MFMA fragment tables (split bf16 hi/lo) + scan tables.
// FIR tap 0 absorbs D[h]. Round-18 PL layout:
//   20480: PL1 [s][lane] f32x2 w32^m                          (4096 B)
//   24576: PL2 [s][g] {w32, w64, w128, w256, w512, c2w} cplx  (1536 B)
// ---------------------------------------------------------------------------
__global__ __launch_bounds__(64) void k_tables(const float* __restrict__ P,
                                               const float* __restrict__ Dp,
                                               char* __restrict__ Tab) {
  __shared__ float kk[32];
  int tid = threadIdx.x;
  int lh = blockIdx.x;
  char* tb = Tab + (size_t)lh * TABB;
  if (tid < 32) {
    int n = tid;
    const float4 pq = reinterpret_cast<const float4*>(P)[(size_t)lh * NN2 + n];
    float wr = pq.x, wi = pq.y, c2r = pq.z, c2i = pq.w;
    int mt = n >> 4;
    float pr = 1.0f, pi = 0.0f;   // w^d
    for (int d = 0; d < 32; ++d) {
      {  // WA at t = 31-d
        int t_ = 31 - d;
        int lane = ((t_ >> 3) << 4) + (n & 15);
        int j = t_ & 7;
        unsigned short hr = bf16bits(pr);
        unsigned short lr = bf16bits(pr - bfval(hr));
        unsigned short hi_ = bf16bits(pi);
        unsigned short li_ = bf16bits(pi - bfval(hi_));
        *(unsigned short*)(tb + (mt * 2 + 0) * 1024 + lane * 16 + j * 2) = hr;
        *(unsigned short*)(tb + (mt * 2 + 1) * 1024 + lane * 16 + j * 2) = hi_;
        *(unsigned short*)(tb + 4096 + (mt * 2 + 0) * 1024 + lane * 16 + j * 2) = lr;
        *(unsigned short*)(tb + 4096 + (mt * 2 + 1) * 1024 + lane * 16 + j * 2) = li_;
      }
      {  // WC at t = d
        int mtT = d >> 4;
        int lane = (((n & 15) >> 2) << 4) + (d & 15);
        int jre = n & 3, jim = (n & 3) + 4;
        unsigned short hr = bf16bits(pr);
        unsigned short lr = bf16bits(pr - bfval(hr));
        float nim = -pi;
        unsigned short hi_ = bf16bits(nim);
        unsigned short li_ = bf16bits(nim - bfval(hi_));
        char* bh = tb + 8192 + (mtT * 2 + mt) * 1024 + lane * 16;
        char* bl = tb + 12288 + (mtT * 2 + mt) * 1024 + lane * 16;
        *(unsigned short*)(bh + jre * 2) = hr;
        *(unsigned short*)(bh + jim * 2) = hi_;
        *(unsigned short*)(bl + jre * 2) = lr;
        *(unsigned short*)(bl + jim * 2) = li_;
      }
      float kp = c2r * pr - c2i * pi;
      #pragma unroll
      for (int k = 1; k < 32; k <<= 1) kp += __shfl_xor(kp, k, 32);
      if (n == 0) kk[d] = (d == 0) ? (kp + Dp[lh]) : kp;
      float nr = pr * wr - pi * wi;
      pi = pr * wi + pi * wr;
      pr = nr;
    }
    float w32r = pr, w32i = pi;
    float c2wr = c2r * wr - c2i * wi;
    float c2wi = c2r * wi + c2i * wr;
    int s = ((n >> 4) << 2) + (n & 3);
    int gg = (n & 15) >> 2;
    // ratio ladder (same formulas as the old in-kernel chain)
    float r2r = w32r * w32r - w32i * w32i, r2i = 2.f * w32r * w32i;      // w64
    float r4r = r2r * r2r - r2i * r2i,     r4i = 2.f * r2r * r2i;        // w128
    float r8r = r4r * r4r - r4i * r4i,     r8i = 2.f * r4r * r4i;        // w256
    float w16r = r8r * r8r - r8i * r8i,    w16i = 2.f * r8r * r8i;       // w512
    float* q2 = (float*)(tb + 24576 + (size_t)(s * 4 + gg) * 48);
    q2[0] = w32r;  q2[1] = w32i;
    q2[2] = r2r;   q2[3] = r2i;
    q2[4] = r4r;   q2[5] = r4i;
    q2[6] = r8r;   q2[7] = r8i;
    q2[8] = w16r;  q2[9] = w16i;
    q2[10] = c2wr; q2[11] = c2wi;
    // PL1: per-lane w32^m
    float pmr = 1.0f, pmi = 0.0f;
    for (int m = 0; m < 16; ++m) {
      float* q = (float*)(tb + 20480 + (size_t)((s * 64) + (gg * 16 + m)) * 8);
      q[0] = pmr; q[1] = pmi;
      float t2 = pmr * w32r - pmi * w32i;
      pmi = pmr * w32i + pmi * w32r;
      pmr = t2;
    }
  }
  __syncthreads();
  for (int idx = tid; idx < 1024; idx += 64) {
    int mt = idx >> 9, rem = idx & 511;
    int lane = rem >> 3, j = rem & 7;
    int tt = (mt << 4) + (lane & 15);
    int jf = ((lane >> 4) << 3) + j;
    float val = (jf <= tt) ? kk[tt - jf] : 0.0f;
    unsigned short hb = bf16bits(val);
    unsigned short lb = bf16bits(val - bfval(hb));
    *(unsigned short*)(tb + 16384 + mt * 1024 + lane * 16 + j * 2) = hb;
    *(unsigned short*)(tb + 18432 + mt * 1024 + lane * 16 + j * 2) = lb;
  }
}

// ---------------------------------------------------------------------------
// fp32 -> bf16 convert (CW weights).
// ---------------------------------------------------------------------------
__global__ __launch_bounds__(256) void k_tobf16(const float* __restrict__ src,
                                                __hip_bfloat16* __restrict__ dst,
                                                int n) {
  int i = (blockIdx.x * 256 + threadIdx.x) * 4;
  if (i >= n) return;
  float4 v = *reinterpret_cast<const float4*>(&src[i]);
  dst[i + 0] = __float2bfloat16(v.x);
  dst[i + 1] = __float2bfloat16(v.y);
  dst[i + 2] = __float2bfloat16(v.z);
  dst[i + 3] = __float2bfloat16(v.w);
}

// ---------------------------------------------------------------------------
// Split X fp32 -> Xhi/Xlo bf16 planes (same [b][l][k] layout).
// ---------------------------------------------------------------------------
__global__ __launch_bounds__(256) void k_splitx(const float* __restrict__ src,
                                                __hip_bfloat16* __restrict__ hi,
                                                __hip_bfloat16* __restrict__ lo,
                                                int n) {
  int i = (blockIdx.x * 256 + threadIdx.x) * 4;
  if (i >= n) return;
  float4 v = *reinterpret_cast<const float4*>(&src[i]);
  float vv[4] = {v.x, v.y, v.z, v.w};
  unsigned short hb[4], lb[4];
  #pragma unroll
  for (int j = 0; j < 4; ++j) {
    hb[j] = bf16bits(vv[j]);
    lb[j] = bf16bits(vv[j] - bfval(hb[j]));
  }
  *reinterpret_cast<uint2*>(hi + i) = make_uint2(
      (unsigned)hb[0] | ((unsigned)hb[1] << 16), (unsigned)hb[2] | ((unsigned)hb[3] << 16));
  *reinterpret_cast<uint2*>(lo + i) = make_uint2(
      (unsigned)lb[0] | ((unsigned)lb[1] << 16), (unsigned)lb[2] | ((unsigned)lb[3] << 16));
}

// ---------------------------------------------------------------------------
// W[k][h] fp32 -> Wt hi/lo bf16 [h][k] (transposed, split). One-time, tiny.
// ---------------------------------------------------------------------------
__global__ __launch_bounds__(256) void k_prepwt(const float* __restrict__ W,
                                                __hip_bfloat16* __restrict__ hi,
                                                __hip_bfloat16* __restrict__ lo) {
  int idx = blockIdx.x * 256 + threadIdx.x;   // h*INP + k
  if (idx >= HH * INP) return;
  int h = idx / INP, k = idx - h * INP;
  float v = W[(size_t)k * HH + h];
  unsigned short hb = bf16bits(v);
  hi[idx] = __builtin_bit_cast(__hip_bfloat16, hb);
  lo[idx] = __float2bfloat16(v - bfval(hb));
}

// ---------------------------------------------------------------------------
// Input GEMM, bf16 MFMA split; writes packed-u32 plane Upk.
// ---------------------------------------------------------------------------
__global__ __launch_bounds__(256) void k_ingemm(const __hip_bfloat16* __restrict__ Xhi,
                                                const __hip_bfloat16* __restrict__ Xlo,
                                                const __hip_bfloat16* __restrict__ Wthi,
                                                const __hip_bfloat16* __restrict__ Wtlo,
                                                const float* __restrict__ bias,
                                                unsigned* __restrict__ Upk) {
  int lt = blockIdx.x * 128;
  int ht = blockIdx.y * 128;
  int b  = blockIdx.z;
  int t = threadIdx.x;
  int wid = t >> 6, lane = t & 63;
  int wrow = wid >> 1, wcol = wid & 1;
  int l15 = lane & 15, g = lane >> 4;

  const short* Xh = (const short*)Xhi + (size_t)b * LL * INP;
  const short* Xl = (const short*)Xlo + (size_t)b * LL * INP;
  const short* Bh = (const short*)Wthi;
  const short* Bl = (const short*)Wtlo;

  f32x4 acc[4][4];
  #pragma unroll
  for (int m = 0; m < 4; ++m)
    #pragma unroll
    for (int n = 0; n < 4; ++n) acc[m][n] = f32x4{0.f, 0.f, 0.f, 0.f};

  int lbase = lt + wrow * 64 + l15;
  int hbase = ht + wcol * 64 + l15;

  #pragma unroll
  for (int ks = 0; ks < 6; ++ks) {
    int k0 = ks * 32 + 8 * g;
    short8 ah[4], al[4], bh[4], bl[4];
    #pragma unroll
    for (int m = 0; m < 4; ++m) {
      size_t off = (size_t)(lbase + m * 16) * INP + k0;
      ah[m] = *reinterpret_cast<const short8*>(Xh + off);
      al[m] = *reinterpret_cast<const short8*>(Xl + off);
    }
    #pragma unroll
    for (int n = 0; n < 4; ++n) {
      size_t off = (size_t)(hbase + n * 16) * INP + k0;
      bh[n] = *reinterpret_cast<const short8*>(Bh + off);
      bl[n] = *reinterpret_cast<const short8*>(Bl + off);
    }
    #pragma unroll
    for (int m = 0; m < 4; ++m)
      #pragma unroll
      for (int n = 0; n < 4; ++n) {
        acc[m][n] = __builtin_amdgcn_mfma_f32_16x16x32_bf16(ah[m], bh[n], acc[m][n], 0, 0, 0);
        acc[m][n] = __builtin_amdgcn_mfma_f32_16x16x32_bf16(ah[m], bl[n], acc[m][n], 0, 0, 0);
        acc[m][n] = __builtin_amdgcn_mfma_f32_16x16x32_bf16(al[m], bh[n], acc[m][n], 0, 0, 0);
      }
  }

  #pragma unroll
  for (int n = 0; n < 4; ++n) {
    int h = hbase + n * 16;
    float bv = bias[h];
    size_t rowoff = ((size_t)b * HH + h) * LL;
    #pragma unroll
    for (int m = 0; m < 4; ++m) {
      int l0 = lt + wrow * 64 + m * 16 + g * 4;
      uint4 o;
      o.x = packsplit(acc[m][n][0] + bv);
      o.y = packsplit(acc[m][n][1] + bv);
      o.z = packsplit(acc[m][n][2] + bv);
      o.w = packsplit(acc[m][n][3] + bv);
      *reinterpret_cast<uint4*>(Upk + rowoff + l0) = o;
    }
  }
}

// ---------------------------------------------------------------------------
// MFMA chunk-parallel S4D scan (round-18: full ratio ladder precomputed in
// PL2 -- deletes the per-slot squaring chain, ~240 VALU instr + ~10 live
// VGPRs; goal is back under the 102-VGPR 5-wave cliff with FREE allocation).
// ---------------------------------------------------------------------------
__global__ __launch_bounds__(256) void k_scan(const unsigned* __restrict__ Upk,
                                              short* __restrict__ Ybt,
                                              const char* __restrict__ Tab) {
  __shared__ __align__(16) char smem[16384];  // ylds [l][h'4], XOR-swizzled
  int t = threadIdx.x;
  int lane = t & 63;
  int wid = t >> 6;                              // 0..3 = h'
  int row = __builtin_amdgcn_readfirstlane(blockIdx.x * 4 + wid);
  int h = row & (HH - 1);
  const char* tb = Tab + (size_t)h * TABB;
  const unsigned* urow = Upk + (size_t)row * LL;
  int g = lane >> 4, m = lane & 15;

  short8 uh[4], ul[4];
  #pragma unroll
  for (int c0 = 0; c0 < 4; ++c0) {
    int off = 512 * c0 + 32 * m + 8 * g;
    uint4 pa = *reinterpret_cast<const uint4*>(urow + off);
    uint4 pb = *reinterpret_cast<const uint4*>(urow + off + 4);
    unsigned p[8] = {pa.x, pa.y, pa.z, pa.w, pb.x, pb.y, pb.z, pb.w};
    unsigned hw[4], lw[4];
    #pragma unroll
    for (int w = 0; w < 4; ++w) {
      unsigned p0 = p[2 * w], p1 = p[2 * w + 1];
      hw[w] = (p1 & 0xFFFF0000u) | (p0 >> 16);
      lw[w] = (p1 << 16) | (p0 & 0x0000FFFFu);
    }
    uh[c0] = __builtin_bit_cast(short8, make_uint4(hw[0], hw[1], hw[2], hw[3]));
    ul[c0] = __builtin_bit_cast(short8, make_uint4(lw[0], lw[1], lw[2], lw[3]));
  }

  short8 afh[2][4], afl[2][4];
  #pragma unroll
  for (int mt = 0; mt < 2; ++mt) {
    f32x4 Z[2][4];
    #pragma unroll
    for (int reim = 0; reim < 2; ++reim) {
      short8 whi = *reinterpret_cast<const short8*>(tb + (mt * 2 + reim) * 1024 + lane * 16);
      short8 wlo = *reinterpret_cast<const short8*>(tb + 4096 + (mt * 2 + reim) * 1024 + lane * 16);
      #pragma unroll
      for (int c0 = 0; c0 < 4; ++c0) {
        f32x4 z = {0.f, 0.f, 0.f, 0.f};
        z = __builtin_amdgcn_mfma_f32_16x16x32_bf16(whi, uh[c0], z, 0, 0, 0);
        z = __builtin_amdgcn_mfma_f32_16x16x32_bf16(whi, ul[c0], z, 0, 0, 0);
        z = __builtin_amdgcn_mfma_f32_16x16x32_bf16(wlo, uh[c0], z, 0, 0, 0);
        Z[reim][c0] = z;
      }
    }
    #pragma unroll
    for (int i = 0; i < 4; ++i) {
      int s = mt * 4 + i;
      f32x2 w32m = *reinterpret_cast<const f32x2*>(tb + 20480 + (size_t)(s * 64 + lane) * 8);
      const float* c6 = (const float*)(tb + 24576 + (size_t)(s * 4 + g) * 48);
      float4 cA = *reinterpret_cast<const float4*>(c6);       // w32, w64
      float4 cB = *reinterpret_cast<const float4*>(c6 + 4);   // w128, w256
      float4 cC = *reinterpret_cast<const float4*>(c6 + 8);   // w512, c2w
      float r1r = cA.x, r1i = cA.y;
      float r2r = cA.z, r2i = cA.w;
      float r4r = cB.x, r4i = cB.y;
      float r8r = cB.z, r8i = cB.w;
      float w16r = cC.x, w16i = cC.y;
      f32x2 c2w = {cC.z, cC.w};

      float Er[4], Ei[4], Tr[4], Ti[4];
      #pragma unroll
      for (int c0 = 0; c0 < 4; ++c0) {
        float Pr = Z[0][c0][i], Pi = Z[1][c0][i];
        {
          float qr = __shfl_up(Pr, 1u, 16), qi = __shfl_up(Pi, 1u, 16);
          if (m < 1) { qr = 0.f; qi = 0.f; }
          Pr = fmaf(r1r, qr, fmaf(-r1i, qi, Pr));
          Pi = fmaf(r1r, qi, fmaf(r1i, qr, Pi));
        }
        {
          float qr = __shfl_up(Pr, 2u, 16), qi = __shfl_up(Pi, 2u, 16);
          if (m < 2) { qr = 0.f; qi = 0.f; }
          Pr = fmaf(r2r, qr, fmaf(-r2i, qi, Pr));
          Pi = fmaf(r2r, qi, fmaf(r2i, qr, Pi));
        }
        {
          float qr = __shfl_up(Pr, 4u, 16), qi = __shfl_up(Pi, 4u, 16);
          if (m < 4) { qr = 0.f; qi = 0.f; }
          Pr = fmaf(r4r, qr, fmaf(-r4i, qi, Pr));
          Pi = fmaf(r4r, qi, fmaf(r4i, qr, Pi));
        }
        {
          float qr = __shfl_up(Pr, 8u, 16), qi = __shfl_up(Pi, 8u, 16);
          if (m < 8) { qr = 0.f; qi = 0.f; }
          Pr = fmaf(r8r, qr, fmaf(-r8i, qi, Pr));
          Pi = fmaf(r8r, qi, fmaf(r8i, qr, Pi));
        }
        float eqr = __shfl_up(Pr, 1u, 16), eqi = __shfl_up(Pi, 1u, 16);
        if (m == 0) { eqr = 0.f; eqi = 0.f; }
        Er[c0] = eqr; Ei[c0] = eqi;
        Tr[c0] = __shfl(Pr, 15, 16);
        Ti[c0] = __shfl(Pi, 15, 16);
      }
      float C1r = Tr[0], C1i = Ti[0];
      float C2r = fmaf(w16r, C1r, fmaf(-w16i, C1i, Tr[1]));
      float C2i = fmaf(w16r, C1i, fmaf(w16i, C1r, Ti[1]));
      float C3r = fmaf(w16r, C2r, fmaf(-w16i, C2i, Tr[2]));
      float C3i = fmaf(w16r, C2i, fmaf(w16i, C2r, Ti[2]));
      float Cr[4] = {0.f, C1r, C2r, C3r};
      float Ci[4] = {0.f, C1i, C2i, C3i};
      #pragma unroll
      for (int c0 = 0; c0 < 4; ++c0) {
        float Erc = fmaf(w32m[0], Cr[c0], fmaf(-w32m[1], Ci[c0], Er[c0]));
        float Eic = fmaf(w32m[0], Ci[c0], fmaf(w32m[1], Cr[c0], Ei[c0]));
        float ar = c2w[0] * Erc - c2w[1] * Eic;
        float ai = c2w[0] * Eic + c2w[1] * Erc;
        unsigned short hr = bf16bits(ar);
        afh[mt][c0][i] = (short)hr;
        afl[mt][c0][i] = (short)bf16bits(ar - bfval(hr));
        unsigned short hi2 = bf16bits(ai);
        afh[mt][c0][4 + i] = (short)hi2;
        afl[mt][c0][4 + i] = (short)bf16bits(ai - bfval(hi2));
      }
    }
  }

  f32x4 y[2][4];
  #pragma unroll
  for (int mtT = 0; mtT < 2; ++mtT) {
    short8 fh = *reinterpret_cast<const short8*>(tb + 16384 + mtT * 1024 + lane * 16);
    short8 fl = *reinterpret_cast<const short8*>(tb + 18432 + mtT * 1024 + lane * 16);
    short8 wch0 = *reinterpret_cast<const short8*>(tb + 8192 + (mtT * 2 + 0) * 1024 + lane * 16);
    short8 wcl0 = *reinterpret_cast<const short8*>(tb + 12288 + (mtT * 2 + 0) * 1024 + lane * 16);
    short8 wch1 = *reinterpret_cast<const short8*>(tb + 8192 + (mtT * 2 + 1) * 1024 + lane * 16);
    short8 wcl1 = *reinterpret_cast<const short8*>(tb + 12288 + (mtT * 2 + 1) * 1024 + lane * 16);
    #pragma unroll
    for (int c0 = 0; c0 < 4; ++c0) {
      f32x4 acc = {0.f, 0.f, 0.f, 0.f};
      acc = __builtin_amdgcn_mfma_f32_16x16x32_bf16(fh, uh[c0], acc, 0, 0, 0);
      acc = __builtin_amdgcn_mfma_f32_16x16x32_bf16(fh, ul[c0], acc, 0, 0, 0);
      acc = __builtin_amdgcn_mfma_f32_16x16x32_bf16(fl, uh[c0], acc, 0, 0, 0);
      acc = __builtin_amdgcn_mfma_f32_16x16x32_bf16(wch0, afh[0][c0], acc, 0, 0, 0);
      acc = __builtin_amdgcn_mfma_f32_16x16x32_bf16(wch0, afl[0][c0], acc, 0, 0, 0);
      acc = __builtin_amdgcn_mfma_f32_16x16x32_bf16(wcl0, afh[0][c0], acc, 0, 0, 0);
      acc = __builtin_amdgcn_mfma_f32_16x16x32_bf16(wch1, afh[1][c0], acc, 0, 0, 0);
      acc = __builtin_amdgcn_mfma_f32_16x16x32_bf16(wch1, afl[1][c0], acc, 0, 0, 0);
      acc = __builtin_amdgcn_mfma_f32_16x16x32_bf16(wcl1, afh[1][c0], acc, 0, 0, 0);
      y[mtT][c0] = acc;
    }
  }

  // epilogue: GELU (D*u already in y via FIR tap 0), pack, LDS transpose
  #pragma unroll
  for (int mtT = 0; mtT < 2; ++mtT)
    #pragma unroll
    for (int c0 = 0; c0 < 4; ++c0) {
      int eb = 512 * c0 + 32 * m + 16 * mtT + 4 * g;
      f32x4 vv = y[mtT][c0];
      unsigned short bv[4];
      bv[0] = bf16bits(gelu_fast(vv[0]));
      bv[1] = bf16bits(gelu_fast(vv[1]));
      bv[2] = bf16bits(gelu_fast(vv[2]));
      bv[3] = bf16bits(gelu_fast(vv[3]));
      #pragma unroll
      for (int k = 0; k < 4; ++k) {
        int l = eb + k;
        *(short*)(smem + ((l * 8 + wid * 2) ^ (((l >> 5) & 7) << 3))) = (short)bv[k];
      }
    }
  __syncthreads();
  #pragma unroll
  for (int i = 0; i < 8; ++i) {
    int l = t + 256 * i;
    uint2 v = *reinterpret_cast<const uint2*>(smem + ((l * 8) ^ (((l >> 5) & 7) << 3)));
    *reinterpret_cast<uint2*>(Ybt + ((size_t)blockIdx.x * 2048 + l) * 4) = v;
  }
}

// ---------------------------------------------------------------------------
// conv1x1 + GLU, bf16 MFMA 16x16x32 (unchanged).
// ---------------------------------------------------------------------------
__global__ __launch_bounds__(256) void k_conv(const short* __restrict__ Ybt,
                                              const __hip_bfloat16* __restrict__ CWb,
                                              const float* __restrict__ CB,
                                              unsigned* __restrict__ Upk) {
  __shared__ short Alds[128 * 64];
  int lt = blockIdx.x * 128;
  int ot = blockIdx.y * 64;
  int b  = blockIdx.z;
  int t = threadIdx.x;
  int wid = t >> 6, lane = t & 63;
  int wr = wid >> 1, wc = wid & 1;
  int l15 = lane & 15, l4 = lane >> 4;
  f32x4 zero = {0.f, 0.f, 0.f, 0.f};
  f32x4 accA[2][4], accG[2][4];
  #pragma unroll
  for (int m = 0; m < 2; ++m)
    #pragma unroll
    for (int n = 0; n < 4; ++n) { accA[m][n] = zero; accG[m][n] = zero; }

  const short* Yb = Ybt + (size_t)b * 128 * 2048 * 4;
  const char* Wb = (const char*)CWb;

  for (int kt = 0; kt < HH; kt += 64) {
    #pragma unroll
    for (int it = 0; it < 4; ++it) {
      int d = 16 * (t + 256 * it);
      int rowl = d >> 7, cb = d & 127;
      int orow = (rowl < 64) ? (ot + rowl) : (448 + ot + rowl);
      gload16(Wb + (size_t)orow * 1024 + kt * 2 + (cb ^ ((rowl & 7) << 4)),
              (char*)Alds + d);
    }
    short8 bfrag[2][4];
    #pragma unroll
    for (int ks = 0; ks < 2; ++ks)
      #pragma unroll
      for (int n = 0; n < 4; ++n) {
        int l = lt + wc * 64 + n * 16 + l15;
        int octg = (kt >> 3) + ks * 4 + l4;
        const short* p0 = Yb + ((size_t)(2 * octg) * 2048 + l) * 4;
        uint2 A = *reinterpret_cast<const uint2*>(p0);
        uint2 B2 = *reinterpret_cast<const uint2*>(p0 + 8192);
        bfrag[ks][n] = __builtin_bit_cast(short8, u2x2{A, B2});
      }
    __syncthreads();
    #pragma unroll
    for (int ks = 0; ks < 2; ++ks) {
      short8 af[4];
      #pragma unroll
      for (int m = 0; m < 4; ++m) {
        int mrow = ((m < 2) ? (wr * 32 + m * 16) : (64 + wr * 32 + (m - 2) * 16)) + l15;
        int colb = (ks * 64 + 16 * l4) ^ ((mrow & 7) << 4);
        af[m] = *reinterpret_cast<const short8*>((const char*)Alds + mrow * 128 + colb);
      }
      #pragma unroll
      for (int m = 0; m < 2; ++m)
        #pragma unroll
        for (int n = 0; n < 4; ++n) {
          accA[m][n] = __builtin_amdgcn_mfma_f32_16x16x32_bf16(af[m], bfrag[ks][n], accA[m][n], 0, 0, 0);
          accG[m][n] = __builtin_amdgcn_mfma_f32_16x16x32_bf16(af[m + 2], bfrag[ks][n], accG[m][n], 0, 0, 0);
        }
    }
    __syncthreads();
  }
  #pragma unroll
  for (int m = 0; m < 2; ++m) {
    #pragma unroll
    for (int r = 0; r < 4; ++r) {
      int rowl = wr * 32 + m * 16 + l4 * 4 + r;
      float ba = CB[ot + rowl];
      float bg = CB[512 + ot + rowl];
      size_t rowoff = ((size_t)b * HH + ot + rowl) * LL + lt + wc * 64;
      #pragma unroll
      for (int n = 0; n < 4; ++n) {
        float a = accA[m][n][r] + ba;
        float gg = accG[m][n][r] + bg;
        Upk[rowoff + n * 16 + l15] = packsplit(a * sigmoidf_(gg));
      }
    }
  }
}

// ---------------------------------------------------------------------------
// Output projection (fp32 out); reads packed plane, u = hi + lo.
// ---------------------------------------------------------------------------
__global__ __launch_bounds__(256) void k_outgemm(const unsigned* __restrict__ Upk,
                                                 const float* __restrict__ Wo,
                                                 const float* __restrict__ bo,
                                                 float* __restrict__ out) {
  int bl = blockIdx.x * 256 + threadIdx.x;
  int b = bl >> 11, l = bl & (LL - 1);
  float a0 = 0.0f, a1 = 0.0f;
  const unsigned* up = Upk + (size_t)b * HH * LL + l;
  #pragma unroll 4
  for (int h = 0; h < HH; ++h) {
    unsigned u = up[(size_t)h * LL];
    float v = bfval((unsigned short)(u >> 16)) + bfval((unsigned short)(u & 0xFFFFu));
    a0 = fmaf(v, Wo[h * 2 + 0], a0);
    a1 = fmaf(v, Wo[h * 2 + 1], a1);
  }
  out[(size_t)bl * 2 + 0] = a0 + bo[0];
  out[(size_t)bl * 2 + 1] = a1 + bo[1];
}

extern "C" void kernel_launch(void* const* d_in, const int* in_sizes, int n_in,
                              void* d_out, int out_size, void* d_ws, size_t ws_size,
                              hipStream_t stream) {
  const float* X      = (const float*)d_in[0];
  const float* Win    = (const float*)d_in[1];
  const float* bin    = (const float*)d_in[2];
  const float* log_dt = (const float*)d_in[3];
  const float* Cri    = (const float*)d_in[4];
  const float* lAr    = (const float*)d_in[5];
  const float* Aim    = (const float*)d_in[6];
  const float* Dp     = (const float*)d_in[7];
  const float* CW     = (const float*)d_in[8];
  const float* CB     = (const float*)d_in[9];
  const float* Wo     = (const float*)d_in[10];
  const float* bo     = (const float*)d_in[11];
  float* out = (float*)d_out;

  const size_t Pfloats   = (size_t)NNL * HH * NN2 * 4;        // 262144
  const size_t CWfloats  = (size_t)NNL * 2 * HH * HH / 2;     // 1048576
  const size_t Tabfloats = (size_t)NNL * HH * (TABB / 4);     // 13369344
  const size_t Wtfloats  = (size_t)HH * INP;                  // 98304 (hi+lo bf16)
  const size_t Xnf       = (size_t)BB * LL * INP;             // 12582912 elems (both planes = Xnf floats)
  const size_t HL        = (size_t)HH * LL;                   // 1048576

  float* P = (float*)d_ws;
  __hip_bfloat16* CWb = (__hip_bfloat16*)(P + Pfloats);
  char* Tab = (char*)(P + Pfloats + CWfloats);
  __hip_bfloat16* Wthi = (__hip_bfloat16*)(P + Pfloats + CWfloats + Tabfloats);
  __hip_bfloat16* Wtlo = Wthi + Wtfloats;
  size_t base = Pfloats + CWfloats + Tabfloats + Wtfloats;

  size_t ws_floats = ws_size / sizeof(float);

  size_t upk32 = (size_t)32 * HL;
  size_t ybt32 = (size_t)32 * HL / 2;
  size_t region32 = (Xnf > ybt32) ? Xnf : ybt32;

  int G;
  unsigned* Upk;
  short* Ybt;
  __hip_bfloat16 *Xhi, *Xlo;

  if (ws_floats >= base + upk32 + region32) {
    G = 32;
    Upk = (unsigned*)(P + base);
    float* region = P + base + upk32;
    Xhi = (__hip_bfloat16*)region;
    Xlo = Xhi + Xnf;
    Ybt = (short*)region;          // overlays X; X dead after k_ingemm
  } else {
    Xhi = (__hip_bfloat16*)(P + base);
    Xlo = Xhi + Xnf;
    size_t head = base + Xnf;
    size_t avail = (ws_floats > head) ? (ws_floats - head) : 0;
    G = (int)(avail / (HL + HL / 2));
    if (G >= 16) G = 16;
    else if (G >= 8) G = 8;
    else if (G >= 4) G = 4;
    else if (G >= 2) G = 2;
    else G = 1;
    Upk = (unsigned*)(P + head);
    Ybt = (short*)(Upk + (size_t)G * HL);
  }

  k_params<<<(NNL * HH * NN2 + 255) / 256, 256, 0, stream>>>(log_dt, Cri, lAr, Aim, P);
  k_tables<<<NNL * HH, 64, 0, stream>>>(P, Dp, Tab);
  k_tobf16<<<(NNL * 2 * HH * HH) / 1024, 256, 0, stream>>>(CW, CWb, NNL * 2 * HH * HH);
  k_prepwt<<<(HH * INP + 255) / 256, 256, 0, stream>>>(Win, Wthi, Wtlo);

  for (int b0 = 0; b0 < BB; b0 += G) {
    int g = (BB - b0 < G) ? (BB - b0) : G;
    k_splitx<<<(int)((size_t)g * LL * INP / 1024), 256, 0, stream>>>(
        X + (size_t)b0 * LL * INP, Xhi, Xlo, (int)((size_t)g * LL * INP));
    k_ingemm<<<dim3(LL / 128, HH / 128, g), 256, 0, stream>>>(
        Xhi, Xlo, Wthi, Wtlo, bin, Upk);
    for (int layer = 0; layer < NNL; ++layer) {
      k_scan<<<g * (HH / 4), 256, 0, stream>>>(
          Upk, Ybt, Tab + (size_t)layer * HH * TABB);
      k_conv<<<dim3(LL / 128, HH / 64, g), 256, 0, stream>>>(
          Ybt, CWb + (size_t)layer * 2 * HH * HH, CB + (size_t)layer * 2 * HH, Upk);
    }
    k_outgemm<<<g * LL / 256, 256, 0, stream>>>(
        Upk, Wo, bo, out + (size_t)b0 * LL * OUTC);
  }
}